// Round 11
// baseline (3091.995 us; speedup 1.0000x reference)
//
#include <hip/hip_runtime.h>

#define DEV __device__ __forceinline__

typedef unsigned short u16;
typedef unsigned int u32;
typedef __attribute__((ext_vector_type(8))) short bf8_t;   // 8 bf16 (4 VGPR)
typedef __attribute__((ext_vector_type(4))) float f4_t;

constexpr int T_SEQ = 1024;
constexpr int DMODEL = 512;
constexpr int NPAT = 512;

// ---------------- epilogue modes ----------------
enum {
  E_BIAS = 0,
  E_VQ = 5,
  E_RES = 6,
  E_ACC = 7,
  E_POS = 8,
  E_GUM3 = 9,
  E_GELU3 = 10,
  E_QKV3 = 11
};

// ---------------- bf16 triple-split helpers ----------------
DEV u16 f2bf(float x) {
  u32 u = __float_as_uint(x);
  u32 r = u + 0x7FFFu + ((u >> 16) & 1u);
  return (u16)(r >> 16);
}
DEV float bf2f(u16 h) { return __uint_as_float((u32)h << 16); }
DEV void split3(float x, u16& h, u16& m, u16& l) {
  h = f2bf(x);
  float r1 = x - bf2f(h);
  m = f2bf(r1);
  float r2 = r1 - bf2f(m);
  l = f2bf(r2);
}

DEV f4_t mf16(bf8_t a, bf8_t b, f4_t c) {
  return __builtin_amdgcn_mfma_f32_16x16x32_bf16(a, b, c, 0, 0, 0);
}
// 6-product triple-split accumulate (err ~2^-24)
DEV f4_t prod6(bf8_t ah, bf8_t am, bf8_t al, bf8_t bh, bf8_t bm, bf8_t bl,
               f4_t c) {
  c = mf16(ah, bh, c);
  c = mf16(ah, bm, c);
  c = mf16(am, bh, c);
  c = mf16(ah, bl, c);
  c = mf16(am, bm, c);
  c = mf16(al, bh, c);
  return c;
}

// async global->LDS, 16B per lane; LDS dest = base + lane*16 (wave-uniform base)
typedef const __attribute__((address_space(1))) unsigned char* gas_t;
typedef __attribute__((address_space(3))) unsigned char* las_t;
DEV void gload16(const u16* g, u16* l) {
  __builtin_amdgcn_global_load_lds((gas_t)(const void*)g, (las_t)(void*)l, 16,
                                   0, 0);
}

// ---------------- MFMA GEMM, triple-bf16 split (fp32-accurate) ---------------
// C[M,N] = A[M,K]*B[N,K]^T via 6 bf16 products. Verified R6-R10.
// 2-phase prefetch: STAGE(t+1 -> buf^1) issued BEFORE compute(buf); single
// __syncthreads()/iter. BM=64, BN=128, LDS dbuf 72KB -> 2 blocks/CU.
// 1-D grid + bijective XCD swizzle.
template <int EPI>
__global__ __launch_bounds__(256, 2) void gemm_mf(
    const u16* __restrict__ Ah, const u16* __restrict__ Am,
    const u16* __restrict__ Al, const u16* __restrict__ Bh,
    const u16* __restrict__ Bm, const u16* __restrict__ Bl,
    const float* __restrict__ bias, const float* __restrict__ res,
    float* __restrict__ Cf, u16* __restrict__ Ch, u16* __restrict__ Cm,
    u16* __restrict__ Cl, int N, int KK, int lda, int ldb, int gx) {
  constexpr int BM = 64;
  constexpr int MT = 2;  // m-tiles per wave
  __shared__ __align__(16) u16 AsH[2][BM][4][8], AsM[2][BM][4][8],
      AsL[2][BM][4][8];
  __shared__ __align__(16) u16 BsH[2][128][4][8], BsM[2][128][4][8],
      BsL[2][128][4][8];
  const int tid = threadIdx.x;
  const int w = tid >> 6, lane = tid & 63;
  const int wy = w >> 1, wx = w & 1;
  const int lr = lane & 15, lg = lane >> 4;

  // bijective XCD swizzle (all grids divisible by 8)
  const int nwg = gridDim.x;
  const int bid = blockIdx.x;
  const int qq = nwg >> 3;
  const int wg = (bid & 7) * qq + (bid >> 3);
  const int by = wg / gx, bx = wg % gx;
  const int bm = by * BM, bn = bx * 128;

  const int rowl = lane >> 2, slot4 = lane & 3;  // per-lane stage coords

  auto STAGE = [&](int k0, int buf) {
#pragma unroll
    for (int it = 0; it < 3; ++it) {  // A: 12 chunks (3 planes x 4)
      const int f = w + 4 * it;
      const int plane = f >> 2;
      const int ch = f & 3;
      const int row = ch * 16 + rowl;
      const int kp = slot4 ^ ((row >> 1) & 3);
      const size_t g = (size_t)(bm + row) * lda + k0 + kp * 8;
      if (plane == 0)
        gload16(&Ah[g], &AsH[buf][0][0][0] + ch * 512);
      else if (plane == 1)
        gload16(&Am[g], &AsM[buf][0][0][0] + ch * 512);
      else
        gload16(&Al[g], &AsL[buf][0][0][0] + ch * 512);
    }
#pragma unroll
    for (int it = 0; it < 6; ++it) {  // B: 24 chunks (3 planes x 8)
      const int f = w + 4 * it;
      const int plane = f >> 3;
      const int ch = f & 7;
      const int row = ch * 16 + rowl;
      const int kp = slot4 ^ ((row >> 1) & 3);
      const size_t g = (size_t)(bn + row) * ldb + k0 + kp * 8;
      if (plane == 0)
        gload16(&Bh[g], &BsH[buf][0][0][0] + ch * 512);
      else if (plane == 1)
        gload16(&Bm[g], &BsM[buf][0][0][0] + ch * 512);
      else
        gload16(&Bl[g], &BsL[buf][0][0][0] + ch * 512);
    }
  };

  f4_t acc[MT][4];
#pragma unroll
  for (int mt = 0; mt < MT; ++mt)
#pragma unroll
    for (int nt = 0; nt < 4; ++nt) acc[mt][nt] = (f4_t){0.f, 0.f, 0.f, 0.f};

  const int nsteps = KK / 32;
  STAGE(0, 0);
  __syncthreads();
  for (int t = 0; t < nsteps; ++t) {
    const int cur = t & 1;
    if (t + 1 < nsteps) STAGE((t + 1) * 32, cur ^ 1);

    bf8_t fah[MT], fam[MT], fal[MT], fbh[4], fbm[4], fbl[4];
#pragma unroll
    for (int mt = 0; mt < MT; ++mt) {
      int row = wy * 32 + mt * 16 + lr;
      int slot = lg ^ ((row >> 1) & 3);
      fah[mt] = *(const bf8_t*)&AsH[cur][row][slot][0];
      fam[mt] = *(const bf8_t*)&AsM[cur][row][slot][0];
      fal[mt] = *(const bf8_t*)&AsL[cur][row][slot][0];
    }
#pragma unroll
    for (int nt = 0; nt < 4; ++nt) {
      int col = wx * 64 + nt * 16 + lr;
      int slot = lg ^ ((col >> 1) & 3);
      fbh[nt] = *(const bf8_t*)&BsH[cur][col][slot][0];
      fbm[nt] = *(const bf8_t*)&BsM[cur][col][slot][0];
      fbl[nt] = *(const bf8_t*)&BsL[cur][col][slot][0];
    }
#pragma unroll
    for (int mt = 0; mt < MT; ++mt)
#pragma unroll
      for (int nt = 0; nt < 4; ++nt)
        acc[mt][nt] = prod6(fah[mt], fam[mt], fal[mt], fbh[nt], fbm[nt],
                            fbl[nt], acc[mt][nt]);
    __syncthreads();
  }

  // ---- epilogue (C frag: col = lane&15, row = 4*(lane>>4)+i) ----
  float bv[4];
  if constexpr (EPI == E_BIAS || EPI == E_RES || EPI == E_GELU3 ||
                EPI == E_QKV3) {
#pragma unroll
    for (int nt = 0; nt < 4; ++nt) bv[nt] = bias[bn + wx * 64 + nt * 16 + lr];
  }
#pragma unroll
  for (int mt = 0; mt < MT; ++mt)
#pragma unroll
    for (int nt = 0; nt < 4; ++nt) {
      const int c = bn + wx * 64 + nt * 16 + lr;
#pragma unroll
      for (int i = 0; i < 4; ++i) {
        const int m = bm + wy * 32 + mt * 16 + 4 * lg + i;
        const size_t idx = (size_t)m * N + c;
        float v = acc[mt][nt][i];
        if constexpr (EPI == E_BIAS) {
          Cf[idx] = v + bv[nt];
        } else if constexpr (EPI == E_RES) {
          Cf[idx] = v + bv[nt] + res[idx];
        } else if constexpr (EPI == E_ACC) {
          Cf[idx] += v;
        } else if constexpr (EPI == E_POS) {
          Cf[idx] = v + res[(size_t)(m & 1023) * N + c];
        } else if constexpr (EPI == E_GUM3) {
          float t = 4.0f * v + 2.0f * res[idx];
          u16 h2, m2, l2;
          split3(t, h2, m2, l2);
          Ch[idx] = h2;
          Cm[idx] = m2;
          Cl[idx] = l2;
        } else if constexpr (EPI == E_GELU3) {
          float t = v + bv[nt];
          float g = 0.5f * t * (1.0f + erff(t * 0.7071067811865476f));
          u16 h2, m2, l2;
          split3(g, h2, m2, l2);
          Ch[idx] = h2;
          Cm[idx] = m2;
          Cl[idx] = l2;
        } else if constexpr (EPI == E_QKV3) {
          float t = v + bv[nt];
          u16 h2, m2, l2;
          split3(t, h2, m2, l2);
          size_t o;
          if (c < 512) {
            o = (size_t)m * 512 + c;                       // Q [B,T,512]
          } else if (c < 1024) {
            o = 4194304 + (size_t)m * 512 + (c - 512);     // K [B,T,512]
          } else {
            int cc = c - 1024, hh2 = cc >> 6, dd = cc & 63;
            int bb2 = m >> 10, tt = m & 1023;
            o = 8388608 +
                (((size_t)(bb2 * 8 + hh2) * 64 + dd) << 10) + tt;  // Vt
          }
          Ch[o] = h2;
          Cm[o] = m2;
          Cl[o] = l2;
        }
      }
    }
}

// ---------------- MFMA flash attention (triple-split, fp32-grade) ------------
// 1-D grid 1024, XCD-swizzled: b = bid&7 so each XCD owns one batch's K/V
// (~6.3MB, L2-resident). 4 waves, each owns 16 q-rows of a 64-row q-tile.
// T14 async-STAGE: K/V(kt+1) loaded to 12 NAMED uint4 regs at top of iter kt
// (latency hides under QK^T+softmax+PV), ds_written to LDS after the PV
// barrier (P and V(kt) dead there). P aliases the K tile as before.
__global__ __launch_bounds__(256, 3) void flash_mfma(
    const u16* __restrict__ QKVh, const u16* __restrict__ QKVm,
    const u16* __restrict__ QKVl, u16* __restrict__ Oh, u16* __restrict__ Om,
    u16* __restrict__ Ol) {
  __shared__ __align__(16) u16 KP[3][64][8][8];  // K tile, then P tile
  __shared__ __align__(16) u16 Vs[3][64][8][8];
  const int tid = threadIdx.x;
  const int w = tid >> 6, lane = tid & 63;
  const int lr = lane & 15, lg = lane >> 4;
  // XCD swizzle: bid&7 -> XCD; slot covers (hh, qt) for batch b
  const int bid = blockIdx.x;
  const int b = bid & 7;
  const int slot = bid >> 3;       // 0..127
  const int hh = slot >> 4;        // 0..7
  const int qt = slot & 15;        // 0..15

  const u16* Qh = QKVh;
  const u16* Qm = QKVm;
  const u16* Ql = QKVl;
  const u16* Kh = QKVh + 4194304;
  const u16* Km = QKVm + 4194304;
  const u16* Kl = QKVl + 4194304;
  const u16* Vh = QKVh + 8388608;
  const u16* Vm = QKVm + 8388608;
  const u16* Vl = QKVl + 8388608;

  // Q fragments (A-op: m = lr, k-packet = lg), hoisted for all kt
  bf8_t qf[2][3];
  {
    size_t g =
        ((size_t)(b * 1024 + qt * 64 + w * 16 + lr)) * 512 + hh * 64 + lg * 8;
    qf[0][0] = *(const bf8_t*)&Qh[g];
    qf[0][1] = *(const bf8_t*)&Qm[g];
    qf[0][2] = *(const bf8_t*)&Ql[g];
    qf[1][0] = *(const bf8_t*)&Qh[g + 32];
    qf[1][1] = *(const bf8_t*)&Qm[g + 32];
    qf[1][2] = *(const bf8_t*)&Ql[g + 32];
  }

  f4_t oacc[4];
#pragma unroll
  for (int nt = 0; nt < 4; ++nt) oacc[nt] = (f4_t){0.f, 0.f, 0.f, 0.f};
  float mrun[4], lrun[4];
#pragma unroll
  for (int i = 0; i < 4; ++i) {
    mrun[i] = -__builtin_huge_valf();
    lrun[i] = 0.0f;
  }

  const int rowl8 = lane >> 3, slot8 = lane & 7;  // stage coords (8 rows/chunk)
  uint4 kr0, kr1, kr2, kr3, kr4, kr5, vr0, vr1, vr2, vr3, vr4, vr5;

#define FM_LD1(it, krv, vrv)                                                \
  {                                                                         \
    const int f = w + 4 * (it);                                             \
    const int plane = f >> 3, ch = f & 7;                                   \
    const int row = ch * 8 + rowl8;                                         \
    const int kp = slot8 ^ (row & 7);                                       \
    const u16* kb = plane == 0 ? Kh : plane == 1 ? Km : Kl;                 \
    krv = *(const uint4*)&kb[((size_t)(b * 1024 + kt2 * 64 + row)) * 512 +  \
                             hh * 64 + kp * 8];                             \
    const u16* vb = plane == 0 ? Vh : plane == 1 ? Vm : Vl;                 \
    vrv = *(const uint4*)&vb[((size_t)((b * 8 + hh) * 64 + row)) * 1024 +   \
                             kt2 * 64 + kp * 8];                            \
  }
#define FM_LOAD(ktv)                                                        \
  {                                                                         \
    const int kt2 = (ktv);                                                  \
    FM_LD1(0, kr0, vr0);                                                    \
    FM_LD1(1, kr1, vr1);                                                    \
    FM_LD1(2, kr2, vr2);                                                    \
    FM_LD1(3, kr3, vr3);                                                    \
    FM_LD1(4, kr4, vr4);                                                    \
    FM_LD1(5, kr5, vr5);                                                    \
  }
#define FM_ST1(it, krv, vrv)                                                \
  {                                                                         \
    const int f = w + 4 * (it);                                             \
    const int plane = f >> 3, ch = f & 7;                                   \
    u16* kd = (plane == 0   ? &KP[0][0][0][0]                               \
               : plane == 1 ? &KP[1][0][0][0]                               \
                            : &KP[2][0][0][0]) +                            \
              ch * 512 + lane * 8;                                          \
    *(uint4*)kd = krv;                                                      \
    u16* vd = (plane == 0   ? &Vs[0][0][0][0]                               \
               : plane == 1 ? &Vs[1][0][0][0]                               \
                            : &Vs[2][0][0][0]) +                            \
              ch * 512 + lane * 8;                                          \
    *(uint4*)vd = vrv;                                                      \
  }
#define FM_STORE()                                                          \
  {                                                                         \
    FM_ST1(0, kr0, vr0);                                                    \
    FM_ST1(1, kr1, vr1);                                                    \
    FM_ST1(2, kr2, vr2);                                                    \
    FM_ST1(3, kr3, vr3);                                                    \
    FM_ST1(4, kr4, vr4);                                                    \
    FM_ST1(5, kr5, vr5);                                                    \
  }

  FM_LOAD(0);
  FM_STORE();
  __syncthreads();

  for (int kt = 0; kt < 16; ++kt) {
    if (kt + 1 < 16) FM_LOAD(kt + 1);  // async; hides under compute below

    // ---- S = Q K^T : 4 n-tiles x 2 k-slices x 6 products ----
    f4_t s[4];
#pragma unroll
    for (int nt = 0; nt < 4; ++nt) {
      s[nt] = (f4_t){0.f, 0.f, 0.f, 0.f};
      const int col = nt * 16 + lr;
#pragma unroll
      for (int ks = 0; ks < 2; ++ks) {
        int slt = (ks * 4 + lg) ^ (col & 7);
        bf8_t kh = *(const bf8_t*)&KP[0][col][slt][0];
        bf8_t km = *(const bf8_t*)&KP[1][col][slt][0];
        bf8_t kl = *(const bf8_t*)&KP[2][col][slt][0];
        s[nt] = prod6(qf[ks][0], qf[ks][1], qf[ks][2], kh, km, kl, s[nt]);
      }
    }

    // ---- online softmax (row = 4*lg+i; reduce over lr via shfl) ----
#pragma unroll
    for (int i = 0; i < 4; ++i) {
      float rm = -__builtin_huge_valf();
#pragma unroll
      for (int nt = 0; nt < 4; ++nt) {
        s[nt][i] *= 0.125f;
        rm = fmaxf(rm, s[nt][i]);
      }
      rm = fmaxf(rm, __shfl_xor(rm, 1));
      rm = fmaxf(rm, __shfl_xor(rm, 2));
      rm = fmaxf(rm, __shfl_xor(rm, 4));
      rm = fmaxf(rm, __shfl_xor(rm, 8));
      float mnew = fmaxf(mrun[i], rm);
      float alpha = __expf(mrun[i] - mnew);
      float rs = 0.0f;
#pragma unroll
      for (int nt = 0; nt < 4; ++nt) {
        float p = __expf(s[nt][i] - mnew);
        s[nt][i] = p;
        rs += p;
      }
      rs += __shfl_xor(rs, 1);
      rs += __shfl_xor(rs, 2);
      rs += __shfl_xor(rs, 4);
      rs += __shfl_xor(rs, 8);
      lrun[i] = lrun[i] * alpha + rs;
      mrun[i] = mnew;
#pragma unroll
      for (int nt = 0; nt < 4; ++nt) oacc[nt][i] *= alpha;
    }

    __syncthreads();  // all waves done reading K tile -> safe to overwrite

    // ---- P -> KP (wave-private rows, 3 planes, swizzled) ----
#pragma unroll
    for (int nt = 0; nt < 4; ++nt)
#pragma unroll
      for (int i = 0; i < 4; ++i) {
        int qrow = w * 16 + 4 * lg + i;
        int kv = nt * 16 + lr;
        int kp = kv >> 3, j = kv & 7;
        int slt = kp ^ (qrow & 7);
        u16 h2, m2, l2;
        split3(s[nt][i], h2, m2, l2);
        KP[0][qrow][slt][j] = h2;
        KP[1][qrow][slt][j] = m2;
        KP[2][qrow][slt][j] = l2;
      }

    // ---- O += P V (A = own P rows, B = Vt cols) ----
    bf8_t pf[2][3];
#pragma unroll
    for (int ks = 0; ks < 2; ++ks) {
      int row = w * 16 + lr;
      int slt = (ks * 4 + lg) ^ (row & 7);
      pf[ks][0] = *(const bf8_t*)&KP[0][row][slt][0];
      pf[ks][1] = *(const bf8_t*)&KP[1][row][slt][0];
      pf[ks][2] = *(const bf8_t*)&KP[2][row][slt][0];
    }
#pragma unroll
    for (int ntd = 0; ntd < 4; ++ntd) {
      const int col = ntd * 16 + lr;
#pragma unroll
      for (int ks = 0; ks < 2; ++ks) {
        int slt = (ks * 4 + lg) ^ (col & 7);
        bf8_t vh = *(const bf8_t*)&Vs[0][col][slt][0];
        bf8_t vm = *(const bf8_t*)&Vs[1][col][slt][0];
        bf8_t vl = *(const bf8_t*)&Vs[2][col][slt][0];
        oacc[ntd] =
            prod6(pf[ks][0], pf[ks][1], pf[ks][2], vh, vm, vl, oacc[ntd]);
      }
    }

    __syncthreads();  // P and V(kt) dead -> write K/V(kt+1)
    if (kt + 1 < 16) {
      FM_STORE();
      __syncthreads();
    }
  }
#undef FM_LD1
#undef FM_LOAD
#undef FM_ST1
#undef FM_STORE

  // ---- epilogue: normalize, split3, store planes [B,T,512] ----
#pragma unroll
  for (int i = 0; i < 4; ++i) {
    float inv = 1.0f / lrun[i];
    int t = qt * 64 + w * 16 + 4 * lg + i;
#pragma unroll
    for (int ntd = 0; ntd < 4; ++ntd) {
      int d = hh * 64 + ntd * 16 + lr;
      size_t idx = ((size_t)(b * 1024 + t)) * 512 + d;
      u16 h2, m2, l2;
      split3(oacc[ntd][i] * inv, h2, m2, l2);
      Oh[idx] = h2;
      Om[idx] = m2;
      Ol[idx] = l2;
    }
  }
}

// ---------------- fp32 vector GEMM (VQ-head precision anchor) ----------------
template <int BM, int BN, int WR, int EPI>
__global__ __launch_bounds__((BM / WR) * (BN / 64) * 64) void gemm_f32(
    const float* __restrict__ A, const float* __restrict__ Bmat,
    const float* __restrict__ bias, float* __restrict__ C, int M, int N, int K,
    const int* __restrict__ ep, const int* __restrict__ tot) {
  constexpr int BK = 16;
  constexpr int WN = BN / 64;
  constexpr int NW = (BM / WR) * WN;
  constexpr int NT = NW * 64;
  constexpr int RM = WR / 8;
  __shared__ __align__(16) float As[BK][BM + 4];
  __shared__ __align__(16) float Bs[BK][BN + 4];
  const int tid = threadIdx.x;
  const int w = tid >> 6, lane = tid & 63;
  const int wy = w / WN, wx = w % WN;
  const int ly = lane >> 3, lx = lane & 7;
  const int bm = blockIdx.y * BM;
  const int bn = blockIdx.x * BN;
  const int rbase = wy * WR + ly * RM;

  float acc[RM][8];
#pragma unroll
  for (int i = 0; i < RM; ++i)
#pragma unroll
    for (int j = 0; j < 8; ++j) acc[i][j] = 0.0f;

  for (int k0 = 0; k0 < K; k0 += BK) {
#pragma unroll
    for (int i = 0; i < (BM * BK / 4) / NT; ++i) {
      int idx = tid + i * NT;
      int r = idx >> 2, c4 = (idx & 3) << 2;
      const float4 v = *(const float4*)(A + (size_t)(bm + r) * K + k0 + c4);
      As[c4 + 0][r] = v.x;
      As[c4 + 1][r] = v.y;
      As[c4 + 2][r] = v.z;
      As[c4 + 3][r] = v.w;
    }
#pragma unroll
    for (int i = 0; i < (BN * BK / 4) / NT; ++i) {
      int idx = tid + i * NT;
      int r = idx >> 2, c4 = (idx & 3) << 2;
      const float4 v = *(const float4*)(Bmat + (size_t)(bn + r) * K + k0 + c4);
      Bs[c4 + 0][r] = v.x;
      Bs[c4 + 1][r] = v.y;
      Bs[c4 + 2][r] = v.z;
      Bs[c4 + 3][r] = v.w;
    }
    __syncthreads();
#pragma unroll
    for (int k = 0; k < BK; ++k) {
      float a[RM], b[8];
#pragma unroll
      for (int r4 = 0; r4 < RM; r4 += 4)
        *(float4*)&a[r4] = *(const float4*)&As[k][rbase + r4];
      *(float4*)&b[0] = *(const float4*)&Bs[k][wx * 64 + lx * 8];
      *(float4*)&b[4] = *(const float4*)&Bs[k][wx * 64 + lx * 8 + 4];
#pragma unroll
      for (int i = 0; i < RM; ++i)
#pragma unroll
        for (int j = 0; j < 8; ++j) acc[i][j] = fmaf(a[i], b[j], acc[i][j]);
    }
    __syncthreads();
  }

  const int ncol = bn + wx * 64 + lx * 8;
  float bb[8];
  if constexpr (EPI == E_BIAS) {
    *(float4*)&bb[0] = *(const float4*)(bias + ncol);
    *(float4*)&bb[4] = *(const float4*)(bias + ncol + 4);
  }
  float invt = 1.0f;
  if constexpr (EPI == E_VQ) {
    float t = 1.0f - 0.5f * (float)ep[0] / (float)tot[0];
    invt = 1.0f / fmaxf(0.5f, t);
  }
#pragma unroll
  for (int i = 0; i < RM; ++i) {
    const int m = bm + rbase + i;
    float o[8];
#pragma unroll
    for (int j = 0; j < 8; ++j) o[j] = acc[i][j];
    if constexpr (EPI == E_BIAS) {
#pragma unroll
      for (int j = 0; j < 8; ++j) o[j] += bb[j];
    } else if constexpr (EPI == E_VQ) {
#pragma unroll
      for (int j = 0; j < 8; ++j) o[j] *= invt;
    }
    *(float4*)(C + (size_t)m * N + ncol) = *(float4*)&o[0];
    *(float4*)(C + (size_t)m * N + ncol + 4) = *(float4*)&o[4];
  }
}

// ---------------- row kernels ----------------
DEV float wave_sum(float v) {
#pragma unroll
  for (int off = 1; off < 64; off <<= 1) v += __shfl_xor(v, off);
  return v;
}

DEV void store8_split3(u16* H, u16* M, u16* L, size_t base, const float* t) {
  u16 vh[8], vm[8], vl[8];
#pragma unroll
  for (int j = 0; j < 8; ++j) split3(t[j], vh[j], vm[j], vl[j]);
  *(ushort4*)&H[base] = make_ushort4(vh[0], vh[1], vh[2], vh[3]);
  *(ushort4*)&H[base + 4] = make_ushort4(vh[4], vh[5], vh[6], vh[7]);
  *(ushort4*)&M[base] = make_ushort4(vm[0], vm[1], vm[2], vm[3]);
  *(ushort4*)&M[base + 4] = make_ushort4(vm[4], vm[5], vm[6], vm[7]);
  *(ushort4*)&L[base] = make_ushort4(vl[0], vl[1], vl[2], vl[3]);
  *(ushort4*)&L[base + 4] = make_ushort4(vl[4], vl[5], vl[6], vl[7]);
}

__global__ __launch_bounds__(256) void ln_split3(const float* __restrict__ x,
                                                 const float* __restrict__ g,
                                                 const float* __restrict__ b,
                                                 u16* __restrict__ yh,
                                                 u16* __restrict__ ym,
                                                 u16* __restrict__ yl) {
  const int row = blockIdx.x * 4 + (threadIdx.x >> 6);
  const int lane = threadIdx.x & 63;
  const float* xr = x + (size_t)row * DMODEL;
  float v[8];
  *(float4*)&v[0] = *(const float4*)(xr + lane * 8);
  *(float4*)&v[4] = *(const float4*)(xr + lane * 8 + 4);
  float s = 0.0f;
#pragma unroll
  for (int j = 0; j < 8; ++j) s += v[j];
  s = wave_sum(s);
  float mean = s * (1.0f / 512.0f);
  float s2 = 0.0f;
#pragma unroll
  for (int j = 0; j < 8; ++j) {
    float d = v[j] - mean;
    s2 += d * d;
  }
  s2 = wave_sum(s2);
  float rstd = 1.0f / sqrtf(s2 * (1.0f / 512.0f) + 1e-5f);
  float gg[8], bv[8];
  *(float4*)&gg[0] = *(const float4*)(g + lane * 8);
  *(float4*)&gg[4] = *(const float4*)(g + lane * 8 + 4);
  *(float4*)&bv[0] = *(const float4*)(b + lane * 8);
  *(float4*)&bv[4] = *(const float4*)(b + lane * 8 + 4);
  float t[8];
#pragma unroll
  for (int j = 0; j < 8; ++j) t[j] = (v[j] - mean) * rstd * gg[j] + bv[j];
  store8_split3(yh, ym, yl, (size_t)row * DMODEL + lane * 8, t);
}

__global__ __launch_bounds__(256) void ln_l2_f32(const float* __restrict__ x,
                                                 const float* __restrict__ g,
                                                 const float* __restrict__ b,
                                                 float* __restrict__ y) {
  const int row = blockIdx.x * 4 + (threadIdx.x >> 6);
  const int lane = threadIdx.x & 63;
  const float* xr = x + (size_t)row * DMODEL;
  float v[8];
  *(float4*)&v[0] = *(const float4*)(xr + lane * 8);
  *(float4*)&v[4] = *(const float4*)(xr + lane * 8 + 4);
  float s = 0.0f;
#pragma unroll
  for (int j = 0; j < 8; ++j) s += v[j];
  s = wave_sum(s);
  float mean = s * (1.0f / 512.0f);
  float s2 = 0.0f;
#pragma unroll
  for (int j = 0; j < 8; ++j) {
    float d = v[j] - mean;
    s2 += d * d;
  }
  s2 = wave_sum(s2);
  float rstd = 1.0f / sqrtf(s2 * (1.0f / 512.0f) + 1e-5f);
  float gg[8], bv[8];
  *(float4*)&gg[0] = *(const float4*)(g + lane * 8);
  *(float4*)&gg[4] = *(const float4*)(g + lane * 8 + 4);
  *(float4*)&bv[0] = *(const float4*)(b + lane * 8);
  *(float4*)&bv[4] = *(const float4*)(b + lane * 8 + 4);
  float t[8];
#pragma unroll
  for (int j = 0; j < 8; ++j) t[j] = (v[j] - mean) * rstd * gg[j] + bv[j];
  float n2 = 0.0f;
#pragma unroll
  for (int j = 0; j < 8; ++j) n2 += t[j] * t[j];
  n2 = wave_sum(n2);
  float den = fmaxf(sqrtf(n2), 1e-12f);
#pragma unroll
  for (int j = 0; j < 8; ++j) t[j] /= den;
  float* yr = y + (size_t)row * DMODEL;
  *(float4*)(yr + lane * 8) = *(float4*)&t[0];
  *(float4*)(yr + lane * 8 + 4) = *(float4*)&t[4];
}

__global__ __launch_bounds__(256) void l2_split3(const float* __restrict__ x,
                                                 u16* __restrict__ yh,
                                                 u16* __restrict__ ym,
                                                 u16* __restrict__ yl) {
  const int row = blockIdx.x * 4 + (threadIdx.x >> 6);
  const int lane = threadIdx.x & 63;
  const float* xr = x + (size_t)row * DMODEL;
  float v[8];
  *(float4*)&v[0] = *(const float4*)(xr + lane * 8);
  *(float4*)&v[4] = *(const float4*)(xr + lane * 8 + 4);
  float n2 = 0.0f;
#pragma unroll
  for (int j = 0; j < 8; ++j) n2 += v[j] * v[j];
  n2 = wave_sum(n2);
  float den = fmaxf(sqrtf(n2), 1e-12f);
#pragma unroll
  for (int j = 0; j < 8; ++j) v[j] /= den;
  store8_split3(yh, ym, yl, (size_t)row * DMODEL + lane * 8, v);
}

__global__ __launch_bounds__(256) void l2_f32(const float* __restrict__ x,
                                              float* __restrict__ y) {
  const int row = blockIdx.x * 4 + (threadIdx.x >> 6);
  const int lane = threadIdx.x & 63;
  const float* xr = x + (size_t)row * DMODEL;
  float v[8];
  *(float4*)&v[0] = *(const float4*)(xr + lane * 8);
  *(float4*)&v[4] = *(const float4*)(xr + lane * 8 + 4);
  float n2 = 0.0f;
#pragma unroll
  for (int j = 0; j < 8; ++j) n2 += v[j] * v[j];
  n2 = wave_sum(n2);
  float den = fmaxf(sqrtf(n2), 1e-12f);
#pragma unroll
  for (int j = 0; j < 8; ++j) v[j] /= den;
  float* yr = y + (size_t)row * DMODEL;
  *(float4*)(yr + lane * 8) = *(float4*)&v[0];
  *(float4*)(yr + lane * 8 + 4) = *(float4*)&v[4];
}

__global__ __launch_bounds__(256) void softmax3(u16* __restrict__ H,
                                                u16* __restrict__ M,
                                                u16* __restrict__ L) {
  const int row = blockIdx.x;
  const int tid = threadIdx.x;
  const size_t base = (size_t)row * 1024 + tid * 4;
  ushort4 qh = *(const ushort4*)&H[base];
  ushort4 qm = *(const ushort4*)&M[base];
  ushort4 ql = *(const ushort4*)&L[base];
  float v0 = bf2f(qh.x) + bf2f(qm.x) + bf2f(ql.x);
  float v1 = bf2f(qh.y) + bf2f(qm.y) + bf2f(ql.y);
  float v2 = bf2f(qh.z) + bf2f(qm.z) + bf2f(ql.z);
  float v3 = bf2f(qh.w) + bf2f(qm.w) + bf2f(ql.w);
  float mx = fmaxf(fmaxf(v0, v1), fmaxf(v2, v3));
#pragma unroll
  for (int off = 1; off < 64; off <<= 1) mx = fmaxf(mx, __shfl_xor(mx, off));
  __shared__ float red[4];
  const int wv = tid >> 6;
  if ((tid & 63) == 0) red[wv] = mx;
  __syncthreads();
  mx = fmaxf(fmaxf(red[0], red[1]), fmaxf(red[2], red[3]));
  float e0 = __expf(v0 - mx), e1 = __expf(v1 - mx), e2 = __expf(v2 - mx),
        e3 = __expf(v3 - mx);
  float s = e0 + e1 + e2 + e3;
#pragma unroll
  for (int off = 1; off < 64; off <<= 1) s += __shfl_xor(s, off);
  __syncthreads();
  if ((tid & 63) == 0) red[wv] = s;
  __syncthreads();
  s = red[0] + red[1] + red[2] + red[3];
  float inv = 1.0f / s;
  u16 ah[4], am[4], al[4];
  split3(e0 * inv, ah[0], am[0], al[0]);
  split3(e1 * inv, ah[1], am[1], al[1]);
  split3(e2 * inv, ah[2], am[2], al[2]);
  split3(e3 * inv, ah[3], am[3], al[3]);
  *(ushort4*)&H[base] = make_ushort4(ah[0], ah[1], ah[2], ah[3]);
  *(ushort4*)&M[base] = make_ushort4(am[0], am[1], am[2], am[3]);
  *(ushort4*)&L[base] = make_ushort4(al[0], al[1], al[2], al[3]);
}

__global__ __launch_bounds__(256) void split3_k(const float* __restrict__ src,
                                                u16* __restrict__ H,
                                                u16* __restrict__ M,
                                                u16* __restrict__ L, int n4) {
  for (int e = blockIdx.x * 256 + threadIdx.x; e < n4; e += gridDim.x * 256) {
    float4 v = *(const float4*)(src + (size_t)e * 4);
    u16 ah[4], am[4], al[4];
    split3(v.x, ah[0], am[0], al[0]);
    split3(v.y, ah[1], am[1], al[1]);
    split3(v.z, ah[2], am[2], al[2]);
    split3(v.w, ah[3], am[3], al[3]);
    *(ushort4*)&H[(size_t)e * 4] = make_ushort4(ah[0], ah[1], ah[2], ah[3]);
    *(ushort4*)&M[(size_t)e * 4] = make_ushort4(am[0], am[1], am[2], am[3]);
    *(ushort4*)&L[(size_t)e * 4] = make_ushort4(al[0], al[1], al[2], al[3]);
  }
}

__global__ __launch_bounds__(256) void tsplit_cb(const float* __restrict__ cb,
                                                 u16* __restrict__ th,
                                                 u16* __restrict__ tm,
                                                 u16* __restrict__ tl) {
  const int c = blockIdx.x;
  const int t = threadIdx.x;
  u16 ah[4], am[4], al[4];
#pragma unroll
  for (int j = 0; j < 4; ++j) {
    float v = cb[(size_t)(4 * t + j) * 512 + c];
    split3(v, ah[j], am[j], al[j]);
  }
  const size_t base = (size_t)c * 1024 + 4 * t;
  *(ushort4*)&th[base] = make_ushort4(ah[0], ah[1], ah[2], ah[3]);
  *(ushort4*)&tm[base] = make_ushort4(am[0], am[1], am[2], am[3]);
  *(ushort4*)&tl[base] = make_ushort4(al[0], al[1], al[2], al[3]);
}

__global__ __launch_bounds__(256) void vq_finalize(
    const float* __restrict__ logits, const float* __restrict__ patterns,
    float* __restrict__ emb, float* __restrict__ assign,
    float* __restrict__ idxf) {
  const int row = blockIdx.x * 4 + (threadIdx.x >> 6);
  const int lane = threadIdx.x & 63;
  const float* lr = logits + (size_t)row * NPAT;
  float best = -__builtin_huge_valf();
  int bi = 0;
#pragma unroll
  for (int jj = 0; jj < 8; ++jj) {
    int j = lane + jj * 64;
    float v = lr[j];
    if (v > best) {
      best = v;
      bi = j;
    }
  }
#pragma unroll
  for (int off = 1; off < 64; off <<= 1) {
    float ob = __shfl_xor(best, off);
    int oi = __shfl_xor(bi, off);
    if (ob > best || (ob == best && oi < bi)) {
      best = ob;
      bi = oi;
    }
  }
  const float* pr = patterns + (size_t)bi * DMODEL;
#pragma unroll
  for (int g = 0; g < 2; ++g) {
    int c = lane * 8 + g * 4;
    float4 pv = *(const float4*)(pr + c);
    *(float4*)(emb + (size_t)row * DMODEL + c) = pv;
    float4 av;
    av.x = (c + 0 == bi) ? 1.0f : 0.0f;
    av.y = (c + 1 == bi) ? 1.0f : 0.0f;
    av.z = (c + 2 == bi) ? 1.0f : 0.0f;
    av.w = (c + 3 == bi) ? 1.0f : 0.0f;
    *(float4*)(assign + (size_t)row * NPAT + c) = av;
  }
  if (lane == 0) idxf[row] = (float)bi;
}

// ---------------- host launch ----------------
extern "C" void kernel_launch(void* const* d_in, const int* in_sizes, int n_in,
                              void* d_out, int out_size, void* d_ws,
                              size_t ws_size, hipStream_t stream) {
  (void)in_sizes;
  (void)n_in;
  (void)out_size;
  (void)ws_size;
  const float* x = (const float*)d_in[0];
  const float* gumbel = (const float*)d_in[1];
  const float* sym_w = (const float*)d_in[2];
  const float* sym_b = (const float*)d_in[3];
  const float* codebook = (const float*)d_in[4];
  const float* pos_enc = (const float*)d_in[5];
  const float* attn_in_w = (const float*)d_in[6];
  const float* attn_in_b = (const float*)d_in[7];
  const float* attn_out_w = (const float*)d_in[8];
  const float* attn_out_b = (const float*)d_in[9];
  const float* n1_g = (const float*)d_in[10];
  const float* n1_b = (const float*)d_in[11];
  const float* n2_g = (const float*)d_in[12];
  const float* n2_b = (const float*)d_in[13];
  const float* ffn_w1 = (const float*)d_in[14];
  const float* ffn_b1 = (const float*)d_in[15];
  const float* ffn_w2 = (const float*)d_in[16];
  const float* ffn_b2 = (const float*)d_in[17];
  const float* q_w = (const float*)d_in[18];
  const float* q_b = (const float*)d_in[19];
  const float* qln_g = (const float*)d_in[20];
  const float* qln_b = (const float*)d_in[21];
  const float* patterns = (const float*)d_in[22];
  const int* epoch = (const int*)d_in[23];
  const int* tot = (const int*)d_in[24];

  float* out = (float*)d_out;
  float* emb = out;               // [8192,512]
  float* assign = out + 4194304;  // [8192,512]
  float* logits = out + 8388608;  // [8192,512]
  float* h = out + 12582912;      // [8192,512]
  float* idxf = out + 16777216;   // [8192]

  float* ws_f = (float*)d_ws;
  // A region @0 (18.87M floats = 37.75M u16)
  u16* a16 = (u16*)ws_f;
  // B region @18.87M floats (6.29M floats = 12.58M u16)
  float* bF = ws_f + 18874368;
  u16* b16 = (u16*)bF;
  u16 *hnH = b16, *hnM = b16 + 4194304, *hnL = b16 + 8388608;
  // W region @25.17M floats (1.18M floats = 2.36M u16)
  float* wF = ws_f + 25165824;
  u16* w16 = (u16*)wF;

  // ---- symbolization ----
  u16 *xH = a16, *xM = a16 + 8388608, *xL = a16 + 16777216;
  split3_k<<<2048, 256, 0, stream>>>(x, xH, xM, xL, 2097152);
  split3_k<<<512, 256, 0, stream>>>(sym_w, w16, w16 + 524288, w16 + 1048576,
                                    131072);
  gemm_mf<E_BIAS><<<512, 256, 0, stream>>>(
      xH, xM, xL, w16, w16 + 524288, w16 + 1048576, sym_b, nullptr, bF,
      nullptr, nullptr, nullptr, 512, 1024, 1024, 1024, 4);
  l2_split3<<<256, 256, 0, stream>>>(codebook, w16, w16 + 524288,
                                     w16 + 1048576);
  u16 *hpH = a16, *hpM = a16 + 4194304, *hpL = a16 + 8388608;
  l2_split3<<<2048, 256, 0, stream>>>(bF, hpH, hpM, hpL);
  u16 *sH = a16 + 12582912, *sM = a16 + 20971520, *sL = a16 + 29360128;
  gemm_mf<E_GUM3><<<1024, 256, 0, stream>>>(
      hpH, hpM, hpL, w16, w16 + 524288, w16 + 1048576, nullptr, gumbel,
      nullptr, sH, sM, sL, 1024, 512, 512, 512, 8);
  softmax3<<<8192, 256, 0, stream>>>(sH, sM, sL);
  tsplit_cb<<<512, 256, 0, stream>>>(codebook, w16, w16 + 524288,
                                     w16 + 1048576);
  gemm_mf<E_POS><<<512, 256, 0, stream>>>(
      sH, sM, sL, w16, w16 + 524288, w16 + 1048576, nullptr, pos_enc, h,
      nullptr, nullptr, nullptr, 512, 1024, 1024, 1024, 4);

  // ---- transformer layers ----
  u16 *qkvH = a16, *qkvM = a16 + 12582912, *qkvL = a16 + 25165824;
  u16* w1p = (u16*)(ws_f + 12582912);
  u16* w2p = (u16*)(ws_f + 14155776);
  u16 *pH = a16, *pM = a16 + 8388608, *pL = a16 + 16777216;

  for (int l = 0; l < 4; ++l) {
    const float* inw = attn_in_w + (size_t)l * 1536 * 512;
    const float* inb = attn_in_b + (size_t)l * 1536;
    const float* outw = attn_out_w + (size_t)l * 512 * 512;
    const float* outb = attn_out_b + (size_t)l * 512;
    const float* w1 = ffn_w1 + (size_t)l * 2048 * 512;
    const float* b1 = ffn_b1 + (size_t)l * 2048;
    const float* w2 = ffn_w2 + (size_t)l * 512 * 2048;
    const float* b2 = ffn_b2 + (size_t)l * 512;

    ln_split3<<<2048, 256, 0, stream>>>(h, n1_g + l * 512, n1_b + l * 512,
                                        hnH, hnM, hnL);
    split3_k<<<1024, 256, 0, stream>>>(inw, w16, w16 + 786432, w16 + 1572864,
                                       196608);
    gemm_mf<E_QKV3><<<1536, 256, 0, stream>>>(
        hnH, hnM, hnL, w16, w16 + 786432, w16 + 1572864, inb, nullptr,
        nullptr, qkvH, qkvM, qkvL, 1536, 512, 512, 512, 12);
    flash_mfma<<<1024, 256, 0, stream>>>(qkvH, qkvM, qkvL, hnH, hnM, hnL);
    split3_k<<<256, 256, 0, stream>>>(outw, w16, w16 + 262144, w16 + 524288,
                                      65536);
    gemm_mf<E_RES><<<512, 256, 0, stream>>>(
        hnH, hnM, hnL, w16, w16 + 262144, w16 + 524288, outb, h, h, nullptr,
        nullptr, nullptr, 512, 512, 512, 512, 4);
    ln_split3<<<2048, 256, 0, stream>>>(h, n2_g + l * 512, n2_b + l * 512,
                                        hnH, hnM, hnL);
    split3_k<<<1024, 256, 0, stream>>>(w1, w1p, w1p + 1048576, w1p + 2097152,
                                       262144);
    split3_k<<<1024, 256, 0, stream>>>(w2, w2p, w2p + 1048576, w2p + 2097152,
                                       262144);
    for (int c = 0; c < 2; ++c) {
      gemm_mf<E_GELU3><<<1024, 256, 0, stream>>>(
          hnH, hnM, hnL, w1p + c * 524288, w1p + 1048576 + c * 524288,
          w1p + 2097152 + c * 524288, b1 + c * 1024, nullptr, nullptr, pH, pM,
          pL, 1024, 512, 512, 512, 8);
      if (c == 0) {
        gemm_mf<E_RES><<<512, 256, 0, stream>>>(
            pH, pM, pL, w2p + 0, w2p + 1048576, w2p + 2097152, b2, h, h,
            nullptr, nullptr, nullptr, 512, 1024, 1024, 2048, 4);
      } else {
        gemm_mf<E_ACC><<<512, 256, 0, stream>>>(
            pH, pM, pL, w2p + 1024, w2p + 1048576 + 1024, w2p + 2097152 + 1024,
            nullptr, nullptr, h, nullptr, nullptr, nullptr, 512, 1024, 1024,
            2048, 4);
      }
    }
  }

  // ---- VQ head (fp32-vector precision anchor) ----
  gemm_f32<64, 128, 32, E_BIAS><<<dim3(4, 128), 256, 0, stream>>>(
      h, q_w, q_b, bF, 8192, 512, 512, nullptr, nullptr);
  ln_l2_f32<<<2048, 256, 0, stream>>>(bF, qln_g, qln_b, bF);
  l2_f32<<<128, 256, 0, stream>>>(patterns, wF);
  gemm_f32<64, 128, 32, E_VQ><<<dim3(4, 128), 256, 0, stream>>>(
      bF, wF, nullptr, logits, 8192, 512, 512, epoch, tot);
  vq_finalize<<<2048, 256, 0, stream>>>(logits, patterns, emb, assign, idxf);
}

// Round 12
// 2602.168 us; speedup vs baseline: 1.1882x; 1.1882x over previous
//
#include <hip/hip_runtime.h>

#define DEV __device__ __forceinline__

typedef unsigned short u16;
typedef unsigned int u32;
typedef __attribute__((ext_vector_type(8))) short bf8_t;   // 8 bf16 (4 VGPR)
typedef __attribute__((ext_vector_type(4))) float f4_t;

constexpr int T_SEQ = 1024;
constexpr int DMODEL = 512;
constexpr int NPAT = 512;

// ---------------- epilogue modes ----------------
enum {
  E_BIAS = 0,
  E_VQ = 5,
  E_RES = 6,
  E_ACC = 7,
  E_POS = 8,
  E_GUM3 = 9,
  E_GELU3 = 10,
  E_QKV3 = 11
};

// ---------------- bf16 triple-split helpers ----------------
DEV u16 f2bf(float x) {
  u32 u = __float_as_uint(x);
  u32 r = u + 0x7FFFu + ((u >> 16) & 1u);
  return (u16)(r >> 16);
}
DEV float bf2f(u16 h) { return __uint_as_float((u32)h << 16); }
DEV void split3(float x, u16& h, u16& m, u16& l) {
  h = f2bf(x);
  float r1 = x - bf2f(h);
  m = f2bf(r1);
  float r2 = r1 - bf2f(m);
  l = f2bf(r2);
}

DEV f4_t mf16(bf8_t a, bf8_t b, f4_t c) {
  return __builtin_amdgcn_mfma_f32_16x16x32_bf16(a, b, c, 0, 0, 0);
}
// 6-product triple-split accumulate (err ~2^-24)
DEV f4_t prod6(bf8_t ah, bf8_t am, bf8_t al, bf8_t bh, bf8_t bm, bf8_t bl,
               f4_t c) {
  c = mf16(ah, bh, c);
  c = mf16(ah, bm, c);
  c = mf16(am, bh, c);
  c = mf16(ah, bl, c);
  c = mf16(am, bm, c);
  c = mf16(al, bh, c);
  return c;
}

// async global->LDS, 16B per lane; LDS dest = base + lane*16 (wave-uniform base)
typedef const __attribute__((address_space(1))) unsigned char* gas_t;
typedef __attribute__((address_space(3))) unsigned char* las_t;
DEV void gload16(const u16* g, u16* l) {
  __builtin_amdgcn_global_load_lds((gas_t)(const void*)g, (las_t)(void*)l, 16,
                                   0, 0);
}

// ---------------- MFMA GEMM, triple-bf16 split (fp32-accurate) ---------------
// C[M,N] = A[M,K]*B[N,K]^T via 6 bf16 products. Verified R6-R10.
// 2-phase prefetch: STAGE(t+1 -> buf^1) issued BEFORE compute(buf); single
// __syncthreads()/iter. BM=64, BN=128, LDS dbuf 72KB -> 2 blocks/CU.
// 1-D grid + bijective XCD swizzle.
template <int EPI>
__global__ __launch_bounds__(256, 2) void gemm_mf(
    const u16* __restrict__ Ah, const u16* __restrict__ Am,
    const u16* __restrict__ Al, const u16* __restrict__ Bh,
    const u16* __restrict__ Bm, const u16* __restrict__ Bl,
    const float* __restrict__ bias, const float* __restrict__ res,
    float* __restrict__ Cf, u16* __restrict__ Ch, u16* __restrict__ Cm,
    u16* __restrict__ Cl, int N, int KK, int lda, int ldb, int gx) {
  constexpr int BM = 64;
  constexpr int MT = 2;  // m-tiles per wave
  __shared__ __align__(16) u16 AsH[2][BM][4][8], AsM[2][BM][4][8],
      AsL[2][BM][4][8];
  __shared__ __align__(16) u16 BsH[2][128][4][8], BsM[2][128][4][8],
      BsL[2][128][4][8];
  const int tid = threadIdx.x;
  const int w = tid >> 6, lane = tid & 63;
  const int wy = w >> 1, wx = w & 1;
  const int lr = lane & 15, lg = lane >> 4;

  // bijective XCD swizzle (all grids divisible by 8)
  const int nwg = gridDim.x;
  const int bid = blockIdx.x;
  const int qq = nwg >> 3;
  const int wg = (bid & 7) * qq + (bid >> 3);
  const int by = wg / gx, bx = wg % gx;
  const int bm = by * BM, bn = bx * 128;

  const int rowl = lane >> 2, slot4 = lane & 3;  // per-lane stage coords

  auto STAGE = [&](int k0, int buf) {
#pragma unroll
    for (int it = 0; it < 3; ++it) {  // A: 12 chunks (3 planes x 4)
      const int f = w + 4 * it;
      const int plane = f >> 2;
      const int ch = f & 3;
      const int row = ch * 16 + rowl;
      const int kp = slot4 ^ ((row >> 1) & 3);
      const size_t g = (size_t)(bm + row) * lda + k0 + kp * 8;
      if (plane == 0)
        gload16(&Ah[g], &AsH[buf][0][0][0] + ch * 512);
      else if (plane == 1)
        gload16(&Am[g], &AsM[buf][0][0][0] + ch * 512);
      else
        gload16(&Al[g], &AsL[buf][0][0][0] + ch * 512);
    }
#pragma unroll
    for (int it = 0; it < 6; ++it) {  // B: 24 chunks (3 planes x 8)
      const int f = w + 4 * it;
      const int plane = f >> 3;
      const int ch = f & 7;
      const int row = ch * 16 + rowl;
      const int kp = slot4 ^ ((row >> 1) & 3);
      const size_t g = (size_t)(bn + row) * ldb + k0 + kp * 8;
      if (plane == 0)
        gload16(&Bh[g], &BsH[buf][0][0][0] + ch * 512);
      else if (plane == 1)
        gload16(&Bm[g], &BsM[buf][0][0][0] + ch * 512);
      else
        gload16(&Bl[g], &BsL[buf][0][0][0] + ch * 512);
    }
  };

  f4_t acc[MT][4];
#pragma unroll
  for (int mt = 0; mt < MT; ++mt)
#pragma unroll
    for (int nt = 0; nt < 4; ++nt) acc[mt][nt] = (f4_t){0.f, 0.f, 0.f, 0.f};

  const int nsteps = KK / 32;
  STAGE(0, 0);
  __syncthreads();
  for (int t = 0; t < nsteps; ++t) {
    const int cur = t & 1;
    if (t + 1 < nsteps) STAGE((t + 1) * 32, cur ^ 1);

    bf8_t fah[MT], fam[MT], fal[MT], fbh[4], fbm[4], fbl[4];
#pragma unroll
    for (int mt = 0; mt < MT; ++mt) {
      int row = wy * 32 + mt * 16 + lr;
      int slot = lg ^ ((row >> 1) & 3);
      fah[mt] = *(const bf8_t*)&AsH[cur][row][slot][0];
      fam[mt] = *(const bf8_t*)&AsM[cur][row][slot][0];
      fal[mt] = *(const bf8_t*)&AsL[cur][row][slot][0];
    }
#pragma unroll
    for (int nt = 0; nt < 4; ++nt) {
      int col = wx * 64 + nt * 16 + lr;
      int slot = lg ^ ((col >> 1) & 3);
      fbh[nt] = *(const bf8_t*)&BsH[cur][col][slot][0];
      fbm[nt] = *(const bf8_t*)&BsM[cur][col][slot][0];
      fbl[nt] = *(const bf8_t*)&BsL[cur][col][slot][0];
    }
#pragma unroll
    for (int mt = 0; mt < MT; ++mt)
#pragma unroll
      for (int nt = 0; nt < 4; ++nt)
        acc[mt][nt] = prod6(fah[mt], fam[mt], fal[mt], fbh[nt], fbm[nt],
                            fbl[nt], acc[mt][nt]);
    __syncthreads();
  }

  // ---- epilogue (C frag: col = lane&15, row = 4*(lane>>4)+i) ----
  float bv[4];
  if constexpr (EPI == E_BIAS || EPI == E_RES || EPI == E_GELU3 ||
                EPI == E_QKV3) {
#pragma unroll
    for (int nt = 0; nt < 4; ++nt) bv[nt] = bias[bn + wx * 64 + nt * 16 + lr];
  }
#pragma unroll
  for (int mt = 0; mt < MT; ++mt)
#pragma unroll
    for (int nt = 0; nt < 4; ++nt) {
      const int c = bn + wx * 64 + nt * 16 + lr;
#pragma unroll
      for (int i = 0; i < 4; ++i) {
        const int m = bm + wy * 32 + mt * 16 + 4 * lg + i;
        const size_t idx = (size_t)m * N + c;
        float v = acc[mt][nt][i];
        if constexpr (EPI == E_BIAS) {
          Cf[idx] = v + bv[nt];
        } else if constexpr (EPI == E_RES) {
          Cf[idx] = v + bv[nt] + res[idx];
        } else if constexpr (EPI == E_ACC) {
          Cf[idx] += v;
        } else if constexpr (EPI == E_POS) {
          Cf[idx] = v + res[(size_t)(m & 1023) * N + c];
        } else if constexpr (EPI == E_GUM3) {
          float t = 4.0f * v + 2.0f * res[idx];
          u16 h2, m2, l2;
          split3(t, h2, m2, l2);
          Ch[idx] = h2;
          Cm[idx] = m2;
          Cl[idx] = l2;
        } else if constexpr (EPI == E_GELU3) {
          float t = v + bv[nt];
          float g = 0.5f * t * (1.0f + erff(t * 0.7071067811865476f));
          u16 h2, m2, l2;
          split3(g, h2, m2, l2);
          Ch[idx] = h2;
          Cm[idx] = m2;
          Cl[idx] = l2;
        } else if constexpr (EPI == E_QKV3) {
          float t = v + bv[nt];
          u16 h2, m2, l2;
          split3(t, h2, m2, l2);
          size_t o;
          if (c < 512) {
            o = (size_t)m * 512 + c;                       // Q [B,T,512]
          } else if (c < 1024) {
            o = 4194304 + (size_t)m * 512 + (c - 512);     // K [B,T,512]
          } else {
            int cc = c - 1024, hh2 = cc >> 6, dd = cc & 63;
            int bb2 = m >> 10, tt = m & 1023;
            o = 8388608 +
                (((size_t)(bb2 * 8 + hh2) * 64 + dd) << 10) + tt;  // Vt
          }
          Ch[o] = h2;
          Cm[o] = m2;
          Cl[o] = l2;
        }
      }
    }
}

// ---------------- MFMA flash attention (triple-split, fp32-grade) ------------
// 1-D grid 1024, XCD-swizzled: b = bid&7 so each XCD owns one batch's K/V
// (~6.3MB, L2-resident; R11 measured FETCH 209->75MB). Staging via
// global_load_lds (R10-proven, no register pressure). 4 waves, each owns 16
// q-rows of a 64-row q-tile. P aliases the K tile (dead after QK^T): LDS 48KB
// -> 3 blocks/CU.
__global__ __launch_bounds__(256) void flash_mfma(
    const u16* __restrict__ QKVh, const u16* __restrict__ QKVm,
    const u16* __restrict__ QKVl, u16* __restrict__ Oh, u16* __restrict__ Om,
    u16* __restrict__ Ol) {
  __shared__ __align__(16) u16 KP[3][64][8][8];  // K tile, then P tile
  __shared__ __align__(16) u16 Vs[3][64][8][8];
  const int tid = threadIdx.x;
  const int w = tid >> 6, lane = tid & 63;
  const int lr = lane & 15, lg = lane >> 4;
  // XCD swizzle: bid&7 -> XCD; slot covers (hh, qt) for batch b
  const int bid = blockIdx.x;
  const int b = bid & 7;
  const int slot_b = bid >> 3;      // 0..127
  const int hh = slot_b >> 4;       // 0..7
  const int qt = slot_b & 15;       // 0..15

  const u16* Qh = QKVh;
  const u16* Qm = QKVm;
  const u16* Ql = QKVl;
  const u16* Kh = QKVh + 4194304;
  const u16* Km = QKVm + 4194304;
  const u16* Kl = QKVl + 4194304;
  const u16* Vh = QKVh + 8388608;
  const u16* Vm = QKVm + 8388608;
  const u16* Vl = QKVl + 8388608;

  // Q fragments (A-op: m = lr, k-packet = lg), hoisted for all kt
  bf8_t qf[2][3];
  {
    size_t g =
        ((size_t)(b * 1024 + qt * 64 + w * 16 + lr)) * 512 + hh * 64 + lg * 8;
    qf[0][0] = *(const bf8_t*)&Qh[g];
    qf[0][1] = *(const bf8_t*)&Qm[g];
    qf[0][2] = *(const bf8_t*)&Ql[g];
    qf[1][0] = *(const bf8_t*)&Qh[g + 32];
    qf[1][1] = *(const bf8_t*)&Qm[g + 32];
    qf[1][2] = *(const bf8_t*)&Ql[g + 32];
  }

  f4_t oacc[4];
#pragma unroll
  for (int nt = 0; nt < 4; ++nt) oacc[nt] = (f4_t){0.f, 0.f, 0.f, 0.f};
  float mrun[4], lrun[4];
#pragma unroll
  for (int i = 0; i < 4; ++i) {
    mrun[i] = -__builtin_huge_valf();
    lrun[i] = 0.0f;
  }

  const int rowl8 = lane >> 3, slot8 = lane & 7;  // stage coords (8 rows/chunk)

  for (int kt = 0; kt < 16; ++kt) {
    __syncthreads();  // prior PV done reading Vs + KP(P)
    // ---- stage K tile + Vt tile via global_load_lds: 48 x 1KB chunks ----
#pragma unroll
    for (int it = 0; it < 6; ++it) {
      const int f = w + 4 * it;
      const int plane = f >> 3, ch = f & 7;
      const int row = ch * 8 + rowl8;
      const int kp = slot8 ^ (row & 7);
      const size_t gk =
          ((size_t)(b * 1024 + kt * 64 + row)) * 512 + hh * 64 + kp * 8;
      if (plane == 0)
        gload16(&Kh[gk], &KP[0][0][0][0] + ch * 512);
      else if (plane == 1)
        gload16(&Km[gk], &KP[1][0][0][0] + ch * 512);
      else
        gload16(&Kl[gk], &KP[2][0][0][0] + ch * 512);
    }
#pragma unroll
    for (int it = 0; it < 6; ++it) {
      const int f = w + 4 * it;
      const int plane = f >> 3, ch = f & 7;
      const int row = ch * 8 + rowl8;
      const int kp = slot8 ^ (row & 7);
      const size_t gv =
          ((size_t)((b * 8 + hh) * 64 + row)) * 1024 + kt * 64 + kp * 8;
      if (plane == 0)
        gload16(&Vh[gv], &Vs[0][0][0][0] + ch * 512);
      else if (plane == 1)
        gload16(&Vm[gv], &Vs[1][0][0][0] + ch * 512);
      else
        gload16(&Vl[gv], &Vs[2][0][0][0] + ch * 512);
    }
    __syncthreads();

    // ---- S = Q K^T : 4 n-tiles x 2 k-slices x 6 products ----
    f4_t s[4];
#pragma unroll
    for (int nt = 0; nt < 4; ++nt) {
      s[nt] = (f4_t){0.f, 0.f, 0.f, 0.f};
      const int col = nt * 16 + lr;
#pragma unroll
      for (int ks = 0; ks < 2; ++ks) {
        int slt = (ks * 4 + lg) ^ (col & 7);
        bf8_t kh = *(const bf8_t*)&KP[0][col][slt][0];
        bf8_t km = *(const bf8_t*)&KP[1][col][slt][0];
        bf8_t kl = *(const bf8_t*)&KP[2][col][slt][0];
        s[nt] = prod6(qf[ks][0], qf[ks][1], qf[ks][2], kh, km, kl, s[nt]);
      }
    }

    // ---- online softmax (row = 4*lg+i; reduce over lr via shfl) ----
#pragma unroll
    for (int i = 0; i < 4; ++i) {
      float rm = -__builtin_huge_valf();
#pragma unroll
      for (int nt = 0; nt < 4; ++nt) {
        s[nt][i] *= 0.125f;
        rm = fmaxf(rm, s[nt][i]);
      }
      rm = fmaxf(rm, __shfl_xor(rm, 1));
      rm = fmaxf(rm, __shfl_xor(rm, 2));
      rm = fmaxf(rm, __shfl_xor(rm, 4));
      rm = fmaxf(rm, __shfl_xor(rm, 8));
      float mnew = fmaxf(mrun[i], rm);
      float alpha = __expf(mrun[i] - mnew);
      float rs = 0.0f;
#pragma unroll
      for (int nt = 0; nt < 4; ++nt) {
        float p = __expf(s[nt][i] - mnew);
        s[nt][i] = p;
        rs += p;
      }
      rs += __shfl_xor(rs, 1);
      rs += __shfl_xor(rs, 2);
      rs += __shfl_xor(rs, 4);
      rs += __shfl_xor(rs, 8);
      lrun[i] = lrun[i] * alpha + rs;
      mrun[i] = mnew;
#pragma unroll
      for (int nt = 0; nt < 4; ++nt) oacc[nt][i] *= alpha;
    }

    __syncthreads();  // all waves done reading K tile -> safe to overwrite

    // ---- P -> KP (wave-private rows, 3 planes, swizzled) ----
#pragma unroll
    for (int nt = 0; nt < 4; ++nt)
#pragma unroll
      for (int i = 0; i < 4; ++i) {
        int qrow = w * 16 + 4 * lg + i;
        int kv = nt * 16 + lr;
        int kp = kv >> 3, j = kv & 7;
        int slt = kp ^ (qrow & 7);
        u16 h2, m2, l2;
        split3(s[nt][i], h2, m2, l2);
        KP[0][qrow][slt][j] = h2;
        KP[1][qrow][slt][j] = m2;
        KP[2][qrow][slt][j] = l2;
      }

    // ---- O += P V (A = own P rows, B = Vt cols) ----
    bf8_t pf[2][3];
#pragma unroll
    for (int ks = 0; ks < 2; ++ks) {
      int row = w * 16 + lr;
      int slt = (ks * 4 + lg) ^ (row & 7);
      pf[ks][0] = *(const bf8_t*)&KP[0][row][slt][0];
      pf[ks][1] = *(const bf8_t*)&KP[1][row][slt][0];
      pf[ks][2] = *(const bf8_t*)&KP[2][row][slt][0];
    }
#pragma unroll
    for (int ntd = 0; ntd < 4; ++ntd) {
      const int col = ntd * 16 + lr;
#pragma unroll
      for (int ks = 0; ks < 2; ++ks) {
        int slt = (ks * 4 + lg) ^ (col & 7);
        bf8_t vh = *(const bf8_t*)&Vs[0][col][slt][0];
        bf8_t vm = *(const bf8_t*)&Vs[1][col][slt][0];
        bf8_t vl = *(const bf8_t*)&Vs[2][col][slt][0];
        oacc[ntd] =
            prod6(pf[ks][0], pf[ks][1], pf[ks][2], vh, vm, vl, oacc[ntd]);
      }
    }
  }

  // ---- epilogue: normalize, split3, store planes [B,T,512] ----
#pragma unroll
  for (int i = 0; i < 4; ++i) {
    float inv = 1.0f / lrun[i];
    int t = qt * 64 + w * 16 + 4 * lg + i;
#pragma unroll
    for (int ntd = 0; ntd < 4; ++ntd) {
      int d = hh * 64 + ntd * 16 + lr;
      size_t idx = ((size_t)(b * 1024 + t)) * 512 + d;
      u16 h2, m2, l2;
      split3(oacc[ntd][i] * inv, h2, m2, l2);
      Oh[idx] = h2;
      Om[idx] = m2;
      Ol[idx] = l2;
    }
  }
}

// ---------------- fp32 vector GEMM (VQ-head precision anchor) ----------------
template <int BM, int BN, int WR, int EPI>
__global__ __launch_bounds__((BM / WR) * (BN / 64) * 64) void gemm_f32(
    const float* __restrict__ A, const float* __restrict__ Bmat,
    const float* __restrict__ bias, float* __restrict__ C, int M, int N, int K,
    const int* __restrict__ ep, const int* __restrict__ tot) {
  constexpr int BK = 16;
  constexpr int WN = BN / 64;
  constexpr int NW = (BM / WR) * WN;
  constexpr int NT = NW * 64;
  constexpr int RM = WR / 8;
  __shared__ __align__(16) float As[BK][BM + 4];
  __shared__ __align__(16) float Bs[BK][BN + 4];
  const int tid = threadIdx.x;
  const int w = tid >> 6, lane = tid & 63;
  const int wy = w / WN, wx = w % WN;
  const int ly = lane >> 3, lx = lane & 7;
  const int bm = blockIdx.y * BM;
  const int bn = blockIdx.x * BN;
  const int rbase = wy * WR + ly * RM;

  float acc[RM][8];
#pragma unroll
  for (int i = 0; i < RM; ++i)
#pragma unroll
    for (int j = 0; j < 8; ++j) acc[i][j] = 0.0f;

  for (int k0 = 0; k0 < K; k0 += BK) {
#pragma unroll
    for (int i = 0; i < (BM * BK / 4) / NT; ++i) {
      int idx = tid + i * NT;
      int r = idx >> 2, c4 = (idx & 3) << 2;
      const float4 v = *(const float4*)(A + (size_t)(bm + r) * K + k0 + c4);
      As[c4 + 0][r] = v.x;
      As[c4 + 1][r] = v.y;
      As[c4 + 2][r] = v.z;
      As[c4 + 3][r] = v.w;
    }
#pragma unroll
    for (int i = 0; i < (BN * BK / 4) / NT; ++i) {
      int idx = tid + i * NT;
      int r = idx >> 2, c4 = (idx & 3) << 2;
      const float4 v = *(const float4*)(Bmat + (size_t)(bn + r) * K + k0 + c4);
      Bs[c4 + 0][r] = v.x;
      Bs[c4 + 1][r] = v.y;
      Bs[c4 + 2][r] = v.z;
      Bs[c4 + 3][r] = v.w;
    }
    __syncthreads();
#pragma unroll
    for (int k = 0; k < BK; ++k) {
      float a[RM], b[8];
#pragma unroll
      for (int r4 = 0; r4 < RM; r4 += 4)
        *(float4*)&a[r4] = *(const float4*)&As[k][rbase + r4];
      *(float4*)&b[0] = *(const float4*)&Bs[k][wx * 64 + lx * 8];
      *(float4*)&b[4] = *(const float4*)&Bs[k][wx * 64 + lx * 8 + 4];
#pragma unroll
      for (int i = 0; i < RM; ++i)
#pragma unroll
        for (int j = 0; j < 8; ++j) acc[i][j] = fmaf(a[i], b[j], acc[i][j]);
    }
    __syncthreads();
  }

  const int ncol = bn + wx * 64 + lx * 8;
  float bb[8];
  if constexpr (EPI == E_BIAS) {
    *(float4*)&bb[0] = *(const float4*)(bias + ncol);
    *(float4*)&bb[4] = *(const float4*)(bias + ncol + 4);
  }
  float invt = 1.0f;
  if constexpr (EPI == E_VQ) {
    float t = 1.0f - 0.5f * (float)ep[0] / (float)tot[0];
    invt = 1.0f / fmaxf(0.5f, t);
  }
#pragma unroll
  for (int i = 0; i < RM; ++i) {
    const int m = bm + rbase + i;
    float o[8];
#pragma unroll
    for (int j = 0; j < 8; ++j) o[j] = acc[i][j];
    if constexpr (EPI == E_BIAS) {
#pragma unroll
      for (int j = 0; j < 8; ++j) o[j] += bb[j];
    } else if constexpr (EPI == E_VQ) {
#pragma unroll
      for (int j = 0; j < 8; ++j) o[j] *= invt;
    }
    *(float4*)(C + (size_t)m * N + ncol) = *(float4*)&o[0];
    *(float4*)(C + (size_t)m * N + ncol + 4) = *(float4*)&o[4];
  }
}

// ---------------- row kernels ----------------
DEV float wave_sum(float v) {
#pragma unroll
  for (int off = 1; off < 64; off <<= 1) v += __shfl_xor(v, off);
  return v;
}

DEV void store8_split3(u16* H, u16* M, u16* L, size_t base, const float* t) {
  u16 vh[8], vm[8], vl[8];
#pragma unroll
  for (int j = 0; j < 8; ++j) split3(t[j], vh[j], vm[j], vl[j]);
  *(ushort4*)&H[base] = make_ushort4(vh[0], vh[1], vh[2], vh[3]);
  *(ushort4*)&H[base + 4] = make_ushort4(vh[4], vh[5], vh[6], vh[7]);
  *(ushort4*)&M[base] = make_ushort4(vm[0], vm[1], vm[2], vm[3]);
  *(ushort4*)&M[base + 4] = make_ushort4(vm[4], vm[5], vm[6], vm[7]);
  *(ushort4*)&L[base] = make_ushort4(vl[0], vl[1], vl[2], vl[3]);
  *(ushort4*)&L[base + 4] = make_ushort4(vl[4], vl[5], vl[6], vl[7]);
}

__global__ __launch_bounds__(256) void ln_split3(const float* __restrict__ x,
                                                 const float* __restrict__ g,
                                                 const float* __restrict__ b,
                                                 u16* __restrict__ yh,
                                                 u16* __restrict__ ym,
                                                 u16* __restrict__ yl) {
  const int row = blockIdx.x * 4 + (threadIdx.x >> 6);
  const int lane = threadIdx.x & 63;
  const float* xr = x + (size_t)row * DMODEL;
  float v[8];
  *(float4*)&v[0] = *(const float4*)(xr + lane * 8);
  *(float4*)&v[4] = *(const float4*)(xr + lane * 8 + 4);
  float s = 0.0f;
#pragma unroll
  for (int j = 0; j < 8; ++j) s += v[j];
  s = wave_sum(s);
  float mean = s * (1.0f / 512.0f);
  float s2 = 0.0f;
#pragma unroll
  for (int j = 0; j < 8; ++j) {
    float d = v[j] - mean;
    s2 += d * d;
  }
  s2 = wave_sum(s2);
  float rstd = 1.0f / sqrtf(s2 * (1.0f / 512.0f) + 1e-5f);
  float gg[8], bv[8];
  *(float4*)&gg[0] = *(const float4*)(g + lane * 8);
  *(float4*)&gg[4] = *(const float4*)(g + lane * 8 + 4);
  *(float4*)&bv[0] = *(const float4*)(b + lane * 8);
  *(float4*)&bv[4] = *(const float4*)(b + lane * 8 + 4);
  float t[8];
#pragma unroll
  for (int j = 0; j < 8; ++j) t[j] = (v[j] - mean) * rstd * gg[j] + bv[j];
  store8_split3(yh, ym, yl, (size_t)row * DMODEL + lane * 8, t);
}

__global__ __launch_bounds__(256) void ln_l2_f32(const float* __restrict__ x,
                                                 const float* __restrict__ g,
                                                 const float* __restrict__ b,
                                                 float* __restrict__ y) {
  const int row = blockIdx.x * 4 + (threadIdx.x >> 6);
  const int lane = threadIdx.x & 63;
  const float* xr = x + (size_t)row * DMODEL;
  float v[8];
  *(float4*)&v[0] = *(const float4*)(xr + lane * 8);
  *(float4*)&v[4] = *(const float4*)(xr + lane * 8 + 4);
  float s = 0.0f;
#pragma unroll
  for (int j = 0; j < 8; ++j) s += v[j];
  s = wave_sum(s);
  float mean = s * (1.0f / 512.0f);
  float s2 = 0.0f;
#pragma unroll
  for (int j = 0; j < 8; ++j) {
    float d = v[j] - mean;
    s2 += d * d;
  }
  s2 = wave_sum(s2);
  float rstd = 1.0f / sqrtf(s2 * (1.0f / 512.0f) + 1e-5f);
  float gg[8], bv[8];
  *(float4*)&gg[0] = *(const float4*)(g + lane * 8);
  *(float4*)&gg[4] = *(const float4*)(g + lane * 8 + 4);
  *(float4*)&bv[0] = *(const float4*)(b + lane * 8);
  *(float4*)&bv[4] = *(const float4*)(b + lane * 8 + 4);
  float t[8];
#pragma unroll
  for (int j = 0; j < 8; ++j) t[j] = (v[j] - mean) * rstd * gg[j] + bv[j];
  float n2 = 0.0f;
#pragma unroll
  for (int j = 0; j < 8; ++j) n2 += t[j] * t[j];
  n2 = wave_sum(n2);
  float den = fmaxf(sqrtf(n2), 1e-12f);
#pragma unroll
  for (int j = 0; j < 8; ++j) t[j] /= den;
  float* yr = y + (size_t)row * DMODEL;
  *(float4*)(yr + lane * 8) = *(float4*)&t[0];
  *(float4*)(yr + lane * 8 + 4) = *(float4*)&t[4];
}

__global__ __launch_bounds__(256) void l2_split3(const float* __restrict__ x,
                                                 u16* __restrict__ yh,
                                                 u16* __restrict__ ym,
                                                 u16* __restrict__ yl) {
  const int row = blockIdx.x * 4 + (threadIdx.x >> 6);
  const int lane = threadIdx.x & 63;
  const float* xr = x + (size_t)row * DMODEL;
  float v[8];
  *(float4*)&v[0] = *(const float4*)(xr + lane * 8);
  *(float4*)&v[4] = *(const float4*)(xr + lane * 8 + 4);
  float n2 = 0.0f;
#pragma unroll
  for (int j = 0; j < 8; ++j) n2 += v[j] * v[j];
  n2 = wave_sum(n2);
  float den = fmaxf(sqrtf(n2), 1e-12f);
#pragma unroll
  for (int j = 0; j < 8; ++j) v[j] /= den;
  store8_split3(yh, ym, yl, (size_t)row * DMODEL + lane * 8, v);
}

__global__ __launch_bounds__(256) void l2_f32(const float* __restrict__ x,
                                              float* __restrict__ y) {
  const int row = blockIdx.x * 4 + (threadIdx.x >> 6);
  const int lane = threadIdx.x & 63;
  const float* xr = x + (size_t)row * DMODEL;
  float v[8];
  *(float4*)&v[0] = *(const float4*)(xr + lane * 8);
  *(float4*)&v[4] = *(const float4*)(xr + lane * 8 + 4);
  float n2 = 0.0f;
#pragma unroll
  for (int j = 0; j < 8; ++j) n2 += v[j] * v[j];
  n2 = wave_sum(n2);
  float den = fmaxf(sqrtf(n2), 1e-12f);
#pragma unroll
  for (int j = 0; j < 8; ++j) v[j] /= den;
  float* yr = y + (size_t)row * DMODEL;
  *(float4*)(yr + lane * 8) = *(float4*)&v[0];
  *(float4*)(yr + lane * 8 + 4) = *(float4*)&v[4];
}

__global__ __launch_bounds__(256) void softmax3(u16* __restrict__ H,
                                                u16* __restrict__ M,
                                                u16* __restrict__ L) {
  const int row = blockIdx.x;
  const int tid = threadIdx.x;
  const size_t base = (size_t)row * 1024 + tid * 4;
  ushort4 qh = *(const ushort4*)&H[base];
  ushort4 qm = *(const ushort4*)&M[base];
  ushort4 ql = *(const ushort4*)&L[base];
  float v0 = bf2f(qh.x) + bf2f(qm.x) + bf2f(ql.x);
  float v1 = bf2f(qh.y) + bf2f(qm.y) + bf2f(ql.y);
  float v2 = bf2f(qh.z) + bf2f(qm.z) + bf2f(ql.z);
  float v3 = bf2f(qh.w) + bf2f(qm.w) + bf2f(ql.w);
  float mx = fmaxf(fmaxf(v0, v1), fmaxf(v2, v3));
#pragma unroll
  for (int off = 1; off < 64; off <<= 1) mx = fmaxf(mx, __shfl_xor(mx, off));
  __shared__ float red[4];
  const int wv = tid >> 6;
  if ((tid & 63) == 0) red[wv] = mx;
  __syncthreads();
  mx = fmaxf(fmaxf(red[0], red[1]), fmaxf(red[2], red[3]));
  float e0 = __expf(v0 - mx), e1 = __expf(v1 - mx), e2 = __expf(v2 - mx),
        e3 = __expf(v3 - mx);
  float s = e0 + e1 + e2 + e3;
#pragma unroll
  for (int off = 1; off < 64; off <<= 1) s += __shfl_xor(s, off);
  __syncthreads();
  if ((tid & 63) == 0) red[wv] = s;
  __syncthreads();
  s = red[0] + red[1] + red[2] + red[3];
  float inv = 1.0f / s;
  u16 ah[4], am[4], al[4];
  split3(e0 * inv, ah[0], am[0], al[0]);
  split3(e1 * inv, ah[1], am[1], al[1]);
  split3(e2 * inv, ah[2], am[2], al[2]);
  split3(e3 * inv, ah[3], am[3], al[3]);
  *(ushort4*)&H[base] = make_ushort4(ah[0], ah[1], ah[2], ah[3]);
  *(ushort4*)&M[base] = make_ushort4(am[0], am[1], am[2], am[3]);
  *(ushort4*)&L[base] = make_ushort4(al[0], al[1], al[2], al[3]);
}

__global__ __launch_bounds__(256) void split3_k(const float* __restrict__ src,
                                                u16* __restrict__ H,
                                                u16* __restrict__ M,
                                                u16* __restrict__ L, int n4) {
  for (int e = blockIdx.x * 256 + threadIdx.x; e < n4; e += gridDim.x * 256) {
    float4 v = *(const float4*)(src + (size_t)e * 4);
    u16 ah[4], am[4], al[4];
    split3(v.x, ah[0], am[0], al[0]);
    split3(v.y, ah[1], am[1], al[1]);
    split3(v.z, ah[2], am[2], al[2]);
    split3(v.w, ah[3], am[3], al[3]);
    *(ushort4*)&H[(size_t)e * 4] = make_ushort4(ah[0], ah[1], ah[2], ah[3]);
    *(ushort4*)&M[(size_t)e * 4] = make_ushort4(am[0], am[1], am[2], am[3]);
    *(ushort4*)&L[(size_t)e * 4] = make_ushort4(al[0], al[1], al[2], al[3]);
  }
}

__global__ __launch_bounds__(256) void tsplit_cb(const float* __restrict__ cb,
                                                 u16* __restrict__ th,
                                                 u16* __restrict__ tm,
                                                 u16* __restrict__ tl) {
  const int c = blockIdx.x;
  const int t = threadIdx.x;
  u16 ah[4], am[4], al[4];
#pragma unroll
  for (int j = 0; j < 4; ++j) {
    float v = cb[(size_t)(4 * t + j) * 512 + c];
    split3(v, ah[j], am[j], al[j]);
  }
  const size_t base = (size_t)c * 1024 + 4 * t;
  *(ushort4*)&th[base] = make_ushort4(ah[0], ah[1], ah[2], ah[3]);
  *(ushort4*)&tm[base] = make_ushort4(am[0], am[1], am[2], am[3]);
  *(ushort4*)&tl[base] = make_ushort4(al[0], al[1], al[2], al[3]);
}

__global__ __launch_bounds__(256) void vq_finalize(
    const float* __restrict__ logits, const float* __restrict__ patterns,
    float* __restrict__ emb, float* __restrict__ assign,
    float* __restrict__ idxf) {
  const int row = blockIdx.x * 4 + (threadIdx.x >> 6);
  const int lane = threadIdx.x & 63;
  const float* lr = logits + (size_t)row * NPAT;
  float best = -__builtin_huge_valf();
  int bi = 0;
#pragma unroll
  for (int jj = 0; jj < 8; ++jj) {
    int j = lane + jj * 64;
    float v = lr[j];
    if (v > best) {
      best = v;
      bi = j;
    }
  }
#pragma unroll
  for (int off = 1; off < 64; off <<= 1) {
    float ob = __shfl_xor(best, off);
    int oi = __shfl_xor(bi, off);
    if (ob > best || (ob == best && oi < bi)) {
      best = ob;
      bi = oi;
    }
  }
  const float* pr = patterns + (size_t)bi * DMODEL;
#pragma unroll
  for (int g = 0; g < 2; ++g) {
    int c = lane * 8 + g * 4;
    float4 pv = *(const float4*)(pr + c);
    *(float4*)(emb + (size_t)row * DMODEL + c) = pv;
    float4 av;
    av.x = (c + 0 == bi) ? 1.0f : 0.0f;
    av.y = (c + 1 == bi) ? 1.0f : 0.0f;
    av.z = (c + 2 == bi) ? 1.0f : 0.0f;
    av.w = (c + 3 == bi) ? 1.0f : 0.0f;
    *(float4*)(assign + (size_t)row * NPAT + c) = av;
  }
  if (lane == 0) idxf[row] = (float)bi;
}

// ---------------- host launch ----------------
extern "C" void kernel_launch(void* const* d_in, const int* in_sizes, int n_in,
                              void* d_out, int out_size, void* d_ws,
                              size_t ws_size, hipStream_t stream) {
  (void)in_sizes;
  (void)n_in;
  (void)out_size;
  (void)ws_size;
  const float* x = (const float*)d_in[0];
  const float* gumbel = (const float*)d_in[1];
  const float* sym_w = (const float*)d_in[2];
  const float* sym_b = (const float*)d_in[3];
  const float* codebook = (const float*)d_in[4];
  const float* pos_enc = (const float*)d_in[5];
  const float* attn_in_w = (const float*)d_in[6];
  const float* attn_in_b = (const float*)d_in[7];
  const float* attn_out_w = (const float*)d_in[8];
  const float* attn_out_b = (const float*)d_in[9];
  const float* n1_g = (const float*)d_in[10];
  const float* n1_b = (const float*)d_in[11];
  const float* n2_g = (const float*)d_in[12];
  const float* n2_b = (const float*)d_in[13];
  const float* ffn_w1 = (const float*)d_in[14];
  const float* ffn_b1 = (const float*)d_in[15];
  const float* ffn_w2 = (const float*)d_in[16];
  const float* ffn_b2 = (const float*)d_in[17];
  const float* q_w = (const float*)d_in[18];
  const float* q_b = (const float*)d_in[19];
  const float* qln_g = (const float*)d_in[20];
  const float* qln_b = (const float*)d_in[21];
  const float* patterns = (const float*)d_in[22];
  const int* epoch = (const int*)d_in[23];
  const int* tot = (const int*)d_in[24];

  float* out = (float*)d_out;
  float* emb = out;               // [8192,512]
  float* assign = out + 4194304;  // [8192,512]
  float* logits = out + 8388608;  // [8192,512]
  float* h = out + 12582912;      // [8192,512]
  float* idxf = out + 16777216;   // [8192]

  float* ws_f = (float*)d_ws;
  // A region @0 (18.87M floats = 37.75M u16)
  u16* a16 = (u16*)ws_f;
  // B region @18.87M floats (6.29M floats = 12.58M u16)
  float* bF = ws_f + 18874368;
  u16* b16 = (u16*)bF;
  u16 *hnH = b16, *hnM = b16 + 4194304, *hnL = b16 + 8388608;
  // W region @25.17M floats (1.18M floats = 2.36M u16)
  float* wF = ws_f + 25165824;
  u16* w16 = (u16*)wF;

  // ---- symbolization ----
  u16 *xH = a16, *xM = a16 + 8388608, *xL = a16 + 16777216;
  split3_k<<<2048, 256, 0, stream>>>(x, xH, xM, xL, 2097152);
  split3_k<<<512, 256, 0, stream>>>(sym_w, w16, w16 + 524288, w16 + 1048576,
                                    131072);
  gemm_mf<E_BIAS><<<512, 256, 0, stream>>>(
      xH, xM, xL, w16, w16 + 524288, w16 + 1048576, sym_b, nullptr, bF,
      nullptr, nullptr, nullptr, 512, 1024, 1024, 1024, 4);
  l2_split3<<<256, 256, 0, stream>>>(codebook, w16, w16 + 524288,
                                     w16 + 1048576);
  u16 *hpH = a16, *hpM = a16 + 4194304, *hpL = a16 + 8388608;
  l2_split3<<<2048, 256, 0, stream>>>(bF, hpH, hpM, hpL);
  u16 *sH = a16 + 12582912, *sM = a16 + 20971520, *sL = a16 + 29360128;
  gemm_mf<E_GUM3><<<1024, 256, 0, stream>>>(
      hpH, hpM, hpL, w16, w16 + 524288, w16 + 1048576, nullptr, gumbel,
      nullptr, sH, sM, sL, 1024, 512, 512, 512, 8);
  softmax3<<<8192, 256, 0, stream>>>(sH, sM, sL);
  tsplit_cb<<<512, 256, 0, stream>>>(codebook, w16, w16 + 524288,
                                     w16 + 1048576);
  gemm_mf<E_POS><<<512, 256, 0, stream>>>(
      sH, sM, sL, w16, w16 + 524288, w16 + 1048576, nullptr, pos_enc, h,
      nullptr, nullptr, nullptr, 512, 1024, 1024, 1024, 4);

  // ---- transformer layers ----
  u16 *qkvH = a16, *qkvM = a16 + 12582912, *qkvL = a16 + 25165824;
  u16* w1p = (u16*)(ws_f + 12582912);
  u16* w2p = (u16*)(ws_f + 14155776);
  u16 *pH = a16, *pM = a16 + 8388608, *pL = a16 + 16777216;

  for (int l = 0; l < 4; ++l) {
    const float* inw = attn_in_w + (size_t)l * 1536 * 512;
    const float* inb = attn_in_b + (size_t)l * 1536;
    const float* outw = attn_out_w + (size_t)l * 512 * 512;
    const float* outb = attn_out_b + (size_t)l * 512;
    const float* w1 = ffn_w1 + (size_t)l * 2048 * 512;
    const float* b1 = ffn_b1 + (size_t)l * 2048;
    const float* w2 = ffn_w2 + (size_t)l * 512 * 2048;
    const float* b2 = ffn_b2 + (size_t)l * 512;

    ln_split3<<<2048, 256, 0, stream>>>(h, n1_g + l * 512, n1_b + l * 512,
                                        hnH, hnM, hnL);
    split3_k<<<1024, 256, 0, stream>>>(inw, w16, w16 + 786432, w16 + 1572864,
                                       196608);
    gemm_mf<E_QKV3><<<1536, 256, 0, stream>>>(
        hnH, hnM, hnL, w16, w16 + 786432, w16 + 1572864, inb, nullptr,
        nullptr, qkvH, qkvM, qkvL, 1536, 512, 512, 512, 12);
    flash_mfma<<<1024, 256, 0, stream>>>(qkvH, qkvM, qkvL, hnH, hnM, hnL);
    split3_k<<<256, 256, 0, stream>>>(outw, w16, w16 + 262144, w16 + 524288,
                                      65536);
    gemm_mf<E_RES><<<512, 256, 0, stream>>>(
        hnH, hnM, hnL, w16, w16 + 262144, w16 + 524288, outb, h, h, nullptr,
        nullptr, nullptr, 512, 512, 512, 512, 4);
    ln_split3<<<2048, 256, 0, stream>>>(h, n2_g + l * 512, n2_b + l * 512,
                                        hnH, hnM, hnL);
    split3_k<<<1024, 256, 0, stream>>>(w1, w1p, w1p + 1048576, w1p + 2097152,
                                       262144);
    split3_k<<<1024, 256, 0, stream>>>(w2, w2p, w2p + 1048576, w2p + 2097152,
                                       262144);
    for (int c = 0; c < 2; ++c) {
      gemm_mf<E_GELU3><<<1024, 256, 0, stream>>>(
          hnH, hnM, hnL, w1p + c * 524288, w1p + 1048576 + c * 524288,
          w1p + 2097152 + c * 524288, b1 + c * 1024, nullptr, nullptr, pH, pM,
          pL, 1024, 512, 512, 512, 8);
      if (c == 0) {
        gemm_mf<E_RES><<<512, 256, 0, stream>>>(
            pH, pM, pL, w2p + 0, w2p + 1048576, w2p + 2097152, b2, h, h,
            nullptr, nullptr, nullptr, 512, 1024, 1024, 2048, 4);
      } else {
        gemm_mf<E_ACC><<<512, 256, 0, stream>>>(
            pH, pM, pL, w2p + 1024, w2p + 1048576 + 1024, w2p + 2097152 + 1024,
            nullptr, nullptr, h, nullptr, nullptr, nullptr, 512, 1024, 1024,
            2048, 4);
      }
    }
  }

  // ---- VQ head (fp32-vector precision anchor) ----
  gemm_f32<64, 128, 32, E_BIAS><<<dim3(4, 128), 256, 0, stream>>>(
      h, q_w, q_b, bF, 8192, 512, 512, nullptr, nullptr);
  ln_l2_f32<<<2048, 256, 0, stream>>>(bF, qln_g, qln_b, bF);
  l2_f32<<<128, 256, 0, stream>>>(patterns, wF);
  gemm_f32<64, 128, 32, E_VQ><<<dim3(4, 128), 256, 0, stream>>>(
      bF, wF, nullptr, logits, 8192, 512, 512, epoch, tot);
  vq_finalize<<<2048, 256, 0, stream>>>(logits, patterns, emb, assign, idxf);
}

// Round 13
// 1804.895 us; speedup vs baseline: 1.7131x; 1.4417x over previous
//
#include <hip/hip_runtime.h>

#define DEV __device__ __forceinline__

typedef unsigned short u16;
typedef unsigned int u32;
typedef __attribute__((ext_vector_type(8))) _Float16 h8_t;  // 8 f16 (4 VGPR)
typedef __attribute__((ext_vector_type(4))) float f4_t;

constexpr int T_SEQ = 1024;
constexpr int DMODEL = 512;
constexpr int NPAT = 512;

// ---------------- epilogue modes ----------------
enum {
  E_BIAS = 0,
  E_VQ = 5,
  E_RES = 6,
  E_ACC = 7,
  E_POS = 8,
  E_GUM2 = 9,
  E_GELU2 = 10,
  E_QKV2 = 11
};

// ---------------- fp16 double-split helpers (err ~2^-22, fp32-grade) ---------
DEV float h2f(u16 h) { return (float)__builtin_bit_cast(_Float16, h); }
DEV void split2(float x, u16& h, u16& l) {
  _Float16 hh = (_Float16)x;
  float r = x - (float)hh;
  _Float16 ll = (_Float16)r;
  h = __builtin_bit_cast(u16, hh);
  l = __builtin_bit_cast(u16, ll);
}

DEV f4_t mfh(h8_t a, h8_t b, f4_t c) {
  return __builtin_amdgcn_mfma_f32_16x16x32_f16(a, b, c, 0, 0, 0);
}
// 3-product double-split accumulate: AB = AhBh + AhBl + AlBh (+O(2^-22))
DEV f4_t prod3(h8_t ah, h8_t al, h8_t bh, h8_t bl, f4_t c) {
  c = mfh(ah, bh, c);
  c = mfh(ah, bl, c);
  c = mfh(al, bh, c);
  return c;
}

// async global->LDS, 16B per lane; LDS dest = base + lane*16 (wave-uniform base)
typedef const __attribute__((address_space(1))) unsigned char* gas_t;
typedef __attribute__((address_space(3))) unsigned char* las_t;
DEV void gload16(const u16* g, u16* l) {
  __builtin_amdgcn_global_load_lds((gas_t)(const void*)g, (las_t)(void*)l, 16,
                                   0, 0);
}

// ---------------- MFMA GEMM, fp16 double-split (fp32-accurate) ---------------
// C[M,N] = A[M,K]*B[N,K]^T via 3 f16 products. Structure verified R6-R12
// (2-phase prefetch, one barrier/iter, XCD swizzle). 2 planes -> LDS dbuf
// 48KB -> 3 blocks/CU.
template <int EPI>
__global__ __launch_bounds__(256, 3) void gemm_mf(
    const u16* __restrict__ Ah, const u16* __restrict__ Al,
    const u16* __restrict__ Bh, const u16* __restrict__ Bl,
    const float* __restrict__ bias, const float* __restrict__ res,
    float* __restrict__ Cf, u16* __restrict__ Ch, u16* __restrict__ Cl, int N,
    int KK, int lda, int ldb, int gx) {
  constexpr int BM = 64;
  constexpr int MT = 2;  // m-tiles per wave
  __shared__ __align__(16) u16 AsH[2][BM][4][8], AsL[2][BM][4][8];
  __shared__ __align__(16) u16 BsH[2][128][4][8], BsL[2][128][4][8];
  const int tid = threadIdx.x;
  const int w = tid >> 6, lane = tid & 63;
  const int wy = w >> 1, wx = w & 1;
  const int lr = lane & 15, lg = lane >> 4;

  // bijective XCD swizzle (all grids divisible by 8)
  const int nwg = gridDim.x;
  const int bid = blockIdx.x;
  const int qq = nwg >> 3;
  const int wg = (bid & 7) * qq + (bid >> 3);
  const int by = wg / gx, bx = wg % gx;
  const int bm = by * BM, bn = bx * 128;

  const int rowl = lane >> 2, slot4 = lane & 3;  // per-lane stage coords

  auto STAGE = [&](int k0, int buf) {
#pragma unroll
    for (int it = 0; it < 2; ++it) {  // A: 8 chunks (2 planes x 4)
      const int f = w + 4 * it;
      const int plane = f >> 2;
      const int ch = f & 3;
      const int row = ch * 16 + rowl;
      const int kp = slot4 ^ ((row >> 1) & 3);
      const size_t g = (size_t)(bm + row) * lda + k0 + kp * 8;
      if (plane == 0)
        gload16(&Ah[g], &AsH[buf][0][0][0] + ch * 512);
      else
        gload16(&Al[g], &AsL[buf][0][0][0] + ch * 512);
    }
#pragma unroll
    for (int it = 0; it < 4; ++it) {  // B: 16 chunks (2 planes x 8)
      const int f = w + 4 * it;
      const int plane = f >> 3;
      const int ch = f & 7;
      const int row = ch * 16 + rowl;
      const int kp = slot4 ^ ((row >> 1) & 3);
      const size_t g = (size_t)(bn + row) * ldb + k0 + kp * 8;
      if (plane == 0)
        gload16(&Bh[g], &BsH[buf][0][0][0] + ch * 512);
      else
        gload16(&Bl[g], &BsL[buf][0][0][0] + ch * 512);
    }
  };

  f4_t acc[MT][4];
#pragma unroll
  for (int mt = 0; mt < MT; ++mt)
#pragma unroll
    for (int nt = 0; nt < 4; ++nt) acc[mt][nt] = (f4_t){0.f, 0.f, 0.f, 0.f};

  const int nsteps = KK / 32;
  STAGE(0, 0);
  __syncthreads();
  for (int t = 0; t < nsteps; ++t) {
    const int cur = t & 1;
    if (t + 1 < nsteps) STAGE((t + 1) * 32, cur ^ 1);

    h8_t fah[MT], fal[MT], fbh[4], fbl[4];
#pragma unroll
    for (int mt = 0; mt < MT; ++mt) {
      int row = wy * 32 + mt * 16 + lr;
      int slot = lg ^ ((row >> 1) & 3);
      fah[mt] = *(const h8_t*)&AsH[cur][row][slot][0];
      fal[mt] = *(const h8_t*)&AsL[cur][row][slot][0];
    }
#pragma unroll
    for (int nt = 0; nt < 4; ++nt) {
      int col = wx * 64 + nt * 16 + lr;
      int slot = lg ^ ((col >> 1) & 3);
      fbh[nt] = *(const h8_t*)&BsH[cur][col][slot][0];
      fbl[nt] = *(const h8_t*)&BsL[cur][col][slot][0];
    }
#pragma unroll
    for (int mt = 0; mt < MT; ++mt)
#pragma unroll
      for (int nt = 0; nt < 4; ++nt)
        acc[mt][nt] = prod3(fah[mt], fal[mt], fbh[nt], fbl[nt], acc[mt][nt]);
    __syncthreads();
  }

  // ---- epilogue (C frag: col = lane&15, row = 4*(lane>>4)+i) ----
  float bv[4];
  if constexpr (EPI == E_BIAS || EPI == E_RES || EPI == E_GELU2 ||
                EPI == E_QKV2) {
#pragma unroll
    for (int nt = 0; nt < 4; ++nt) bv[nt] = bias[bn + wx * 64 + nt * 16 + lr];
  }
#pragma unroll
  for (int mt = 0; mt < MT; ++mt)
#pragma unroll
    for (int nt = 0; nt < 4; ++nt) {
      const int c = bn + wx * 64 + nt * 16 + lr;
#pragma unroll
      for (int i = 0; i < 4; ++i) {
        const int m = bm + wy * 32 + mt * 16 + 4 * lg + i;
        const size_t idx = (size_t)m * N + c;
        float v = acc[mt][nt][i];
        if constexpr (EPI == E_BIAS) {
          Cf[idx] = v + bv[nt];
        } else if constexpr (EPI == E_RES) {
          Cf[idx] = v + bv[nt] + res[idx];
        } else if constexpr (EPI == E_ACC) {
          Cf[idx] += v;
        } else if constexpr (EPI == E_POS) {
          Cf[idx] = v + res[(size_t)(m & 1023) * N + c];
        } else if constexpr (EPI == E_GUM2) {
          float t = 4.0f * v + 2.0f * res[idx];
          u16 h2, l2;
          split2(t, h2, l2);
          Ch[idx] = h2;
          Cl[idx] = l2;
        } else if constexpr (EPI == E_GELU2) {
          float t = v + bv[nt];
          float g = 0.5f * t * (1.0f + erff(t * 0.7071067811865476f));
          u16 h2, l2;
          split2(g, h2, l2);
          Ch[idx] = h2;
          Cl[idx] = l2;
        } else if constexpr (EPI == E_QKV2) {
          float t = v + bv[nt];
          u16 h2, l2;
          split2(t, h2, l2);
          size_t o;
          if (c < 512) {
            o = (size_t)m * 512 + c;                       // Q [B,T,512]
          } else if (c < 1024) {
            o = 4194304 + (size_t)m * 512 + (c - 512);     // K [B,T,512]
          } else {
            int cc = c - 1024, hh2 = cc >> 6, dd = cc & 63;
            int bb2 = m >> 10, tt = m & 1023;
            o = 8388608 +
                (((size_t)(bb2 * 8 + hh2) * 64 + dd) << 10) + tt;  // Vt
          }
          Ch[o] = h2;
          Cl[o] = l2;
        }
      }
    }
}

// ---------------- MFMA flash attention (fp16 double-split) -------------------
// 1-D grid 1024, XCD-swizzled (b = bid&7 -> K/V L2-resident per XCD; R12
// verified FETCH 37MB). Staging via global_load_lds. P aliases the K tile.
// 2 planes: LDS 32KB -> 4+ blocks/CU.
__global__ __launch_bounds__(256, 4) void flash_mfma(
    const u16* __restrict__ QKVh, const u16* __restrict__ QKVl,
    u16* __restrict__ Oh, u16* __restrict__ Ol) {
  __shared__ __align__(16) u16 KP[2][64][8][8];  // K tile, then P tile
  __shared__ __align__(16) u16 Vs[2][64][8][8];
  const int tid = threadIdx.x;
  const int w = tid >> 6, lane = tid & 63;
  const int lr = lane & 15, lg = lane >> 4;
  const int bid = blockIdx.x;
  const int b = bid & 7;
  const int slot_b = bid >> 3;  // 0..127
  const int hh = slot_b >> 4;   // 0..7
  const int qt = slot_b & 15;   // 0..15

  const u16* Qh = QKVh;
  const u16* Ql = QKVl;
  const u16* Kh = QKVh + 4194304;
  const u16* Kl = QKVl + 4194304;
  const u16* Vh = QKVh + 8388608;
  const u16* Vl = QKVl + 8388608;

  // Q fragments (A-op: m = lr, k-packet = lg), hoisted for all kt
  h8_t qf[2][2];
  {
    size_t g =
        ((size_t)(b * 1024 + qt * 64 + w * 16 + lr)) * 512 + hh * 64 + lg * 8;
    qf[0][0] = *(const h8_t*)&Qh[g];
    qf[0][1] = *(const h8_t*)&Ql[g];
    qf[1][0] = *(const h8_t*)&Qh[g + 32];
    qf[1][1] = *(const h8_t*)&Ql[g + 32];
  }

  f4_t oacc[4];
#pragma unroll
  for (int nt = 0; nt < 4; ++nt) oacc[nt] = (f4_t){0.f, 0.f, 0.f, 0.f};
  float mrun[4], lrun[4];
#pragma unroll
  for (int i = 0; i < 4; ++i) {
    mrun[i] = -__builtin_huge_valf();
    lrun[i] = 0.0f;
  }

  const int rowl8 = lane >> 3, slot8 = lane & 7;  // stage coords (8 rows/chunk)

  for (int kt = 0; kt < 16; ++kt) {
    __syncthreads();  // prior PV done reading Vs + KP(P)
    // ---- stage K tile + Vt tile via global_load_lds: 32 x 1KB chunks ----
#pragma unroll
    for (int it = 0; it < 4; ++it) {
      const int f = w + 4 * it;
      const int plane = f >> 3, ch = f & 7;
      const int row = ch * 8 + rowl8;
      const int kp = slot8 ^ (row & 7);
      const size_t gk =
          ((size_t)(b * 1024 + kt * 64 + row)) * 512 + hh * 64 + kp * 8;
      if (plane == 0)
        gload16(&Kh[gk], &KP[0][0][0][0] + ch * 512);
      else
        gload16(&Kl[gk], &KP[1][0][0][0] + ch * 512);
    }
#pragma unroll
    for (int it = 0; it < 4; ++it) {
      const int f = w + 4 * it;
      const int plane = f >> 3, ch = f & 7;
      const int row = ch * 8 + rowl8;
      const int kp = slot8 ^ (row & 7);
      const size_t gv =
          ((size_t)((b * 8 + hh) * 64 + row)) * 1024 + kt * 64 + kp * 8;
      if (plane == 0)
        gload16(&Vh[gv], &Vs[0][0][0][0] + ch * 512);
      else
        gload16(&Vl[gv], &Vs[1][0][0][0] + ch * 512);
    }
    __syncthreads();

    // ---- S = Q K^T : 4 n-tiles x 2 k-slices x 3 products ----
    f4_t s[4];
#pragma unroll
    for (int nt = 0; nt < 4; ++nt) {
      s[nt] = (f4_t){0.f, 0.f, 0.f, 0.f};
      const int col = nt * 16 + lr;
#pragma unroll
      for (int ks = 0; ks < 2; ++ks) {
        int slt = (ks * 4 + lg) ^ (col & 7);
        h8_t kh = *(const h8_t*)&KP[0][col][slt][0];
        h8_t kl = *(const h8_t*)&KP[1][col][slt][0];
        s[nt] = prod3(qf[ks][0], qf[ks][1], kh, kl, s[nt]);
      }
    }

    // ---- online softmax (row = 4*lg+i; reduce over lr via shfl) ----
#pragma unroll
    for (int i = 0; i < 4; ++i) {
      float rm = -__builtin_huge_valf();
#pragma unroll
      for (int nt = 0; nt < 4; ++nt) {
        s[nt][i] *= 0.125f;
        rm = fmaxf(rm, s[nt][i]);
      }
      rm = fmaxf(rm, __shfl_xor(rm, 1));
      rm = fmaxf(rm, __shfl_xor(rm, 2));
      rm = fmaxf(rm, __shfl_xor(rm, 4));
      rm = fmaxf(rm, __shfl_xor(rm, 8));
      float mnew = fmaxf(mrun[i], rm);
      float alpha = __expf(mrun[i] - mnew);
      float rs = 0.0f;
#pragma unroll
      for (int nt = 0; nt < 4; ++nt) {
        float p = __expf(s[nt][i] - mnew);
        s[nt][i] = p;
        rs += p;
      }
      rs += __shfl_xor(rs, 1);
      rs += __shfl_xor(rs, 2);
      rs += __shfl_xor(rs, 4);
      rs += __shfl_xor(rs, 8);
      lrun[i] = lrun[i] * alpha + rs;
      mrun[i] = mnew;
#pragma unroll
      for (int nt = 0; nt < 4; ++nt) oacc[nt][i] *= alpha;
    }

    __syncthreads();  // all waves done reading K tile -> safe to overwrite

    // ---- P -> KP (wave-private rows, 2 planes, swizzled) ----
#pragma unroll
    for (int nt = 0; nt < 4; ++nt)
#pragma unroll
      for (int i = 0; i < 4; ++i) {
        int qrow = w * 16 + 4 * lg + i;
        int kv = nt * 16 + lr;
        int kp = kv >> 3, j = kv & 7;
        int slt = kp ^ (qrow & 7);
        u16 h2, l2;
        split2(s[nt][i], h2, l2);
        KP[0][qrow][slt][j] = h2;
        KP[1][qrow][slt][j] = l2;
      }

    // ---- O += P V (A = own P rows, B = Vt cols) ----
    h8_t pf[2][2];
#pragma unroll
    for (int ks = 0; ks < 2; ++ks) {
      int row = w * 16 + lr;
      int slt = (ks * 4 + lg) ^ (row & 7);
      pf[ks][0] = *(const h8_t*)&KP[0][row][slt][0];
      pf[ks][1] = *(const h8_t*)&KP[1][row][slt][0];
    }
#pragma unroll
    for (int ntd = 0; ntd < 4; ++ntd) {
      const int col = ntd * 16 + lr;
#pragma unroll
      for (int ks = 0; ks < 2; ++ks) {
        int slt = (ks * 4 + lg) ^ (col & 7);
        h8_t vh = *(const h8_t*)&Vs[0][col][slt][0];
        h8_t vl = *(const h8_t*)&Vs[1][col][slt][0];
        oacc[ntd] = prod3(pf[ks][0], pf[ks][1], vh, vl, oacc[ntd]);
      }
    }
  }

  // ---- epilogue: normalize, split2, store planes [B,T,512] ----
#pragma unroll
  for (int i = 0; i < 4; ++i) {
    float inv = 1.0f / lrun[i];
    int t = qt * 64 + w * 16 + 4 * lg + i;
#pragma unroll
    for (int ntd = 0; ntd < 4; ++ntd) {
      int d = hh * 64 + ntd * 16 + lr;
      size_t idx = ((size_t)(b * 1024 + t)) * 512 + d;
      u16 h2, l2;
      split2(oacc[ntd][i] * inv, h2, l2);
      Oh[idx] = h2;
      Ol[idx] = l2;
    }
  }
}

// ---------------- fp32 vector GEMM (VQ-head precision anchor) ----------------
template <int BM, int BN, int WR, int EPI>
__global__ __launch_bounds__((BM / WR) * (BN / 64) * 64) void gemm_f32(
    const float* __restrict__ A, const float* __restrict__ Bmat,
    const float* __restrict__ bias, float* __restrict__ C, int M, int N, int K,
    const int* __restrict__ ep, const int* __restrict__ tot) {
  constexpr int BK = 16;
  constexpr int WN = BN / 64;
  constexpr int NW = (BM / WR) * WN;
  constexpr int NT = NW * 64;
  constexpr int RM = WR / 8;
  __shared__ __align__(16) float As[BK][BM + 4];
  __shared__ __align__(16) float Bs[BK][BN + 4];
  const int tid = threadIdx.x;
  const int w = tid >> 6, lane = tid & 63;
  const int wy = w / WN, wx = w % WN;
  const int ly = lane >> 3, lx = lane & 7;
  const int bm = blockIdx.y * BM;
  const int bn = blockIdx.x * BN;
  const int rbase = wy * WR + ly * RM;

  float acc[RM][8];
#pragma unroll
  for (int i = 0; i < RM; ++i)
#pragma unroll
    for (int j = 0; j < 8; ++j) acc[i][j] = 0.0f;

  for (int k0 = 0; k0 < K; k0 += BK) {
#pragma unroll
    for (int i = 0; i < (BM * BK / 4) / NT; ++i) {
      int idx = tid + i * NT;
      int r = idx >> 2, c4 = (idx & 3) << 2;
      const float4 v = *(const float4*)(A + (size_t)(bm + r) * K + k0 + c4);
      As[c4 + 0][r] = v.x;
      As[c4 + 1][r] = v.y;
      As[c4 + 2][r] = v.z;
      As[c4 + 3][r] = v.w;
    }
#pragma unroll
    for (int i = 0; i < (BN * BK / 4) / NT; ++i) {
      int idx = tid + i * NT;
      int r = idx >> 2, c4 = (idx & 3) << 2;
      const float4 v = *(const float4*)(Bmat + (size_t)(bn + r) * K + k0 + c4);
      Bs[c4 + 0][r] = v.x;
      Bs[c4 + 1][r] = v.y;
      Bs[c4 + 2][r] = v.z;
      Bs[c4 + 3][r] = v.w;
    }
    __syncthreads();
#pragma unroll
    for (int k = 0; k < BK; ++k) {
      float a[RM], b[8];
#pragma unroll
      for (int r4 = 0; r4 < RM; r4 += 4)
        *(float4*)&a[r4] = *(const float4*)&As[k][rbase + r4];
      *(float4*)&b[0] = *(const float4*)&Bs[k][wx * 64 + lx * 8];
      *(float4*)&b[4] = *(const float4*)&Bs[k][wx * 64 + lx * 8 + 4];
#pragma unroll
      for (int i = 0; i < RM; ++i)
#pragma unroll
        for (int j = 0; j < 8; ++j) acc[i][j] = fmaf(a[i], b[j], acc[i][j]);
    }
    __syncthreads();
  }

  const int ncol = bn + wx * 64 + lx * 8;
  float bb[8];
  if constexpr (EPI == E_BIAS) {
    *(float4*)&bb[0] = *(const float4*)(bias + ncol);
    *(float4*)&bb[4] = *(const float4*)(bias + ncol + 4);
  }
  float invt = 1.0f;
  if constexpr (EPI == E_VQ) {
    float t = 1.0f - 0.5f * (float)ep[0] / (float)tot[0];
    invt = 1.0f / fmaxf(0.5f, t);
  }
#pragma unroll
  for (int i = 0; i < RM; ++i) {
    const int m = bm + rbase + i;
    float o[8];
#pragma unroll
    for (int j = 0; j < 8; ++j) o[j] = acc[i][j];
    if constexpr (EPI == E_BIAS) {
#pragma unroll
      for (int j = 0; j < 8; ++j) o[j] += bb[j];
    } else if constexpr (EPI == E_VQ) {
#pragma unroll
      for (int j = 0; j < 8; ++j) o[j] *= invt;
    }
    *(float4*)(C + (size_t)m * N + ncol) = *(float4*)&o[0];
    *(float4*)(C + (size_t)m * N + ncol + 4) = *(float4*)&o[4];
  }
}

// ---------------- row kernels ----------------
DEV float wave_sum(float v) {
#pragma unroll
  for (int off = 1; off < 64; off <<= 1) v += __shfl_xor(v, off);
  return v;
}

DEV void store8_split2(u16* H, u16* L, size_t base, const float* t) {
  u16 vh[8], vl[8];
#pragma unroll
  for (int j = 0; j < 8; ++j) split2(t[j], vh[j], vl[j]);
  *(ushort4*)&H[base] = make_ushort4(vh[0], vh[1], vh[2], vh[3]);
  *(ushort4*)&H[base + 4] = make_ushort4(vh[4], vh[5], vh[6], vh[7]);
  *(ushort4*)&L[base] = make_ushort4(vl[0], vl[1], vl[2], vl[3]);
  *(ushort4*)&L[base + 4] = make_ushort4(vl[4], vl[5], vl[6], vl[7]);
}

__global__ __launch_bounds__(256) void ln_split2(const float* __restrict__ x,
                                                 const float* __restrict__ g,
                                                 const float* __restrict__ b,
                                                 u16* __restrict__ yh,
                                                 u16* __restrict__ yl) {
  const int row = blockIdx.x * 4 + (threadIdx.x >> 6);
  const int lane = threadIdx.x & 63;
  const float* xr = x + (size_t)row * DMODEL;
  float v[8];
  *(float4*)&v[0] = *(const float4*)(xr + lane * 8);
  *(float4*)&v[4] = *(const float4*)(xr + lane * 8 + 4);
  float s = 0.0f;
#pragma unroll
  for (int j = 0; j < 8; ++j) s += v[j];
  s = wave_sum(s);
  float mean = s * (1.0f / 512.0f);
  float s2 = 0.0f;
#pragma unroll
  for (int j = 0; j < 8; ++j) {
    float d = v[j] - mean;
    s2 += d * d;
  }
  s2 = wave_sum(s2);
  float rstd = 1.0f / sqrtf(s2 * (1.0f / 512.0f) + 1e-5f);
  float gg[8], bv[8];
  *(float4*)&gg[0] = *(const float4*)(g + lane * 8);
  *(float4*)&gg[4] = *(const float4*)(g + lane * 8 + 4);
  *(float4*)&bv[0] = *(const float4*)(b + lane * 8);
  *(float4*)&bv[4] = *(const float4*)(b + lane * 8 + 4);
  float t[8];
#pragma unroll
  for (int j = 0; j < 8; ++j) t[j] = (v[j] - mean) * rstd * gg[j] + bv[j];
  store8_split2(yh, yl, (size_t)row * DMODEL + lane * 8, t);
}

__global__ __launch_bounds__(256) void ln_l2_f32(const float* __restrict__ x,
                                                 const float* __restrict__ g,
                                                 const float* __restrict__ b,
                                                 float* __restrict__ y) {
  const int row = blockIdx.x * 4 + (threadIdx.x >> 6);
  const int lane = threadIdx.x & 63;
  const float* xr = x + (size_t)row * DMODEL;
  float v[8];
  *(float4*)&v[0] = *(const float4*)(xr + lane * 8);
  *(float4*)&v[4] = *(const float4*)(xr + lane * 8 + 4);
  float s = 0.0f;
#pragma unroll
  for (int j = 0; j < 8; ++j) s += v[j];
  s = wave_sum(s);
  float mean = s * (1.0f / 512.0f);
  float s2 = 0.0f;
#pragma unroll
  for (int j = 0; j < 8; ++j) {
    float d = v[j] - mean;
    s2 += d * d;
  }
  s2 = wave_sum(s2);
  float rstd = 1.0f / sqrtf(s2 * (1.0f / 512.0f) + 1e-5f);
  float gg[8], bv[8];
  *(float4*)&gg[0] = *(const float4*)(g + lane * 8);
  *(float4*)&gg[4] = *(const float4*)(g + lane * 8 + 4);
  *(float4*)&bv[0] = *(const float4*)(b + lane * 8);
  *(float4*)&bv[4] = *(const float4*)(b + lane * 8 + 4);
  float t[8];
#pragma unroll
  for (int j = 0; j < 8; ++j) t[j] = (v[j] - mean) * rstd * gg[j] + bv[j];
  float n2 = 0.0f;
#pragma unroll
  for (int j = 0; j < 8; ++j) n2 += t[j] * t[j];
  n2 = wave_sum(n2);
  float den = fmaxf(sqrtf(n2), 1e-12f);
#pragma unroll
  for (int j = 0; j < 8; ++j) t[j] /= den;
  float* yr = y + (size_t)row * DMODEL;
  *(float4*)(yr + lane * 8) = *(float4*)&t[0];
  *(float4*)(yr + lane * 8 + 4) = *(float4*)&t[4];
}

__global__ __launch_bounds__(256) void l2_split2(const float* __restrict__ x,
                                                 u16* __restrict__ yh,
                                                 u16* __restrict__ yl) {
  const int row = blockIdx.x * 4 + (threadIdx.x >> 6);
  const int lane = threadIdx.x & 63;
  const float* xr = x + (size_t)row * DMODEL;
  float v[8];
  *(float4*)&v[0] = *(const float4*)(xr + lane * 8);
  *(float4*)&v[4] = *(const float4*)(xr + lane * 8 + 4);
  float n2 = 0.0f;
#pragma unroll
  for (int j = 0; j < 8; ++j) n2 += v[j] * v[j];
  n2 = wave_sum(n2);
  float den = fmaxf(sqrtf(n2), 1e-12f);
#pragma unroll
  for (int j = 0; j < 8; ++j) v[j] /= den;
  store8_split2(yh, yl, (size_t)row * DMODEL + lane * 8, v);
}

__global__ __launch_bounds__(256) void l2_f32(const float* __restrict__ x,
                                              float* __restrict__ y) {
  const int row = blockIdx.x * 4 + (threadIdx.x >> 6);
  const int lane = threadIdx.x & 63;
  const float* xr = x + (size_t)row * DMODEL;
  float v[8];
  *(float4*)&v[0] = *(const float4*)(xr + lane * 8);
  *(float4*)&v[4] = *(const float4*)(xr + lane * 8 + 4);
  float n2 = 0.0f;
#pragma unroll
  for (int j = 0; j < 8; ++j) n2 += v[j] * v[j];
  n2 = wave_sum(n2);
  float den = fmaxf(sqrtf(n2), 1e-12f);
#pragma unroll
  for (int j = 0; j < 8; ++j) v[j] /= den;
  float* yr = y + (size_t)row * DMODEL;
  *(float4*)(yr + lane * 8) = *(float4*)&v[0];
  *(float4*)(yr + lane * 8 + 4) = *(float4*)&v[4];
}

// softmax over rows of 1024, in-place on 2 fp16 planes
__global__ __launch_bounds__(256) void softmax2(u16* __restrict__ H,
                                                u16* __restrict__ L) {
  const int row = blockIdx.x;
  const int tid = threadIdx.x;
  const size_t base = (size_t)row * 1024 + tid * 4;
  ushort4 qh = *(const ushort4*)&H[base];
  ushort4 ql = *(const ushort4*)&L[base];
  float v0 = h2f(qh.x) + h2f(ql.x);
  float v1 = h2f(qh.y) + h2f(ql.y);
  float v2 = h2f(qh.z) + h2f(ql.z);
  float v3 = h2f(qh.w) + h2f(ql.w);
  float mx = fmaxf(fmaxf(v0, v1), fmaxf(v2, v3));
#pragma unroll
  for (int off = 1; off < 64; off <<= 1) mx = fmaxf(mx, __shfl_xor(mx, off));
  __shared__ float red[4];
  const int wv = tid >> 6;
  if ((tid & 63) == 0) red[wv] = mx;
  __syncthreads();
  mx = fmaxf(fmaxf(red[0], red[1]), fmaxf(red[2], red[3]));
  float e0 = __expf(v0 - mx), e1 = __expf(v1 - mx), e2 = __expf(v2 - mx),
        e3 = __expf(v3 - mx);
  float s = e0 + e1 + e2 + e3;
#pragma unroll
  for (int off = 1; off < 64; off <<= 1) s += __shfl_xor(s, off);
  __syncthreads();
  if ((tid & 63) == 0) red[wv] = s;
  __syncthreads();
  s = red[0] + red[1] + red[2] + red[3];
  float inv = 1.0f / s;
  u16 ah[4], al[4];
  split2(e0 * inv, ah[0], al[0]);
  split2(e1 * inv, ah[1], al[1]);
  split2(e2 * inv, ah[2], al[2]);
  split2(e3 * inv, ah[3], al[3]);
  *(ushort4*)&H[base] = make_ushort4(ah[0], ah[1], ah[2], ah[3]);
  *(ushort4*)&L[base] = make_ushort4(al[0], al[1], al[2], al[3]);
}

// generic fp32 -> 2 fp16 planes splitter (n4 = n/4)
__global__ __launch_bounds__(256) void split2_k(const float* __restrict__ src,
                                                u16* __restrict__ H,
                                                u16* __restrict__ L, int n4) {
  for (int e = blockIdx.x * 256 + threadIdx.x; e < n4; e += gridDim.x * 256) {
    float4 v = *(const float4*)(src + (size_t)e * 4);
    u16 ah[4], al[4];
    split2(v.x, ah[0], al[0]);
    split2(v.y, ah[1], al[1]);
    split2(v.z, ah[2], al[2]);
    split2(v.w, ah[3], al[3]);
    *(ushort4*)&H[(size_t)e * 4] = make_ushort4(ah[0], ah[1], ah[2], ah[3]);
    *(ushort4*)&L[(size_t)e * 4] = make_ushort4(al[0], al[1], al[2], al[3]);
  }
}

// transpose codebook [1024][512] -> cbT [512][1024], split into 2 planes
__global__ __launch_bounds__(256) void tsplit_cb(const float* __restrict__ cb,
                                                 u16* __restrict__ th,
                                                 u16* __restrict__ tl) {
  const int c = blockIdx.x;
  const int t = threadIdx.x;
  u16 ah[4], al[4];
#pragma unroll
  for (int j = 0; j < 4; ++j) {
    float v = cb[(size_t)(4 * t + j) * 512 + c];
    split2(v, ah[j], al[j]);
  }
  const size_t base = (size_t)c * 1024 + 4 * t;
  *(ushort4*)&th[base] = make_ushort4(ah[0], ah[1], ah[2], ah[3]);
  *(ushort4*)&tl[base] = make_ushort4(al[0], al[1], al[2], al[3]);
}

__global__ __launch_bounds__(256) void vq_finalize(
    const float* __restrict__ logits, const float* __restrict__ patterns,
    float* __restrict__ emb, float* __restrict__ assign,
    float* __restrict__ idxf) {
  const int row = blockIdx.x * 4 + (threadIdx.x >> 6);
  const int lane = threadIdx.x & 63;
  const float* lr = logits + (size_t)row * NPAT;
  float best = -__builtin_huge_valf();
  int bi = 0;
#pragma unroll
  for (int jj = 0; jj < 8; ++jj) {
    int j = lane + jj * 64;
    float v = lr[j];
    if (v > best) {
      best = v;
      bi = j;
    }
  }
#pragma unroll
  for (int off = 1; off < 64; off <<= 1) {
    float ob = __shfl_xor(best, off);
    int oi = __shfl_xor(bi, off);
    if (ob > best || (ob == best && oi < bi)) {
      best = ob;
      bi = oi;
    }
  }
  const float* pr = patterns + (size_t)bi * DMODEL;
#pragma unroll
  for (int g = 0; g < 2; ++g) {
    int c = lane * 8 + g * 4;
    float4 pv = *(const float4*)(pr + c);
    *(float4*)(emb + (size_t)row * DMODEL + c) = pv;
    float4 av;
    av.x = (c + 0 == bi) ? 1.0f : 0.0f;
    av.y = (c + 1 == bi) ? 1.0f : 0.0f;
    av.z = (c + 2 == bi) ? 1.0f : 0.0f;
    av.w = (c + 3 == bi) ? 1.0f : 0.0f;
    *(float4*)(assign + (size_t)row * NPAT + c) = av;
  }
  if (lane == 0) idxf[row] = (float)bi;
}

// ---------------- host launch ----------------
extern "C" void kernel_launch(void* const* d_in, const int* in_sizes, int n_in,
                              void* d_out, int out_size, void* d_ws,
                              size_t ws_size, hipStream_t stream) {
  (void)in_sizes;
  (void)n_in;
  (void)out_size;
  (void)ws_size;
  const float* x = (const float*)d_in[0];
  const float* gumbel = (const float*)d_in[1];
  const float* sym_w = (const float*)d_in[2];
  const float* sym_b = (const float*)d_in[3];
  const float* codebook = (const float*)d_in[4];
  const float* pos_enc = (const float*)d_in[5];
  const float* attn_in_w = (const float*)d_in[6];
  const float* attn_in_b = (const float*)d_in[7];
  const float* attn_out_w = (const float*)d_in[8];
  const float* attn_out_b = (const float*)d_in[9];
  const float* n1_g = (const float*)d_in[10];
  const float* n1_b = (const float*)d_in[11];
  const float* n2_g = (const float*)d_in[12];
  const float* n2_b = (const float*)d_in[13];
  const float* ffn_w1 = (const float*)d_in[14];
  const float* ffn_b1 = (const float*)d_in[15];
  const float* ffn_w2 = (const float*)d_in[16];
  const float* ffn_b2 = (const float*)d_in[17];
  const float* q_w = (const float*)d_in[18];
  const float* q_b = (const float*)d_in[19];
  const float* qln_g = (const float*)d_in[20];
  const float* qln_b = (const float*)d_in[21];
  const float* patterns = (const float*)d_in[22];
  const int* epoch = (const int*)d_in[23];
  const int* tot = (const int*)d_in[24];

  float* out = (float*)d_out;
  float* emb = out;               // [8192,512]
  float* assign = out + 4194304;  // [8192,512]
  float* logits = out + 8388608;  // [8192,512]
  float* h = out + 12582912;      // [8192,512]
  float* idxf = out + 16777216;   // [8192]

  float* ws_f = (float*)d_ws;
  // A region @0 (18.87M floats = 37.75M u16)
  u16* a16 = (u16*)ws_f;
  // B region @18.87M floats (6.29M floats = 12.58M u16)
  float* bF = ws_f + 18874368;
  u16* b16 = (u16*)bF;
  u16 *hnH = b16, *hnL = b16 + 4194304;
  // W region @25.17M floats (2.36M u16 capacity)
  float* wF = ws_f + 25165824;
  u16* w16 = (u16*)wF;

  // ---- symbolization ----
  u16 *xH = a16, *xL = a16 + 8388608;
  split2_k<<<2048, 256, 0, stream>>>(x, xH, xL, 2097152);
  split2_k<<<512, 256, 0, stream>>>(sym_w, w16, w16 + 524288, 131072);
  gemm_mf<E_BIAS><<<512, 256, 0, stream>>>(xH, xL, w16, w16 + 524288, sym_b,
                                           nullptr, bF, nullptr, nullptr, 512,
                                           1024, 1024, 1024, 4);
  l2_split2<<<256, 256, 0, stream>>>(codebook, w16, w16 + 524288);
  u16 *hpH = a16, *hpL = a16 + 4194304;
  l2_split2<<<2048, 256, 0, stream>>>(bF, hpH, hpL);
  u16 *sH = a16 + 12582912, *sL = a16 + 20971520;
  gemm_mf<E_GUM2><<<1024, 256, 0, stream>>>(hpH, hpL, w16, w16 + 524288,
                                            nullptr, gumbel, nullptr, sH, sL,
                                            1024, 512, 512, 512, 8);
  softmax2<<<8192, 256, 0, stream>>>(sH, sL);
  tsplit_cb<<<512, 256, 0, stream>>>(codebook, w16, w16 + 524288);
  gemm_mf<E_POS><<<512, 256, 0, stream>>>(sH, sL, w16, w16 + 524288, nullptr,
                                          pos_enc, h, nullptr, nullptr, 512,
                                          1024, 1024, 1024, 4);

  // ---- transformer layers ----
  u16 *qkvH = a16, *qkvL = a16 + 12582912;
  u16* w1p = (u16*)(ws_f + 12582912);  // 2 x 1048576 u16
  u16* w2p = (u16*)(ws_f + 13631488);  // 2 x 1048576 u16
  u16 *pH = a16, *pL = a16 + 8388608;  // FFN mid planes (qkv dead by then)

  for (int l = 0; l < 4; ++l) {
    const float* inw = attn_in_w + (size_t)l * 1536 * 512;
    const float* inb = attn_in_b + (size_t)l * 1536;
    const float* outw = attn_out_w + (size_t)l * 512 * 512;
    const float* outb = attn_out_b + (size_t)l * 512;
    const float* w1 = ffn_w1 + (size_t)l * 2048 * 512;
    const float* b1 = ffn_b1 + (size_t)l * 2048;
    const float* w2 = ffn_w2 + (size_t)l * 512 * 2048;
    const float* b2 = ffn_b2 + (size_t)l * 512;

    ln_split2<<<2048, 256, 0, stream>>>(h, n1_g + l * 512, n1_b + l * 512,
                                        hnH, hnL);
    split2_k<<<1024, 256, 0, stream>>>(inw, w16, w16 + 786432, 196608);
    gemm_mf<E_QKV2><<<1536, 256, 0, stream>>>(hnH, hnL, w16, w16 + 786432,
                                              inb, nullptr, nullptr, qkvH,
                                              qkvL, 1536, 512, 512, 512, 12);
    flash_mfma<<<1024, 256, 0, stream>>>(qkvH, qkvL, hnH, hnL);
    split2_k<<<256, 256, 0, stream>>>(outw, w16, w16 + 262144, 65536);
    gemm_mf<E_RES><<<512, 256, 0, stream>>>(hnH, hnL, w16, w16 + 262144, outb,
                                            h, h, nullptr, nullptr, 512, 512,
                                            512, 512, 4);
    ln_split2<<<2048, 256, 0, stream>>>(h, n2_g + l * 512, n2_b + l * 512,
                                        hnH, hnL);
    split2_k<<<1024, 256, 0, stream>>>(w1, w1p, w1p + 1048576, 262144);
    split2_k<<<1024, 256, 0, stream>>>(w2, w2p, w2p + 1048576, 262144);
    for (int c = 0; c < 2; ++c) {
      gemm_mf<E_GELU2><<<1024, 256, 0, stream>>>(
          hnH, hnL, w1p + c * 524288, w1p + 1048576 + c * 524288, b1 + c * 1024,
          nullptr, nullptr, pH, pL, 1024, 512, 512, 512, 8);
      if (c == 0) {
        gemm_mf<E_RES><<<512, 256, 0, stream>>>(
            pH, pL, w2p + 0, w2p + 1048576, b2, h, h, nullptr, nullptr, 512,
            1024, 1024, 2048, 4);
      } else {
        gemm_mf<E_ACC><<<512, 256, 0, stream>>>(
            pH, pL, w2p + 1024, w2p + 1048576 + 1024, nullptr, nullptr, h,
            nullptr, nullptr, 512, 1024, 1024, 2048, 4);
      }
    }
  }

  // ---- VQ head (fp32-vector precision anchor) ----
  gemm_f32<64, 128, 32, E_BIAS><<<dim3(4, 128), 256, 0, stream>>>(
      h, q_w, q_b, bF, 8192, 512, 512, nullptr, nullptr);
  ln_l2_f32<<<2048, 256, 0, stream>>>(bF, qln_g, qln_b, bF);
  l2_f32<<<128, 256, 0, stream>>>(patterns, wF);
  gemm_f32<64, 128, 32, E_VQ><<<dim3(4, 128), 256, 0, stream>>>(
      bF, wF, nullptr, logits, 8192, 512, 512, epoch, tot);
  vq_finalize<<<2048, 256, 0, stream>>>(logits, patterns, emb, assign, idxf);
}

// Round 14
// 1766.043 us; speedup vs baseline: 1.7508x; 1.0220x over previous
//
#include <hip/hip_runtime.h>

#define DEV __device__ __forceinline__

typedef unsigned short u16;
typedef unsigned int u32;
typedef __attribute__((ext_vector_type(8))) _Float16 h8_t;  // 8 f16 (4 VGPR)
typedef __attribute__((ext_vector_type(4))) float f4_t;

constexpr int T_SEQ = 1024;
constexpr int DMODEL = 512;
constexpr int NPAT = 512;

// ---------------- epilogue modes ----------------
enum {
  E_BIAS = 0,
  E_VQ = 5,
  E_RES = 6,
  E_POS = 8,
  E_GUM2 = 9,
  E_GELU2 = 10,
  E_QKV2 = 11
};

// ---------------- fp16 double-split helpers (err ~2^-22, fp32-grade) ---------
DEV float h2f(u16 h) { return (float)__builtin_bit_cast(_Float16, h); }
DEV void split2(float x, u16& h, u16& l) {
  _Float16 hh = (_Float16)x;
  float r = x - (float)hh;
  _Float16 ll = (_Float16)r;
  h = __builtin_bit_cast(u16, hh);
  l = __builtin_bit_cast(u16, ll);
}

DEV f4_t mfh(h8_t a, h8_t b, f4_t c) {
  return __builtin_amdgcn_mfma_f32_16x16x32_f16(a, b, c, 0, 0, 0);
}
// 3-product double-split accumulate: AB = AhBh + AhBl + AlBh (+O(2^-22))
DEV f4_t prod3(h8_t ah, h8_t al, h8_t bh, h8_t bl, f4_t c) {
  c = mfh(ah, bh, c);
  c = mfh(ah, bl, c);
  c = mfh(al, bh, c);
  return c;
}

// async global->LDS, 16B per lane; LDS dest = base + lane*16 (wave-uniform base)
typedef const __attribute__((address_space(1))) unsigned char* gas_t;
typedef __attribute__((address_space(3))) unsigned char* las_t;
DEV void gload16(const u16* g, u16* l) {
  __builtin_amdgcn_global_load_lds((gas_t)(const void*)g, (las_t)(void*)l, 16,
                                   0, 0);
}

// ---------------- MFMA GEMM, fp16 double-split (fp32-accurate) ---------------
// C[M,N] = A[M,K]*B[N,K]^T via 3 f16 products. BM=BN=128, 4 waves (2x2), each
// wave owns a 64x64 tile (4x4 16x16 frags): 16 ds_reads feed 48 MFMA
// (3 MFMA/read vs 2 before -> less LDS-BW-bound). 2-phase prefetch (R9-R13
// verified), one barrier/iter, XCD swizzle. LDS dbuf 64KB -> 2 blocks/CU.
template <int EPI>
__global__ __launch_bounds__(256, 2) void gemm_mf(
    const u16* __restrict__ Ah, const u16* __restrict__ Al,
    const u16* __restrict__ Bh, const u16* __restrict__ Bl,
    const float* __restrict__ bias, const float* __restrict__ res,
    float* __restrict__ Cf, u16* __restrict__ Ch, u16* __restrict__ Cl, int N,
    int KK, int lda, int ldb, int gx) {
  __shared__ __align__(16) u16 AsH[2][128][4][8], AsL[2][128][4][8];
  __shared__ __align__(16) u16 BsH[2][128][4][8], BsL[2][128][4][8];
  const int tid = threadIdx.x;
  const int w = tid >> 6, lane = tid & 63;
  const int wy = w >> 1, wx = w & 1;
  const int lr = lane & 15, lg = lane >> 4;

  // bijective XCD swizzle (all grids divisible by 8)
  const int nwg = gridDim.x;
  const int bid = blockIdx.x;
  const int qq = nwg >> 3;
  const int wg = (bid & 7) * qq + (bid >> 3);
  const int by = wg / gx, bx = wg % gx;
  const int bm = by * 128, bn = bx * 128;

  const int rowl = lane >> 2, slot4 = lane & 3;  // per-lane stage coords

  auto STAGE = [&](int k0, int buf) {
#pragma unroll
    for (int it = 0; it < 4; ++it) {  // A: 16 chunks (2 planes x 8)
      const int f = w + 4 * it;
      const int plane = f >> 3;
      const int ch = f & 7;
      const int row = ch * 16 + rowl;
      const int kp = slot4 ^ ((row >> 1) & 3);
      const size_t g = (size_t)(bm + row) * lda + k0 + kp * 8;
      if (plane == 0)
        gload16(&Ah[g], &AsH[buf][0][0][0] + ch * 512);
      else
        gload16(&Al[g], &AsL[buf][0][0][0] + ch * 512);
    }
#pragma unroll
    for (int it = 0; it < 4; ++it) {  // B: 16 chunks (2 planes x 8)
      const int f = w + 4 * it;
      const int plane = f >> 3;
      const int ch = f & 7;
      const int row = ch * 16 + rowl;
      const int kp = slot4 ^ ((row >> 1) & 3);
      const size_t g = (size_t)(bn + row) * ldb + k0 + kp * 8;
      if (plane == 0)
        gload16(&Bh[g], &BsH[buf][0][0][0] + ch * 512);
      else
        gload16(&Bl[g], &BsL[buf][0][0][0] + ch * 512);
    }
  };

  f4_t acc[4][4];
#pragma unroll
  for (int mt = 0; mt < 4; ++mt)
#pragma unroll
    for (int nt = 0; nt < 4; ++nt) acc[mt][nt] = (f4_t){0.f, 0.f, 0.f, 0.f};

  const int nsteps = KK / 32;
  STAGE(0, 0);
  __syncthreads();
  for (int t = 0; t < nsteps; ++t) {
    const int cur = t & 1;
    if (t + 1 < nsteps) STAGE((t + 1) * 32, cur ^ 1);

    h8_t fah[4], fal[4], fbh[4], fbl[4];
#pragma unroll
    for (int mt = 0; mt < 4; ++mt) {
      int row = wy * 64 + mt * 16 + lr;
      int slot = lg ^ ((row >> 1) & 3);
      fah[mt] = *(const h8_t*)&AsH[cur][row][slot][0];
      fal[mt] = *(const h8_t*)&AsL[cur][row][slot][0];
    }
#pragma unroll
    for (int nt = 0; nt < 4; ++nt) {
      int col = wx * 64 + nt * 16 + lr;
      int slot = lg ^ ((col >> 1) & 3);
      fbh[nt] = *(const h8_t*)&BsH[cur][col][slot][0];
      fbl[nt] = *(const h8_t*)&BsL[cur][col][slot][0];
    }
#pragma unroll
    for (int mt = 0; mt < 4; ++mt)
#pragma unroll
      for (int nt = 0; nt < 4; ++nt)
        acc[mt][nt] = prod3(fah[mt], fal[mt], fbh[nt], fbl[nt], acc[mt][nt]);
    __syncthreads();
  }

  // ---- epilogue (C frag: col = lane&15, row = 4*(lane>>4)+i) ----
  float bv[4];
  if constexpr (EPI == E_BIAS || EPI == E_RES || EPI == E_GELU2 ||
                EPI == E_QKV2) {
#pragma unroll
    for (int nt = 0; nt < 4; ++nt) bv[nt] = bias[bn + wx * 64 + nt * 16 + lr];
  }
#pragma unroll
  for (int mt = 0; mt < 4; ++mt)
#pragma unroll
    for (int nt = 0; nt < 4; ++nt) {
      const int c = bn + wx * 64 + nt * 16 + lr;
#pragma unroll
      for (int i = 0; i < 4; ++i) {
        const int m = bm + wy * 64 + mt * 16 + 4 * lg + i;
        const size_t idx = (size_t)m * N + c;
        float v = acc[mt][nt][i];
        if constexpr (EPI == E_BIAS) {
          Cf[idx] = v + bv[nt];
        } else if constexpr (EPI == E_RES) {
          Cf[idx] = v + bv[nt] + res[idx];
        } else if constexpr (EPI == E_POS) {
          Cf[idx] = v + res[(size_t)(m & 1023) * N + c];
        } else if constexpr (EPI == E_GUM2) {
          float t = 4.0f * v + 2.0f * res[idx];
          u16 h2, l2;
          split2(t, h2, l2);
          Ch[idx] = h2;
          Cl[idx] = l2;
        } else if constexpr (EPI == E_GELU2) {
          float t = v + bv[nt];
          float g = 0.5f * t * (1.0f + erff(t * 0.7071067811865476f));
          u16 h2, l2;
          split2(g, h2, l2);
          Ch[idx] = h2;
          Cl[idx] = l2;
        } else if constexpr (EPI == E_QKV2) {
          float t = v + bv[nt];
          u16 h2, l2;
          split2(t, h2, l2);
          size_t o;
          if (c < 512) {
            o = (size_t)m * 512 + c;                       // Q [B,T,512]
          } else if (c < 1024) {
            o = 4194304 + (size_t)m * 512 + (c - 512);     // K [B,T,512]
          } else {
            int cc = c - 1024, hh2 = cc >> 6, dd = cc & 63;
            int bb2 = m >> 10, tt = m & 1023;
            o = 8388608 +
                (((size_t)(bb2 * 8 + hh2) * 64 + dd) << 10) + tt;  // Vt
          }
          Ch[o] = h2;
          Cl[o] = l2;
        }
      }
    }
}

// ---------------- MFMA flash attention (fp16 double-split) -------------------
// 1-D grid 1024, XCD-swizzled (b = bid&7 -> K/V L2-resident per XCD).
// Staging via global_load_lds. P aliases the K tile. LDS 32KB.
__global__ __launch_bounds__(256, 4) void flash_mfma(
    const u16* __restrict__ QKVh, const u16* __restrict__ QKVl,
    u16* __restrict__ Oh, u16* __restrict__ Ol) {
  __shared__ __align__(16) u16 KP[2][64][8][8];  // K tile, then P tile
  __shared__ __align__(16) u16 Vs[2][64][8][8];
  const int tid = threadIdx.x;
  const int w = tid >> 6, lane = tid & 63;
  const int lr = lane & 15, lg = lane >> 4;
  const int bid = blockIdx.x;
  const int b = bid & 7;
  const int slot_b = bid >> 3;  // 0..127
  const int hh = slot_b >> 4;   // 0..7
  const int qt = slot_b & 15;   // 0..15

  const u16* Qh = QKVh;
  const u16* Ql = QKVl;
  const u16* Kh = QKVh + 4194304;
  const u16* Kl = QKVl + 4194304;
  const u16* Vh = QKVh + 8388608;
  const u16* Vl = QKVl + 8388608;

  // Q fragments (A-op: m = lr, k-packet = lg), hoisted for all kt
  h8_t qf[2][2];
  {
    size_t g =
        ((size_t)(b * 1024 + qt * 64 + w * 16 + lr)) * 512 + hh * 64 + lg * 8;
    qf[0][0] = *(const h8_t*)&Qh[g];
    qf[0][1] = *(const h8_t*)&Ql[g];
    qf[1][0] = *(const h8_t*)&Qh[g + 32];
    qf[1][1] = *(const h8_t*)&Ql[g + 32];
  }

  f4_t oacc[4];
#pragma unroll
  for (int nt = 0; nt < 4; ++nt) oacc[nt] = (f4_t){0.f, 0.f, 0.f, 0.f};
  float mrun[4], lrun[4];
#pragma unroll
  for (int i = 0; i < 4; ++i) {
    mrun[i] = -__builtin_huge_valf();
    lrun[i] = 0.0f;
  }

  const int rowl8 = lane >> 3, slot8 = lane & 7;  // stage coords (8 rows/chunk)

  for (int kt = 0; kt < 16; ++kt) {
    __syncthreads();  // prior PV done reading Vs + KP(P)
    // ---- stage K tile + Vt tile via global_load_lds: 32 x 1KB chunks ----
#pragma unroll
    for (int it = 0; it < 4; ++it) {
      const int f = w + 4 * it;
      const int plane = f >> 3, ch = f & 7;
      const int row = ch * 8 + rowl8;
      const int kp = slot8 ^ (row & 7);
      const size_t gk =
          ((size_t)(b * 1024 + kt * 64 + row)) * 512 + hh * 64 + kp * 8;
      if (plane == 0)
        gload16(&Kh[gk], &KP[0][0][0][0] + ch * 512);
      else
        gload16(&Kl[gk], &KP[1][0][0][0] + ch * 512);
    }
#pragma unroll
    for (int it = 0; it < 4; ++it) {
      const int f = w + 4 * it;
      const int plane = f >> 3, ch = f & 7;
      const int row = ch * 8 + rowl8;
      const int kp = slot8 ^ (row & 7);
      const size_t gv =
          ((size_t)((b * 8 + hh) * 64 + row)) * 1024 + kt * 64 + kp * 8;
      if (plane == 0)
        gload16(&Vh[gv], &Vs[0][0][0][0] + ch * 512);
      else
        gload16(&Vl[gv], &Vs[1][0][0][0] + ch * 512);
    }
    __syncthreads();

    // ---- S = Q K^T : 4 n-tiles x 2 k-slices x 3 products ----
    f4_t s[4];
#pragma unroll
    for (int nt = 0; nt < 4; ++nt) {
      s[nt] = (f4_t){0.f, 0.f, 0.f, 0.f};
      const int col = nt * 16 + lr;
#pragma unroll
      for (int ks = 0; ks < 2; ++ks) {
        int slt = (ks * 4 + lg) ^ (col & 7);
        h8_t kh = *(const h8_t*)&KP[0][col][slt][0];
        h8_t kl = *(const h8_t*)&KP[1][col][slt][0];
        s[nt] = prod3(qf[ks][0], qf[ks][1], kh, kl, s[nt]);
      }
    }

    // ---- online softmax (row = 4*lg+i; reduce over lr via shfl) ----
#pragma unroll
    for (int i = 0; i < 4; ++i) {
      float rm = -__builtin_huge_valf();
#pragma unroll
      for (int nt = 0; nt < 4; ++nt) {
        s[nt][i] *= 0.125f;
        rm = fmaxf(rm, s[nt][i]);
      }
      rm = fmaxf(rm, __shfl_xor(rm, 1));
      rm = fmaxf(rm, __shfl_xor(rm, 2));
      rm = fmaxf(rm, __shfl_xor(rm, 4));
      rm = fmaxf(rm, __shfl_xor(rm, 8));
      float mnew = fmaxf(mrun[i], rm);
      float alpha = __expf(mrun[i] - mnew);
      float rs = 0.0f;
#pragma unroll
      for (int nt = 0; nt < 4; ++nt) {
        float p = __expf(s[nt][i] - mnew);
        s[nt][i] = p;
        rs += p;
      }
      rs += __shfl_xor(rs, 1);
      rs += __shfl_xor(rs, 2);
      rs += __shfl_xor(rs, 4);
      rs += __shfl_xor(rs, 8);
      lrun[i] = lrun[i] * alpha + rs;
      mrun[i] = mnew;
#pragma unroll
      for (int nt = 0; nt < 4; ++nt) oacc[nt][i] *= alpha;
    }

    __syncthreads();  // all waves done reading K tile -> safe to overwrite

    // ---- P -> KP (wave-private rows, 2 planes, swizzled) ----
#pragma unroll
    for (int nt = 0; nt < 4; ++nt)
#pragma unroll
      for (int i = 0; i < 4; ++i) {
        int qrow = w * 16 + 4 * lg + i;
        int kv = nt * 16 + lr;
        int kp = kv >> 3, j = kv & 7;
        int slt = kp ^ (qrow & 7);
        u16 h2, l2;
        split2(s[nt][i], h2, l2);
        KP[0][qrow][slt][j] = h2;
        KP[1][qrow][slt][j] = l2;
      }

    // ---- O += P V (A = own P rows, B = Vt cols) ----
    h8_t pf[2][2];
#pragma unroll
    for (int ks = 0; ks < 2; ++ks) {
      int row = w * 16 + lr;
      int slt = (ks * 4 + lg) ^ (row & 7);
      pf[ks][0] = *(const h8_t*)&KP[0][row][slt][0];
      pf[ks][1] = *(const h8_t*)&KP[1][row][slt][0];
    }
#pragma unroll
    for (int ntd = 0; ntd < 4; ++ntd) {
      const int col = ntd * 16 + lr;
#pragma unroll
      for (int ks = 0; ks < 2; ++ks) {
        int slt = (ks * 4 + lg) ^ (col & 7);
        h8_t vh = *(const h8_t*)&Vs[0][col][slt][0];
        h8_t vl = *(const h8_t*)&Vs[1][col][slt][0];
        oacc[ntd] = prod3(pf[ks][0], pf[ks][1], vh, vl, oacc[ntd]);
      }
    }
  }

  // ---- epilogue: normalize, split2, store planes [B,T,512] ----
#pragma unroll
  for (int i = 0; i < 4; ++i) {
    float inv = 1.0f / lrun[i];
    int t = qt * 64 + w * 16 + 4 * lg + i;
#pragma unroll
    for (int ntd = 0; ntd < 4; ++ntd) {
      int d = hh * 64 + ntd * 16 + lr;
      size_t idx = ((size_t)(b * 1024 + t)) * 512 + d;
      u16 h2, l2;
      split2(oacc[ntd][i] * inv, h2, l2);
      Oh[idx] = h2;
      Ol[idx] = l2;
    }
  }
}

// ---------------- fp32 vector GEMM (VQ-head precision anchor) ----------------
template <int BM, int BN, int WR, int EPI>
__global__ __launch_bounds__((BM / WR) * (BN / 64) * 64) void gemm_f32(
    const float* __restrict__ A, const float* __restrict__ Bmat,
    const float* __restrict__ bias, float* __restrict__ C, int M, int N, int K,
    const int* __restrict__ ep, const int* __restrict__ tot) {
  constexpr int BK = 16;
  constexpr int WN = BN / 64;
  constexpr int NW = (BM / WR) * WN;
  constexpr int NT = NW * 64;
  constexpr int RM = WR / 8;
  __shared__ __align__(16) float As[BK][BM + 4];
  __shared__ __align__(16) float Bs[BK][BN + 4];
  const int tid = threadIdx.x;
  const int w = tid >> 6, lane = tid & 63;
  const int wy = w / WN, wx = w % WN;
  const int ly = lane >> 3, lx = lane & 7;
  const int bm = blockIdx.y * BM;
  const int bn = blockIdx.x * BN;
  const int rbase = wy * WR + ly * RM;

  float acc[RM][8];
#pragma unroll
  for (int i = 0; i < RM; ++i)
#pragma unroll
    for (int j = 0; j < 8; ++j) acc[i][j] = 0.0f;

  for (int k0 = 0; k0 < K; k0 += BK) {
#pragma unroll
    for (int i = 0; i < (BM * BK / 4) / NT; ++i) {
      int idx = tid + i * NT;
      int r = idx >> 2, c4 = (idx & 3) << 2;
      const float4 v = *(const float4*)(A + (size_t)(bm + r) * K + k0 + c4);
      As[c4 + 0][r] = v.x;
      As[c4 + 1][r] = v.y;
      As[c4 + 2][r] = v.z;
      As[c4 + 3][r] = v.w;
    }
#pragma unroll
    for (int i = 0; i < (BN * BK / 4) / NT; ++i) {
      int idx = tid + i * NT;
      int r = idx >> 2, c4 = (idx & 3) << 2;
      const float4 v = *(const float4*)(Bmat + (size_t)(bn + r) * K + k0 + c4);
      Bs[c4 + 0][r] = v.x;
      Bs[c4 + 1][r] = v.y;
      Bs[c4 + 2][r] = v.z;
      Bs[c4 + 3][r] = v.w;
    }
    __syncthreads();
#pragma unroll
    for (int k = 0; k < BK; ++k) {
      float a[RM], b[8];
#pragma unroll
      for (int r4 = 0; r4 < RM; r4 += 4)
        *(float4*)&a[r4] = *(const float4*)&As[k][rbase + r4];
      *(float4*)&b[0] = *(const float4*)&Bs[k][wx * 64 + lx * 8];
      *(float4*)&b[4] = *(const float4*)&Bs[k][wx * 64 + lx * 8 + 4];
#pragma unroll
      for (int i = 0; i < RM; ++i)
#pragma unroll
        for (int j = 0; j < 8; ++j) acc[i][j] = fmaf(a[i], b[j], acc[i][j]);
    }
    __syncthreads();
  }

  const int ncol = bn + wx * 64 + lx * 8;
  float bb[8];
  if constexpr (EPI == E_BIAS) {
    *(float4*)&bb[0] = *(const float4*)(bias + ncol);
    *(float4*)&bb[4] = *(const float4*)(bias + ncol + 4);
  }
  float invt = 1.0f;
  if constexpr (EPI == E_VQ) {
    float t = 1.0f - 0.5f * (float)ep[0] / (float)tot[0];
    invt = 1.0f / fmaxf(0.5f, t);
  }
#pragma unroll
  for (int i = 0; i < RM; ++i) {
    const int m = bm + rbase + i;
    float o[8];
#pragma unroll
    for (int j = 0; j < 8; ++j) o[j] = acc[i][j];
    if constexpr (EPI == E_BIAS) {
#pragma unroll
      for (int j = 0; j < 8; ++j) o[j] += bb[j];
    } else if constexpr (EPI == E_VQ) {
#pragma unroll
      for (int j = 0; j < 8; ++j) o[j] *= invt;
    }
    *(float4*)(C + (size_t)m * N + ncol) = *(float4*)&o[0];
    *(float4*)(C + (size_t)m * N + ncol + 4) = *(float4*)&o[4];
  }
}

// ---------------- row kernels ----------------
DEV float wave_sum(float v) {
#pragma unroll
  for (int off = 1; off < 64; off <<= 1) v += __shfl_xor(v, off);
  return v;
}

DEV void store8_split2(u16* H, u16* L, size_t base, const float* t) {
  u16 vh[8], vl[8];
#pragma unroll
  for (int j = 0; j < 8; ++j) split2(t[j], vh[j], vl[j]);
  *(ushort4*)&H[base] = make_ushort4(vh[0], vh[1], vh[2], vh[3]);
  *(ushort4*)&H[base + 4] = make_ushort4(vh[4], vh[5], vh[6], vh[7]);
  *(ushort4*)&L[base] = make_ushort4(vl[0], vl[1], vl[2], vl[3]);
  *(ushort4*)&L[base + 4] = make_ushort4(vl[4], vl[5], vl[6], vl[7]);
}

__global__ __launch_bounds__(256) void ln_split2(const float* __restrict__ x,
                                                 const float* __restrict__ g,
                                                 const float* __restrict__ b,
                                                 u16* __restrict__ yh,
                                                 u16* __restrict__ yl) {
  const int row = blockIdx.x * 4 + (threadIdx.x >> 6);
  const int lane = threadIdx.x & 63;
  const float* xr = x + (size_t)row * DMODEL;
  float v[8];
  *(float4*)&v[0] = *(const float4*)(xr + lane * 8);
  *(float4*)&v[4] = *(const float4*)(xr + lane * 8 + 4);
  float s = 0.0f;
#pragma unroll
  for (int j = 0; j < 8; ++j) s += v[j];
  s = wave_sum(s);
  float mean = s * (1.0f / 512.0f);
  float s2 = 0.0f;
#pragma unroll
  for (int j = 0; j < 8; ++j) {
    float d = v[j] - mean;
    s2 += d * d;
  }
  s2 = wave_sum(s2);
  float rstd = 1.0f / sqrtf(s2 * (1.0f / 512.0f) + 1e-5f);
  float gg[8], bv[8];
  *(float4*)&gg[0] = *(const float4*)(g + lane * 8);
  *(float4*)&gg[4] = *(const float4*)(g + lane * 8 + 4);
  *(float4*)&bv[0] = *(const float4*)(b + lane * 8);
  *(float4*)&bv[4] = *(const float4*)(b + lane * 8 + 4);
  float t[8];
#pragma unroll
  for (int j = 0; j < 8; ++j) t[j] = (v[j] - mean) * rstd * gg[j] + bv[j];
  store8_split2(yh, yl, (size_t)row * DMODEL + lane * 8, t);
}

__global__ __launch_bounds__(256) void ln_l2_f32(const float* __restrict__ x,
                                                 const float* __restrict__ g,
                                                 const float* __restrict__ b,
                                                 float* __restrict__ y) {
  const int row = blockIdx.x * 4 + (threadIdx.x >> 6);
  const int lane = threadIdx.x & 63;
  const float* xr = x + (size_t)row * DMODEL;
  float v[8];
  *(float4*)&v[0] = *(const float4*)(xr + lane * 8);
  *(float4*)&v[4] = *(const float4*)(xr + lane * 8 + 4);
  float s = 0.0f;
#pragma unroll
  for (int j = 0; j < 8; ++j) s += v[j];
  s = wave_sum(s);
  float mean = s * (1.0f / 512.0f);
  float s2 = 0.0f;
#pragma unroll
  for (int j = 0; j < 8; ++j) {
    float d = v[j] - mean;
    s2 += d * d;
  }
  s2 = wave_sum(s2);
  float rstd = 1.0f / sqrtf(s2 * (1.0f / 512.0f) + 1e-5f);
  float gg[8], bv[8];
  *(float4*)&gg[0] = *(const float4*)(g + lane * 8);
  *(float4*)&gg[4] = *(const float4*)(g + lane * 8 + 4);
  *(float4*)&bv[0] = *(const float4*)(b + lane * 8);
  *(float4*)&bv[4] = *(const float4*)(b + lane * 8 + 4);
  float t[8];
#pragma unroll
  for (int j = 0; j < 8; ++j) t[j] = (v[j] - mean) * rstd * gg[j] + bv[j];
  float n2 = 0.0f;
#pragma unroll
  for (int j = 0; j < 8; ++j) n2 += t[j] * t[j];
  n2 = wave_sum(n2);
  float den = fmaxf(sqrtf(n2), 1e-12f);
#pragma unroll
  for (int j = 0; j < 8; ++j) t[j] /= den;
  float* yr = y + (size_t)row * DMODEL;
  *(float4*)(yr + lane * 8) = *(float4*)&t[0];
  *(float4*)(yr + lane * 8 + 4) = *(float4*)&t[4];
}

__global__ __launch_bounds__(256) void l2_split2(const float* __restrict__ x,
                                                 u16* __restrict__ yh,
                                                 u16* __restrict__ yl) {
  const int row = blockIdx.x * 4 + (threadIdx.x >> 6);
  const int lane = threadIdx.x & 63;
  const float* xr = x + (size_t)row * DMODEL;
  float v[8];
  *(float4*)&v[0] = *(const float4*)(xr + lane * 8);
  *(float4*)&v[4] = *(const float4*)(xr + lane * 8 + 4);
  float n2 = 0.0f;
#pragma unroll
  for (int j = 0; j < 8; ++j) n2 += v[j] * v[j];
  n2 = wave_sum(n2);
  float den = fmaxf(sqrtf(n2), 1e-12f);
#pragma unroll
  for (int j = 0; j < 8; ++j) v[j] /= den;
  store8_split2(yh, yl, (size_t)row * DMODEL + lane * 8, v);
}

__global__ __launch_bounds__(256) void l2_f32(const float* __restrict__ x,
                                              float* __restrict__ y) {
  const int row = blockIdx.x * 4 + (threadIdx.x >> 6);
  const int lane = threadIdx.x & 63;
  const float* xr = x + (size_t)row * DMODEL;
  float v[8];
  *(float4*)&v[0] = *(const float4*)(xr + lane * 8);
  *(float4*)&v[4] = *(const float4*)(xr + lane * 8 + 4);
  float n2 = 0.0f;
#pragma unroll
  for (int j = 0; j < 8; ++j) n2 += v[j] * v[j];
  n2 = wave_sum(n2);
  float den = fmaxf(sqrtf(n2), 1e-12f);
#pragma unroll
  for (int j = 0; j < 8; ++j) v[j] /= den;
  float* yr = y + (size_t)row * DMODEL;
  *(float4*)(yr + lane * 8) = *(float4*)&v[0];
  *(float4*)(yr + lane * 8 + 4) = *(float4*)&v[4];
}

// softmax over rows of 1024, in-place on 2 fp16 planes
__global__ __launch_bounds__(256) void softmax2(u16* __restrict__ H,
                                                u16* __restrict__ L) {
  const int row = blockIdx.x;
  const int tid = threadIdx.x;
  const size_t base = (size_t)row * 1024 + tid * 4;
  ushort4 qh = *(const ushort4*)&H[base];
  ushort4 ql = *(const ushort4*)&L[base];
  float v0 = h2f(qh.x) + h2f(ql.x);
  float v1 = h2f(qh.y) + h2f(ql.y);
  float v2 = h2f(qh.z) + h2f(ql.z);
  float v3 = h2f(qh.w) + h2f(ql.w);
  float mx = fmaxf(fmaxf(v0, v1), fmaxf(v2, v3));
#pragma unroll
  for (int off = 1; off < 64; off <<= 1) mx = fmaxf(mx, __shfl_xor(mx, off));
  __shared__ float red[4];
  const int wv = tid >> 6;
  if ((tid & 63) == 0) red[wv] = mx;
  __syncthreads();
  mx = fmaxf(fmaxf(red[0], red[1]), fmaxf(red[2], red[3]));
  float e0 = __expf(v0 - mx), e1 = __expf(v1 - mx), e2 = __expf(v2 - mx),
        e3 = __expf(v3 - mx);
  float s = e0 + e1 + e2 + e3;
#pragma unroll
  for (int off = 1; off < 64; off <<= 1) s += __shfl_xor(s, off);
  __syncthreads();
  if ((tid & 63) == 0) red[wv] = s;
  __syncthreads();
  s = red[0] + red[1] + red[2] + red[3];
  float inv = 1.0f / s;
  u16 ah[4], al[4];
  split2(e0 * inv, ah[0], al[0]);
  split2(e1 * inv, ah[1], al[1]);
  split2(e2 * inv, ah[2], al[2]);
  split2(e3 * inv, ah[3], al[3]);
  *(ushort4*)&H[base] = make_ushort4(ah[0], ah[1], ah[2], ah[3]);
  *(ushort4*)&L[base] = make_ushort4(al[0], al[1], al[2], al[3]);
}

// generic fp32 -> 2 fp16 planes splitter (n4 = n/4)
__global__ __launch_bounds__(256) void split2_k(const float* __restrict__ src,
                                                u16* __restrict__ H,
                                                u16* __restrict__ L, int n4) {
  for (int e = blockIdx.x * 256 + threadIdx.x; e < n4; e += gridDim.x * 256) {
    float4 v = *(const float4*)(src + (size_t)e * 4);
    u16 ah[4], al[4];
    split2(v.x, ah[0], al[0]);
    split2(v.y, ah[1], al[1]);
    split2(v.z, ah[2], al[2]);
    split2(v.w, ah[3], al[3]);
    *(ushort4*)&H[(size_t)e * 4] = make_ushort4(ah[0], ah[1], ah[2], ah[3]);
    *(ushort4*)&L[(size_t)e * 4] = make_ushort4(al[0], al[1], al[2], al[3]);
  }
}

// transpose codebook [1024][512] -> cbT [512][1024], split into 2 planes
__global__ __launch_bounds__(256) void tsplit_cb(const float* __restrict__ cb,
                                                 u16* __restrict__ th,
                                                 u16* __restrict__ tl) {
  const int c = blockIdx.x;
  const int t = threadIdx.x;
  u16 ah[4], al[4];
#pragma unroll
  for (int j = 0; j < 4; ++j) {
    float v = cb[(size_t)(4 * t + j) * 512 + c];
    split2(v, ah[j], al[j]);
  }
  const size_t base = (size_t)c * 1024 + 4 * t;
  *(ushort4*)&th[base] = make_ushort4(ah[0], ah[1], ah[2], ah[3]);
  *(ushort4*)&tl[base] = make_ushort4(al[0], al[1], al[2], al[3]);
}

__global__ __launch_bounds__(256) void vq_finalize(
    const float* __restrict__ logits, const float* __restrict__ patterns,
    float* __restrict__ emb, float* __restrict__ assign,
    float* __restrict__ idxf) {
  const int row = blockIdx.x * 4 + (threadIdx.x >> 6);
  const int lane = threadIdx.x & 63;
  const float* lr = logits + (size_t)row * NPAT;
  float best = -__builtin_huge_valf();
  int bi = 0;
#pragma unroll
  for (int jj = 0; jj < 8; ++jj) {
    int j = lane + jj * 64;
    float v = lr[j];
    if (v > best) {
      best = v;
      bi = j;
    }
  }
#pragma unroll
  for (int off = 1; off < 64; off <<= 1) {
    float ob = __shfl_xor(best, off);
    int oi = __shfl_xor(bi, off);
    if (ob > best || (ob == best && oi < bi)) {
      best = ob;
      bi = oi;
    }
  }
  const float* pr = patterns + (size_t)bi * DMODEL;
#pragma unroll
  for (int g = 0; g < 2; ++g) {
    int c = lane * 8 + g * 4;
    float4 pv = *(const float4*)(pr + c);
    *(float4*)(emb + (size_t)row * DMODEL + c) = pv;
    float4 av;
    av.x = (c + 0 == bi) ? 1.0f : 0.0f;
    av.y = (c + 1 == bi) ? 1.0f : 0.0f;
    av.z = (c + 2 == bi) ? 1.0f : 0.0f;
    av.w = (c + 3 == bi) ? 1.0f : 0.0f;
    *(float4*)(assign + (size_t)row * NPAT + c) = av;
  }
  if (lane == 0) idxf[row] = (float)bi;
}

// ---------------- host launch ----------------
extern "C" void kernel_launch(void* const* d_in, const int* in_sizes, int n_in,
                              void* d_out, int out_size, void* d_ws,
                              size_t ws_size, hipStream_t stream) {
  (void)in_sizes;
  (void)n_in;
  (void)out_size;
  (void)ws_size;
  const float* x = (const float*)d_in[0];
  const float* gumbel = (const float*)d_in[1];
  const float* sym_w = (const float*)d_in[2];
  const float* sym_b = (const float*)d_in[3];
  const float* codebook = (const float*)d_in[4];
  const float* pos_enc = (const float*)d_in[5];
  const float* attn_in_w = (const float*)d_in[6];
  const float* attn_in_b = (const float*)d_in[7];
  const float* attn_out_w = (const float*)d_in[8];
  const float* attn_out_b = (const float*)d_in[9];
  const float* n1_g = (const float*)d_in[10];
  const float* n1_b = (const float*)d_in[11];
  const float* n2_g = (const float*)d_in[12];
  const float* n2_b = (const float*)d_in[13];
  const float* ffn_w1 = (const float*)d_in[14];
  const float* ffn_b1 = (const float*)d_in[15];
  const float* ffn_w2 = (const float*)d_in[16];
  const float* ffn_b2 = (const float*)d_in[17];
  const float* q_w = (const float*)d_in[18];
  const float* q_b = (const float*)d_in[19];
  const float* qln_g = (const float*)d_in[20];
  const float* qln_b = (const float*)d_in[21];
  const float* patterns = (const float*)d_in[22];
  const int* epoch = (const int*)d_in[23];
  const int* tot = (const int*)d_in[24];

  float* out = (float*)d_out;
  float* emb = out;               // [8192,512]
  float* assign = out + 4194304;  // [8192,512]
  float* logits = out + 8388608;  // [8192,512]
  float* h = out + 12582912;      // [8192,512]
  float* idxf = out + 16777216;   // [8192]

  float* ws_f = (float*)d_ws;
  // A region @0 (18.87M floats = 37.75M u16)
  u16* a16 = (u16*)ws_f;
  // B region @18.87M floats (6.29M floats = 12.58M u16)
  float* bF = ws_f + 18874368;
  u16* b16 = (u16*)bF;
  u16 *hnH = b16, *hnL = b16 + 4194304;
  // W region @25.17M floats (2.36M u16 capacity)
  float* wF = ws_f + 25165824;
  u16* w16 = (u16*)wF;

  // ---- symbolization ----
  u16 *xH = a16, *xL = a16 + 8388608;
  split2_k<<<2048, 256, 0, stream>>>(x, xH, xL, 2097152);
  split2_k<<<512, 256, 0, stream>>>(sym_w, w16, w16 + 524288, 131072);
  gemm_mf<E_BIAS><<<256, 256, 0, stream>>>(xH, xL, w16, w16 + 524288, sym_b,
                                           nullptr, bF, nullptr, nullptr, 512,
                                           1024, 1024, 1024, 4);
  l2_split2<<<256, 256, 0, stream>>>(codebook, w16, w16 + 524288);
  u16 *hpH = a16, *hpL = a16 + 4194304;
  l2_split2<<<2048, 256, 0, stream>>>(bF, hpH, hpL);
  u16 *sH = a16 + 12582912, *sL = a16 + 20971520;
  gemm_mf<E_GUM2><<<512, 256, 0, stream>>>(hpH, hpL, w16, w16 + 524288,
                                           nullptr, gumbel, nullptr, sH, sL,
                                           1024, 512, 512, 512, 8);
  softmax2<<<8192, 256, 0, stream>>>(sH, sL);
  tsplit_cb<<<512, 256, 0, stream>>>(codebook, w16, w16 + 524288);
  gemm_mf<E_POS><<<256, 256, 0, stream>>>(sH, sL, w16, w16 + 524288, nullptr,
                                          pos_enc, h, nullptr, nullptr, 512,
                                          1024, 1024, 1024, 4);

  // ---- transformer layers ----
  u16 *qkvH = a16, *qkvL = a16 + 12582912;
  u16* w1p = a16 + 33554432;           // 2 x 1048576 u16 (after qkv/mid)
  u16* w2p = b16 + 8388608;            // 2 x 1048576 u16 (after hn planes)
  u16 *pH = a16, *pL = a16 + 16777216;  // FFN mid [8192,2048] x2 planes

  for (int l = 0; l < 4; ++l) {
    const float* inw = attn_in_w + (size_t)l * 1536 * 512;
    const float* inb = attn_in_b + (size_t)l * 1536;
    const float* outw = attn_out_w + (size_t)l * 512 * 512;
    const float* outb = attn_out_b + (size_t)l * 512;
    const float* w1 = ffn_w1 + (size_t)l * 2048 * 512;
    const float* b1 = ffn_b1 + (size_t)l * 2048;
    const float* w2 = ffn_w2 + (size_t)l * 512 * 2048;
    const float* b2 = ffn_b2 + (size_t)l * 512;

    ln_split2<<<2048, 256, 0, stream>>>(h, n1_g + l * 512, n1_b + l * 512,
                                        hnH, hnL);
    split2_k<<<1024, 256, 0, stream>>>(inw, w16, w16 + 786432, 196608);
    gemm_mf<E_QKV2><<<768, 256, 0, stream>>>(hnH, hnL, w16, w16 + 786432, inb,
                                             nullptr, nullptr, qkvH, qkvL,
                                             1536, 512, 512, 512, 12);
    flash_mfma<<<1024, 256, 0, stream>>>(qkvH, qkvL, hnH, hnL);
    split2_k<<<256, 256, 0, stream>>>(outw, w16, w16 + 262144, 65536);
    gemm_mf<E_RES><<<256, 256, 0, stream>>>(hnH, hnL, w16, w16 + 262144, outb,
                                            h, h, nullptr, nullptr, 512, 512,
                                            512, 512, 4);
    ln_split2<<<2048, 256, 0, stream>>>(h, n2_g + l * 512, n2_b + l * 512,
                                        hnH, hnL);
    split2_k<<<1024, 256, 0, stream>>>(w1, w1p, w1p + 1048576, 262144);
    split2_k<<<1024, 256, 0, stream>>>(w2, w2p, w2p + 1048576, 262144);
    // GELU: single N=2048 GEMM into full-width mid planes
    gemm_mf<E_GELU2><<<1024, 256, 0, stream>>>(hnH, hnL, w1p, w1p + 1048576,
                                               b1, nullptr, nullptr, pH, pL,
                                               2048, 512, 512, 512, 16);
    // w2: single K=2048 GEMM with residual
    gemm_mf<E_RES><<<256, 256, 0, stream>>>(pH, pL, w2p, w2p + 1048576, b2, h,
                                            h, nullptr, nullptr, 512, 2048,
                                            2048, 2048, 4);
  }

  // ---- VQ head (fp32-vector precision anchor) ----
  gemm_f32<64, 128, 32, E_BIAS><<<dim3(4, 128), 256, 0, stream>>>(
      h, q_w, q_b, bF, 8192, 512, 512, nullptr, nullptr);
  ln_l2_f32<<<2048, 256, 0, stream>>>(bF, qln_g, qln_b, bF);
  l2_f32<<<128, 256, 0, stream>>>(patterns, wF);
  gemm_f32<64, 128, 32, E_VQ><<<dim3(4, 128), 256, 0, stream>>>(
      bF, wF, nullptr, logits, 8192, 512, 512, epoch, tot);
  vq_finalize<<<2048, 256, 0, stream>>>(logits, patterns, emb, assign, idxf);
}

// Round 15
// 1617.654 us; speedup vs baseline: 1.9114x; 1.0917x over previous
//
#include <hip/hip_runtime.h>

#define DEV __device__ __forceinline__

typedef unsigned short u16;
typedef unsigned int u32;
typedef __attribute__((ext_vector_type(8))) _Float16 h8_t;  // 8 f16 (4 VGPR)
typedef __attribute__((ext_vector_type(4))) float f4_t;

constexpr int T_SEQ = 1024;
constexpr int DMODEL = 512;
constexpr int NPAT = 512;

// ---------------- epilogue modes ----------------
enum {
  E_BIAS = 0,
  E_VQ = 5,
  E_RES = 6,
  E_POS = 8,
  E_GUM2 = 9,
  E_GELU2 = 10,
  E_QKV2 = 11
};

// ---------------- fp16 double-split helpers (err ~2^-22, fp32-grade) ---------
DEV float h2f(u16 h) { return (float)__builtin_bit_cast(_Float16, h); }
DEV void split2(float x, u16& h, u16& l) {
  _Float16 hh = (_Float16)x;
  float r = x - (float)hh;
  _Float16 ll = (_Float16)r;
  h = __builtin_bit_cast(u16, hh);
  l = __builtin_bit_cast(u16, ll);
}

DEV f4_t mfh(h8_t a, h8_t b, f4_t c) {
  return __builtin_amdgcn_mfma_f32_16x16x32_f16(a, b, c, 0, 0, 0);
}
// 3-product double-split accumulate: AB = AhBh + AhBl + AlBh (+O(2^-22))
DEV f4_t prod3(h8_t ah, h8_t al, h8_t bh, h8_t bl, f4_t c) {
  c = mfh(ah, bh, c);
  c = mfh(ah, bl, c);
  c = mfh(al, bh, c);
  return c;
}

// async global->LDS, 16B per lane; LDS dest = base + lane*16 (wave-uniform base)
typedef const __attribute__((address_space(1))) unsigned char* gas_t;
typedef __attribute__((address_space(3))) unsigned char* las_t;
DEV void gload16(const u16* g, u16* l) {
  __builtin_amdgcn_global_load_lds((gas_t)(const void*)g, (las_t)(void*)l, 16,
                                   0, 0);
}

// ---------------- MFMA GEMM, fp16 double-split (fp32-accurate) ---------------
// C[M,N] = A[M,K]*B[N,K]^T via 3 f16 products. BN=128 fixed.
// BM=64 (R13-proven): 2 waves-rows x 64x64/wave? -> MT=2, LDS 48KB, 3 blk/CU.
// BM=128 (R14): MT=4, 16 ds_reads feed 48 MFMA, LDS 64KB, 2 blk/CU.
// 2-phase prefetch, one barrier/iter, bijective XCD swizzle.
template <int BM, int EPI>
__global__ __launch_bounds__(256, BM == 64 ? 3 : 2) void gemm_mf(
    const u16* __restrict__ Ah, const u16* __restrict__ Al,
    const u16* __restrict__ Bh, const u16* __restrict__ Bl,
    const float* __restrict__ bias, const float* __restrict__ res,
    float* __restrict__ Cf, u16* __restrict__ Ch, u16* __restrict__ Cl, int N,
    int KK, int lda, int ldb, int gx, const int* __restrict__ ep,
    const int* __restrict__ tot) {
  constexpr int MT = BM / 32;       // m-frags per wave
  constexpr int CPP = BM / 16;      // A stage chunks per plane
  __shared__ __align__(16) u16 AsH[2][BM][4][8], AsL[2][BM][4][8];
  __shared__ __align__(16) u16 BsH[2][128][4][8], BsL[2][128][4][8];
  const int tid = threadIdx.x;
  const int w = tid >> 6, lane = tid & 63;
  const int wy = w >> 1, wx = w & 1;
  const int lr = lane & 15, lg = lane >> 4;

  // bijective XCD swizzle (all grids divisible by 8)
  const int nwg = gridDim.x;
  const int bid = blockIdx.x;
  const int qq = nwg >> 3;
  const int wg = (bid & 7) * qq + (bid >> 3);
  const int by = wg / gx, bx = wg % gx;
  const int bm = by * BM, bn = bx * 128;

  const int rowl = lane >> 2, slot4 = lane & 3;  // per-lane stage coords

  auto STAGE = [&](int k0, int buf) {
#pragma unroll
    for (int it = 0; it < CPP / 2; ++it) {  // A: 2*CPP chunks
      const int f = w + 4 * it;
      const int plane = f / CPP;
      const int ch = f % CPP;
      const int row = ch * 16 + rowl;
      const int kp = slot4 ^ ((row >> 1) & 3);
      const size_t g = (size_t)(bm + row) * lda + k0 + kp * 8;
      if (plane == 0)
        gload16(&Ah[g], &AsH[buf][0][0][0] + ch * 512);
      else
        gload16(&Al[g], &AsL[buf][0][0][0] + ch * 512);
    }
#pragma unroll
    for (int it = 0; it < 4; ++it) {  // B: 16 chunks (2 planes x 8)
      const int f = w + 4 * it;
      const int plane = f >> 3;
      const int ch = f & 7;
      const int row = ch * 16 + rowl;
      const int kp = slot4 ^ ((row >> 1) & 3);
      const size_t g = (size_t)(bn + row) * ldb + k0 + kp * 8;
      if (plane == 0)
        gload16(&Bh[g], &BsH[buf][0][0][0] + ch * 512);
      else
        gload16(&Bl[g], &BsL[buf][0][0][0] + ch * 512);
    }
  };

  f4_t acc[MT][4];
#pragma unroll
  for (int mt = 0; mt < MT; ++mt)
#pragma unroll
    for (int nt = 0; nt < 4; ++nt) acc[mt][nt] = (f4_t){0.f, 0.f, 0.f, 0.f};

  const int nsteps = KK / 32;
  STAGE(0, 0);
  __syncthreads();
  for (int t = 0; t < nsteps; ++t) {
    const int cur = t & 1;
    if (t + 1 < nsteps) STAGE((t + 1) * 32, cur ^ 1);

    h8_t fah[MT], fal[MT], fbh[4], fbl[4];
#pragma unroll
    for (int mt = 0; mt < MT; ++mt) {
      int row = wy * (BM / 2) + mt * 16 + lr;
      int slot = lg ^ ((row >> 1) & 3);
      fah[mt] = *(const h8_t*)&AsH[cur][row][slot][0];
      fal[mt] = *(const h8_t*)&AsL[cur][row][slot][0];
    }
#pragma unroll
    for (int nt = 0; nt < 4; ++nt) {
      int col = wx * 64 + nt * 16 + lr;
      int slot = lg ^ ((col >> 1) & 3);
      fbh[nt] = *(const h8_t*)&BsH[cur][col][slot][0];
      fbl[nt] = *(const h8_t*)&BsL[cur][col][slot][0];
    }
#pragma unroll
    for (int mt = 0; mt < MT; ++mt)
#pragma unroll
      for (int nt = 0; nt < 4; ++nt)
        acc[mt][nt] = prod3(fah[mt], fal[mt], fbh[nt], fbl[nt], acc[mt][nt]);
    __syncthreads();
  }

  // ---- epilogue (C frag: col = lane&15, row = 4*(lane>>4)+i) ----
  float bv[4];
  if constexpr (EPI == E_BIAS || EPI == E_RES || EPI == E_GELU2 ||
                EPI == E_QKV2) {
#pragma unroll
    for (int nt = 0; nt < 4; ++nt) bv[nt] = bias[bn + wx * 64 + nt * 16 + lr];
  }
  float invt = 1.0f;
  if constexpr (EPI == E_VQ) {
    float tt = 1.0f - 0.5f * (float)ep[0] / (float)tot[0];
    invt = 1.0f / fmaxf(0.5f, tt);
  }
#pragma unroll
  for (int mt = 0; mt < MT; ++mt)
#pragma unroll
    for (int nt = 0; nt < 4; ++nt) {
      const int c = bn + wx * 64 + nt * 16 + lr;
#pragma unroll
      for (int i = 0; i < 4; ++i) {
        const int m = bm + wy * (BM / 2) + mt * 16 + 4 * lg + i;
        const size_t idx = (size_t)m * N + c;
        float v = acc[mt][nt][i];
        if constexpr (EPI == E_BIAS) {
          Cf[idx] = v + bv[nt];
        } else if constexpr (EPI == E_VQ) {
          Cf[idx] = v * invt;
        } else if constexpr (EPI == E_RES) {
          Cf[idx] = v + bv[nt] + res[idx];
        } else if constexpr (EPI == E_POS) {
          Cf[idx] = v + res[(size_t)(m & 1023) * N + c];
        } else if constexpr (EPI == E_GUM2) {
          float t = 4.0f * v + 2.0f * res[idx];
          u16 h2, l2;
          split2(t, h2, l2);
          Ch[idx] = h2;
          Cl[idx] = l2;
        } else if constexpr (EPI == E_GELU2) {
          float t = v + bv[nt];
          float g = 0.5f * t * (1.0f + erff(t * 0.7071067811865476f));
          u16 h2, l2;
          split2(g, h2, l2);
          Ch[idx] = h2;
          Cl[idx] = l2;
        } else if constexpr (EPI == E_QKV2) {
          float t = v + bv[nt];
          u16 h2, l2;
          split2(t, h2, l2);
          size_t o;
          if (c < 512) {
            o = (size_t)m * 512 + c;                       // Q [B,T,512]
          } else if (c < 1024) {
            o = 4194304 + (size_t)m * 512 + (c - 512);     // K [B,T,512]
          } else {
            int cc = c - 1024, hh2 = cc >> 6, dd = cc & 63;
            int bb2 = m >> 10, tt2 = m & 1023;
            o = 8388608 +
                (((size_t)(bb2 * 8 + hh2) * 64 + dd) << 10) + tt2;  // Vt
          }
          Ch[o] = h2;
          Cl[o] = l2;
        }
      }
    }
}

// ---------------- MFMA flash attention (fp16 double-split) -------------------
// 1-D grid 1024, XCD-swizzled (b = bid&7 -> K/V L2-resident per XCD).
// Staging via global_load_lds. P aliases the K tile. LDS 32KB.
__global__ __launch_bounds__(256, 4) void flash_mfma(
    const u16* __restrict__ QKVh, const u16* __restrict__ QKVl,
    u16* __restrict__ Oh, u16* __restrict__ Ol) {
  __shared__ __align__(16) u16 KP[2][64][8][8];  // K tile, then P tile
  __shared__ __align__(16) u16 Vs[2][64][8][8];
  const int tid = threadIdx.x;
  const int w = tid >> 6, lane = tid & 63;
  const int lr = lane & 15, lg = lane >> 4;
  const int bid = blockIdx.x;
  const int b = bid & 7;
  const int slot_b = bid >> 3;  // 0..127
  const int hh = slot_b >> 4;   // 0..7
  const int qt = slot_b & 15;   // 0..15

  const u16* Qh = QKVh;
  const u16* Ql = QKVl;
  const u16* Kh = QKVh + 4194304;
  const u16* Kl = QKVl + 4194304;
  const u16* Vh = QKVh + 8388608;
  const u16* Vl = QKVl + 8388608;

  // Q fragments (A-op: m = lr, k-packet = lg), hoisted for all kt
  h8_t qf[2][2];
  {
    size_t g =
        ((size_t)(b * 1024 + qt * 64 + w * 16 + lr)) * 512 + hh * 64 + lg * 8;
    qf[0][0] = *(const h8_t*)&Qh[g];
    qf[0][1] = *(const h8_t*)&Ql[g];
    qf[1][0] = *(const h8_t*)&Qh[g + 32];
    qf[1][1] = *(const h8_t*)&Ql[g + 32];
  }

  f4_t oacc[4];
#pragma unroll
  for (int nt = 0; nt < 4; ++nt) oacc[nt] = (f4_t){0.f, 0.f, 0.f, 0.f};
  float mrun[4], lrun[4];
#pragma unroll
  for (int i = 0; i < 4; ++i) {
    mrun[i] = -__builtin_huge_valf();
    lrun[i] = 0.0f;
  }

  const int rowl8 = lane >> 3, slot8 = lane & 7;  // stage coords (8 rows/chunk)

  for (int kt = 0; kt < 16; ++kt) {
    __syncthreads();  // prior PV done reading Vs + KP(P)
    // ---- stage K tile + Vt tile via global_load_lds: 32 x 1KB chunks ----
#pragma unroll
    for (int it = 0; it < 4; ++it) {
      const int f = w + 4 * it;
      const int plane = f >> 3, ch = f & 7;
      const int row = ch * 8 + rowl8;
      const int kp = slot8 ^ (row & 7);
      const size_t gk =
          ((size_t)(b * 1024 + kt * 64 + row)) * 512 + hh * 64 + kp * 8;
      if (plane == 0)
        gload16(&Kh[gk], &KP[0][0][0][0] + ch * 512);
      else
        gload16(&Kl[gk], &KP[1][0][0][0] + ch * 512);
    }
#pragma unroll
    for (int it = 0; it < 4; ++it) {
      const int f = w + 4 * it;
      const int plane = f >> 3, ch = f & 7;
      const int row = ch * 8 + rowl8;
      const int kp = slot8 ^ (row & 7);
      const size_t gv =
          ((size_t)((b * 8 + hh) * 64 + row)) * 1024 + kt * 64 + kp * 8;
      if (plane == 0)
        gload16(&Vh[gv], &Vs[0][0][0][0] + ch * 512);
      else
        gload16(&Vl[gv], &Vs[1][0][0][0] + ch * 512);
    }
    __syncthreads();

    // ---- S = Q K^T : 4 n-tiles x 2 k-slices x 3 products ----
    f4_t s[4];
#pragma unroll
    for (int nt = 0; nt < 4; ++nt) {
      s[nt] = (f4_t){0.f, 0.f, 0.f, 0.f};
      const int col = nt * 16 + lr;
#pragma unroll
      for (int ks = 0; ks < 2; ++ks) {
        int slt = (ks * 4 + lg) ^ (col & 7);
        h8_t kh = *(const h8_t*)&KP[0][col][slt][0];
        h8_t kl = *(const h8_t*)&KP[1][col][slt][0];
        s[nt] = prod3(qf[ks][0], qf[ks][1], kh, kl, s[nt]);
      }
    }

    // ---- online softmax (row = 4*lg+i; reduce over lr via shfl) ----
#pragma unroll
    for (int i = 0; i < 4; ++i) {
      float rm = -__builtin_huge_valf();
#pragma unroll
      for (int nt = 0; nt < 4; ++nt) {
        s[nt][i] *= 0.125f;
        rm = fmaxf(rm, s[nt][i]);
      }
      rm = fmaxf(rm, __shfl_xor(rm, 1));
      rm = fmaxf(rm, __shfl_xor(rm, 2));
      rm = fmaxf(rm, __shfl_xor(rm, 4));
      rm = fmaxf(rm, __shfl_xor(rm, 8));
      float mnew = fmaxf(mrun[i], rm);
      float alpha = __expf(mrun[i] - mnew);
      float rs = 0.0f;
#pragma unroll
      for (int nt = 0; nt < 4; ++nt) {
        float p = __expf(s[nt][i] - mnew);
        s[nt][i] = p;
        rs += p;
      }
      rs += __shfl_xor(rs, 1);
      rs += __shfl_xor(rs, 2);
      rs += __shfl_xor(rs, 4);
      rs += __shfl_xor(rs, 8);
      lrun[i] = lrun[i] * alpha + rs;
      mrun[i] = mnew;
#pragma unroll
      for (int nt = 0; nt < 4; ++nt) oacc[nt][i] *= alpha;
    }

    __syncthreads();  // all waves done reading K tile -> safe to overwrite

    // ---- P -> KP (wave-private rows, 2 planes, swizzled) ----
#pragma unroll
    for (int nt = 0; nt < 4; ++nt)
#pragma unroll
      for (int i = 0; i < 4; ++i) {
        int qrow = w * 16 + 4 * lg + i;
        int kv = nt * 16 + lr;
        int kp = kv >> 3, j = kv & 7;
        int slt = kp ^ (qrow & 7);
        u16 h2, l2;
        split2(s[nt][i], h2, l2);
        KP[0][qrow][slt][j] = h2;
        KP[1][qrow][slt][j] = l2;
      }

    // ---- O += P V (A = own P rows, B = Vt cols) ----
    h8_t pf[2][2];
#pragma unroll
    for (int ks = 0; ks < 2; ++ks) {
      int row = w * 16 + lr;
      int slt = (ks * 4 + lg) ^ (row & 7);
      pf[ks][0] = *(const h8_t*)&KP[0][row][slt][0];
      pf[ks][1] = *(const h8_t*)&KP[1][row][slt][0];
    }
#pragma unroll
    for (int ntd = 0; ntd < 4; ++ntd) {
      const int col = ntd * 16 + lr;
#pragma unroll
      for (int ks = 0; ks < 2; ++ks) {
        int slt = (ks * 4 + lg) ^ (col & 7);
        h8_t vh = *(const h8_t*)&Vs[0][col][slt][0];
        h8_t vl = *(const h8_t*)&Vs[1][col][slt][0];
        oacc[ntd] = prod3(pf[ks][0], pf[ks][1], vh, vl, oacc[ntd]);
      }
    }
  }

  // ---- epilogue: normalize, split2, store planes [B,T,512] ----
#pragma unroll
  for (int i = 0; i < 4; ++i) {
    float inv = 1.0f / lrun[i];
    int t = qt * 64 + w * 16 + 4 * lg + i;
#pragma unroll
    for (int ntd = 0; ntd < 4; ++ntd) {
      int d = hh * 64 + ntd * 16 + lr;
      size_t idx = ((size_t)(b * 1024 + t)) * 512 + d;
      u16 h2, l2;
      split2(oacc[ntd][i] * inv, h2, l2);
      Oh[idx] = h2;
      Ol[idx] = l2;
    }
  }
}

// ---------------- row kernels ----------------
DEV float wave_sum(float v) {
#pragma unroll
  for (int off = 1; off < 64; off <<= 1) v += __shfl_xor(v, off);
  return v;
}

DEV void store8_split2(u16* H, u16* L, size_t base, const float* t) {
  u16 vh[8], vl[8];
#pragma unroll
  for (int j = 0; j < 8; ++j) split2(t[j], vh[j], vl[j]);
  *(ushort4*)&H[base] = make_ushort4(vh[0], vh[1], vh[2], vh[3]);
  *(ushort4*)&H[base + 4] = make_ushort4(vh[4], vh[5], vh[6], vh[7]);
  *(ushort4*)&L[base] = make_ushort4(vl[0], vl[1], vl[2], vl[3]);
  *(ushort4*)&L[base + 4] = make_ushort4(vl[4], vl[5], vl[6], vl[7]);
}

__global__ __launch_bounds__(256) void ln_split2(const float* __restrict__ x,
                                                 const float* __restrict__ g,
                                                 const float* __restrict__ b,
                                                 u16* __restrict__ yh,
                                                 u16* __restrict__ yl) {
  const int row = blockIdx.x * 4 + (threadIdx.x >> 6);
  const int lane = threadIdx.x & 63;
  const float* xr = x + (size_t)row * DMODEL;
  float v[8];
  *(float4*)&v[0] = *(const float4*)(xr + lane * 8);
  *(float4*)&v[4] = *(const float4*)(xr + lane * 8 + 4);
  float s = 0.0f;
#pragma unroll
  for (int j = 0; j < 8; ++j) s += v[j];
  s = wave_sum(s);
  float mean = s * (1.0f / 512.0f);
  float s2 = 0.0f;
#pragma unroll
  for (int j = 0; j < 8; ++j) {
    float d = v[j] - mean;
    s2 += d * d;
  }
  s2 = wave_sum(s2);
  float rstd = 1.0f / sqrtf(s2 * (1.0f / 512.0f) + 1e-5f);
  float gg[8], bv[8];
  *(float4*)&gg[0] = *(const float4*)(g + lane * 8);
  *(float4*)&gg[4] = *(const float4*)(g + lane * 8 + 4);
  *(float4*)&bv[0] = *(const float4*)(b + lane * 8);
  *(float4*)&bv[4] = *(const float4*)(b + lane * 8 + 4);
  float t[8];
#pragma unroll
  for (int j = 0; j < 8; ++j) t[j] = (v[j] - mean) * rstd * gg[j] + bv[j];
  store8_split2(yh, yl, (size_t)row * DMODEL + lane * 8, t);
}

// LN + l2norm -> 2 fp16 planes (VQ head Q)
__global__ __launch_bounds__(256) void ln_l2_split2(
    const float* __restrict__ x, const float* __restrict__ g,
    const float* __restrict__ b, u16* __restrict__ yh, u16* __restrict__ yl) {
  const int row = blockIdx.x * 4 + (threadIdx.x >> 6);
  const int lane = threadIdx.x & 63;
  const float* xr = x + (size_t)row * DMODEL;
  float v[8];
  *(float4*)&v[0] = *(const float4*)(xr + lane * 8);
  *(float4*)&v[4] = *(const float4*)(xr + lane * 8 + 4);
  float s = 0.0f;
#pragma unroll
  for (int j = 0; j < 8; ++j) s += v[j];
  s = wave_sum(s);
  float mean = s * (1.0f / 512.0f);
  float s2 = 0.0f;
#pragma unroll
  for (int j = 0; j < 8; ++j) {
    float d = v[j] - mean;
    s2 += d * d;
  }
  s2 = wave_sum(s2);
  float rstd = 1.0f / sqrtf(s2 * (1.0f / 512.0f) + 1e-5f);
  float gg[8], bv[8];
  *(float4*)&gg[0] = *(const float4*)(g + lane * 8);
  *(float4*)&gg[4] = *(const float4*)(g + lane * 8 + 4);
  *(float4*)&bv[0] = *(const float4*)(b + lane * 8);
  *(float4*)&bv[4] = *(const float4*)(b + lane * 8 + 4);
  float t[8];
#pragma unroll
  for (int j = 0; j < 8; ++j) t[j] = (v[j] - mean) * rstd * gg[j] + bv[j];
  float n2 = 0.0f;
#pragma unroll
  for (int j = 0; j < 8; ++j) n2 += t[j] * t[j];
  n2 = wave_sum(n2);
  float den = fmaxf(sqrtf(n2), 1e-12f);
#pragma unroll
  for (int j = 0; j < 8; ++j) t[j] /= den;
  store8_split2(yh, yl, (size_t)row * DMODEL + lane * 8, t);
}

__global__ __launch_bounds__(256) void l2_split2(const float* __restrict__ x,
                                                 u16* __restrict__ yh,
                                                 u16* __restrict__ yl) {
  const int row = blockIdx.x * 4 + (threadIdx.x >> 6);
  const int lane = threadIdx.x & 63;
  const float* xr = x + (size_t)row * DMODEL;
  float v[8];
  *(float4*)&v[0] = *(const float4*)(xr + lane * 8);
  *(float4*)&v[4] = *(const float4*)(xr + lane * 8 + 4);
  float n2 = 0.0f;
#pragma unroll
  for (int j = 0; j < 8; ++j) n2 += v[j] * v[j];
  n2 = wave_sum(n2);
  float den = fmaxf(sqrtf(n2), 1e-12f);
#pragma unroll
  for (int j = 0; j < 8; ++j) v[j] /= den;
  store8_split2(yh, yl, (size_t)row * DMODEL + lane * 8, v);
}

// softmax over rows of 1024, in-place on 2 fp16 planes
__global__ __launch_bounds__(256) void softmax2(u16* __restrict__ H,
                                                u16* __restrict__ L) {
  const int row = blockIdx.x;
  const int tid = threadIdx.x;
  const size_t base = (size_t)row * 1024 + tid * 4;
  ushort4 qh = *(const ushort4*)&H[base];
  ushort4 ql = *(const ushort4*)&L[base];
  float v0 = h2f(qh.x) + h2f(ql.x);
  float v1 = h2f(qh.y) + h2f(ql.y);
  float v2 = h2f(qh.z) + h2f(ql.z);
  float v3 = h2f(qh.w) + h2f(ql.w);
  float mx = fmaxf(fmaxf(v0, v1), fmaxf(v2, v3));
#pragma unroll
  for (int off = 1; off < 64; off <<= 1) mx = fmaxf(mx, __shfl_xor(mx, off));
  __shared__ float red[4];
  const int wv = tid >> 6;
  if ((tid & 63) == 0) red[wv] = mx;
  __syncthreads();
  mx = fmaxf(fmaxf(red[0], red[1]), fmaxf(red[2], red[3]));
  float e0 = __expf(v0 - mx), e1 = __expf(v1 - mx), e2 = __expf(v2 - mx),
        e3 = __expf(v3 - mx);
  float s = e0 + e1 + e2 + e3;
#pragma unroll
  for (int off = 1; off < 64; off <<= 1) s += __shfl_xor(s, off);
  __syncthreads();
  if ((tid & 63) == 0) red[wv] = s;
  __syncthreads();
  s = red[0] + red[1] + red[2] + red[3];
  float inv = 1.0f / s;
  u16 ah[4], al[4];
  split2(e0 * inv, ah[0], al[0]);
  split2(e1 * inv, ah[1], al[1]);
  split2(e2 * inv, ah[2], al[2]);
  split2(e3 * inv, ah[3], al[3]);
  *(ushort4*)&H[base] = make_ushort4(ah[0], ah[1], ah[2], ah[3]);
  *(ushort4*)&L[base] = make_ushort4(al[0], al[1], al[2], al[3]);
}

// generic fp32 -> 2 fp16 planes splitter (n4 = n/4)
__global__ __launch_bounds__(256) void split2_k(const float* __restrict__ src,
                                                u16* __restrict__ H,
                                                u16* __restrict__ L, int n4) {
  for (int e = blockIdx.x * 256 + threadIdx.x; e < n4; e += gridDim.x * 256) {
    float4 v = *(const float4*)(src + (size_t)e * 4);
    u16 ah[4], al[4];
    split2(v.x, ah[0], al[0]);
    split2(v.y, ah[1], al[1]);
    split2(v.z, ah[2], al[2]);
    split2(v.w, ah[3], al[3]);
    *(ushort4*)&H[(size_t)e * 4] = make_ushort4(ah[0], ah[1], ah[2], ah[3]);
    *(ushort4*)&L[(size_t)e * 4] = make_ushort4(al[0], al[1], al[2], al[3]);
  }
}

// transpose codebook [1024][512] -> cbT [512][1024], split into 2 planes
__global__ __launch_bounds__(256) void tsplit_cb(const float* __restrict__ cb,
                                                 u16* __restrict__ th,
                                                 u16* __restrict__ tl) {
  const int c = blockIdx.x;
  const int t = threadIdx.x;
  u16 ah[4], al[4];
#pragma unroll
  for (int j = 0; j < 4; ++j) {
    float v = cb[(size_t)(4 * t + j) * 512 + c];
    split2(v, ah[j], al[j]);
  }
  const size_t base = (size_t)c * 1024 + 4 * t;
  *(ushort4*)&th[base] = make_ushort4(ah[0], ah[1], ah[2], ah[3]);
  *(ushort4*)&tl[base] = make_ushort4(al[0], al[1], al[2], al[3]);
}

__global__ __launch_bounds__(256) void vq_finalize(
    const float* __restrict__ logits, const float* __restrict__ patterns,
    float* __restrict__ emb, float* __restrict__ assign,
    float* __restrict__ idxf) {
  const int row = blockIdx.x * 4 + (threadIdx.x >> 6);
  const int lane = threadIdx.x & 63;
  const float* lr = logits + (size_t)row * NPAT;
  float best = -__builtin_huge_valf();
  int bi = 0;
#pragma unroll
  for (int jj = 0; jj < 8; ++jj) {
    int j = lane + jj * 64;
    float v = lr[j];
    if (v > best) {
      best = v;
      bi = j;
    }
  }
#pragma unroll
  for (int off = 1; off < 64; off <<= 1) {
    float ob = __shfl_xor(best, off);
    int oi = __shfl_xor(bi, off);
    if (ob > best || (ob == best && oi < bi)) {
      best = ob;
      bi = oi;
    }
  }
  const float* pr = patterns + (size_t)bi * DMODEL;
#pragma unroll
  for (int g = 0; g < 2; ++g) {
    int c = lane * 8 + g * 4;
    float4 pv = *(const float4*)(pr + c);
    *(float4*)(emb + (size_t)row * DMODEL + c) = pv;
    float4 av;
    av.x = (c + 0 == bi) ? 1.0f : 0.0f;
    av.y = (c + 1 == bi) ? 1.0f : 0.0f;
    av.z = (c + 2 == bi) ? 1.0f : 0.0f;
    av.w = (c + 3 == bi) ? 1.0f : 0.0f;
    *(float4*)(assign + (size_t)row * NPAT + c) = av;
  }
  if (lane == 0) idxf[row] = (float)bi;
}

// ---------------- host launch ----------------
extern "C" void kernel_launch(void* const* d_in, const int* in_sizes, int n_in,
                              void* d_out, int out_size, void* d_ws,
                              size_t ws_size, hipStream_t stream) {
  (void)in_sizes;
  (void)n_in;
  (void)out_size;
  (void)ws_size;
  const float* x = (const float*)d_in[0];
  const float* gumbel = (const float*)d_in[1];
  const float* sym_w = (const float*)d_in[2];
  const float* sym_b = (const float*)d_in[3];
  const float* codebook = (const float*)d_in[4];
  const float* pos_enc = (const float*)d_in[5];
  const float* attn_in_w = (const float*)d_in[6];
  const float* attn_in_b = (const float*)d_in[7];
  const float* attn_out_w = (const float*)d_in[8];
  const float* attn_out_b = (const float*)d_in[9];
  const float* n1_g = (const float*)d_in[10];
  const float* n1_b = (const float*)d_in[11];
  const float* n2_g = (const float*)d_in[12];
  const float* n2_b = (const float*)d_in[13];
  const float* ffn_w1 = (const float*)d_in[14];
  const float* ffn_b1 = (const float*)d_in[15];
  const float* ffn_w2 = (const float*)d_in[16];
  const float* ffn_b2 = (const float*)d_in[17];
  const float* q_w = (const float*)d_in[18];
  const float* q_b = (const float*)d_in[19];
  const float* qln_g = (const float*)d_in[20];
  const float* qln_b = (const float*)d_in[21];
  const float* patterns = (const float*)d_in[22];
  const int* epoch = (const int*)d_in[23];
  const int* tot = (const int*)d_in[24];

  float* out = (float*)d_out;
  float* emb = out;               // [8192,512]
  float* assign = out + 4194304;  // [8192,512]
  float* logits = out + 8388608;  // [8192,512]
  float* h = out + 12582912;      // [8192,512]
  float* idxf = out + 16777216;   // [8192]

  float* ws_f = (float*)d_ws;
  // A region @0 (18.87M floats = 37.75M u16)
  u16* a16 = (u16*)ws_f;
  // B region @18.87M floats (6.29M floats = 12.58M u16)
  float* bF = ws_f + 18874368;
  u16* b16 = (u16*)bF;
  u16 *hnH = b16, *hnL = b16 + 4194304;
  // W region @25.17M floats (2.36M u16 capacity)
  float* wF = ws_f + 25165824;
  u16* w16 = (u16*)wF;

  // ---- symbolization ----
  u16 *xH = a16, *xL = a16 + 8388608;
  split2_k<<<2048, 256, 0, stream>>>(x, xH, xL, 2097152);
  split2_k<<<512, 256, 0, stream>>>(sym_w, w16, w16 + 524288, 131072);
  gemm_mf<64, E_BIAS><<<512, 256, 0, stream>>>(
      xH, xL, w16, w16 + 524288, sym_b, nullptr, bF, nullptr, nullptr, 512,
      1024, 1024, 1024, 4, nullptr, nullptr);
  l2_split2<<<256, 256, 0, stream>>>(codebook, w16, w16 + 524288);
  u16 *hpH = a16, *hpL = a16 + 4194304;
  l2_split2<<<2048, 256, 0, stream>>>(bF, hpH, hpL);
  u16 *sH = a16 + 12582912, *sL = a16 + 20971520;
  gemm_mf<64, E_GUM2><<<1024, 256, 0, stream>>>(
      hpH, hpL, w16, w16 + 524288, nullptr, gumbel, nullptr, sH, sL, 1024, 512,
      512, 512, 8, nullptr, nullptr);
  softmax2<<<8192, 256, 0, stream>>>(sH, sL);
  tsplit_cb<<<512, 256, 0, stream>>>(codebook, w16, w16 + 524288);
  gemm_mf<64, E_POS><<<512, 256, 0, stream>>>(
      sH, sL, w16, w16 + 524288, nullptr, pos_enc, h, nullptr, nullptr, 512,
      1024, 1024, 1024, 4, nullptr, nullptr);

  // ---- transformer layers ----
  u16 *qkvH = a16, *qkvL = a16 + 12582912;
  u16* w1p = a16 + 33554432;            // 2 x 1048576 u16 (after qkv/mid)
  u16* w2p = b16 + 8388608;             // 2 x 1048576 u16 (after hn planes)
  u16 *pH = a16, *pL = a16 + 16777216;  // FFN mid [8192,2048] x2 planes

  for (int l = 0; l < 4; ++l) {
    const float* inw = attn_in_w + (size_t)l * 1536 * 512;
    const float* inb = attn_in_b + (size_t)l * 1536;
    const float* outw = attn_out_w + (size_t)l * 512 * 512;
    const float* outb = attn_out_b + (size_t)l * 512;
    const float* w1 = ffn_w1 + (size_t)l * 2048 * 512;
    const float* b1 = ffn_b1 + (size_t)l * 2048;
    const float* w2 = ffn_w2 + (size_t)l * 512 * 2048;
    const float* b2 = ffn_b2 + (size_t)l * 512;

    ln_split2<<<2048, 256, 0, stream>>>(h, n1_g + l * 512, n1_b + l * 512,
                                        hnH, hnL);
    split2_k<<<1024, 256, 0, stream>>>(inw, w16, w16 + 786432, 196608);
    gemm_mf<128, E_QKV2><<<768, 256, 0, stream>>>(
        hnH, hnL, w16, w16 + 786432, inb, nullptr, nullptr, qkvH, qkvL, 1536,
        512, 512, 512, 12, nullptr, nullptr);
    flash_mfma<<<1024, 256, 0, stream>>>(qkvH, qkvL, hnH, hnL);
    split2_k<<<256, 256, 0, stream>>>(outw, w16, w16 + 262144, 65536);
    gemm_mf<64, E_RES><<<512, 256, 0, stream>>>(
        hnH, hnL, w16, w16 + 262144, outb, h, h, nullptr, nullptr, 512, 512,
        512, 512, 4, nullptr, nullptr);
    ln_split2<<<2048, 256, 0, stream>>>(h, n2_g + l * 512, n2_b + l * 512,
                                        hnH, hnL);
    split2_k<<<1024, 256, 0, stream>>>(w1, w1p, w1p + 1048576, 262144);
    split2_k<<<1024, 256, 0, stream>>>(w2, w2p, w2p + 1048576, 262144);
    // GELU: single N=2048 GEMM into full-width mid planes
    gemm_mf<128, E_GELU2><<<1024, 256, 0, stream>>>(
        hnH, hnL, w1p, w1p + 1048576, b1, nullptr, nullptr, pH, pL, 2048, 512,
        512, 512, 16, nullptr, nullptr);
    // w2: single K=2048 GEMM with residual (BM=64 -> 512 blocks, 3 blk/CU)
    gemm_mf<64, E_RES><<<512, 256, 0, stream>>>(
        pH, pL, w2p, w2p + 1048576, b2, h, h, nullptr, nullptr, 512, 2048,
        2048, 2048, 4, nullptr, nullptr);
  }

  // ---- VQ head (MFMA fp16 double-split) ----
  u16 *hsH = a16, *hsL = a16 + 4194304;          // h planes
  u16 *QpH = a16 + 8388608, *QpL = a16 + 12582912;  // Q planes
  split2_k<<<1024, 256, 0, stream>>>(h, hsH, hsL, 1048576);
  split2_k<<<256, 256, 0, stream>>>(q_w, w16, w16 + 262144, 65536);
  gemm_mf<64, E_BIAS><<<512, 256, 0, stream>>>(
      hsH, hsL, w16, w16 + 262144, q_b, nullptr, bF, nullptr, nullptr, 512,
      512, 512, 512, 4, nullptr, nullptr);
  ln_l2_split2<<<2048, 256, 0, stream>>>(bF, qln_g, qln_b, QpH, QpL);
  l2_split2<<<128, 256, 0, stream>>>(patterns, w16 + 524288, w16 + 786432);
  gemm_mf<64, E_VQ><<<512, 256, 0, stream>>>(
      QpH, QpL, w16 + 524288, w16 + 786432, nullptr, nullptr, logits, nullptr,
      nullptr, 512, 512, 512, 512, 4, epoch, tot);
  vq_finalize<<<2048, 256, 0, stream>>>(logits, patterns, emb, assign, idxf);
}